// Round 1
// baseline (2835.605 us; speedup 1.0000x reference)
//
#include <hip/hip_runtime.h>
#include <hip/hip_bf16.h>
#include <math.h>

// Problem constants (from reference setup_inputs)
constexpr int Bc  = 2;
constexpr int Sc  = 2048;
constexpr int Hc  = 512;
constexpr int NHc = 8;
constexpr int DHc = 64;
constexpr int Tc  = Bc * Sc;      // 4096 tokens
constexpr int Ec  = 64;           // experts
constexpr int Fc  = 2048;         // ffn dim
constexpr int Cap = 256;          // capacity = 2 * T * 2 / E

__device__ __forceinline__ float gelu_f(float x) {
    // jax.nn.gelu default approximate=True (tanh)
    float x3 = x * x * x;
    return 0.5f * x * (1.0f + tanhf(0.7978845608028654f * (x + 0.044715f * x3)));
}

// ---------------- LayerNorm: one block per row (H=512, 256 threads) ----------
__global__ __launch_bounds__(256) void ln_kernel(const float* __restrict__ x,
                                                 const float* __restrict__ g,
                                                 const float* __restrict__ b,
                                                 float* __restrict__ o) {
    int t = blockIdx.x;
    const float* row = x + (size_t)t * Hc;
    int tid = threadIdx.x;
    float v0 = row[tid];
    float v1 = row[tid + 256];
    float s = v0 + v1, s2 = v0 * v0 + v1 * v1;
    for (int off = 32; off; off >>= 1) {
        s  += __shfl_down(s,  off);
        s2 += __shfl_down(s2, off);
    }
    __shared__ float ls[4], ls2[4];
    int wid = tid >> 6, lane = tid & 63;
    if (lane == 0) { ls[wid] = s; ls2[wid] = s2; }
    __syncthreads();
    if (tid == 0) {
        float a = 0.f, a2 = 0.f;
        for (int i = 0; i < 4; i++) { a += ls[i]; a2 += ls2[i]; }
        ls[0] = a; ls2[0] = a2;
    }
    __syncthreads();
    float mean = ls[0] * (1.0f / Hc);
    float var  = ls2[0] * (1.0f / Hc) - mean * mean;
    float r = rsqrtf(var + 1e-5f);
    o[(size_t)t * Hc + tid]       = (v0 - mean) * r * g[tid]       + b[tid];
    o[(size_t)t * Hc + tid + 256] = (v1 - mean) * r * g[tid + 256] + b[tid + 256];
}

// ---------------- Generic tiled fp32 GEMM ------------------------------------
// C[M,N] = A[M,K] @ W[K,N]  (+ epilogue), batched via blockIdx.z with strides.
// EPI: 0=none, 1=+X[m,n] residual, 2=gelu(acc + X[n]) , 3=acc + X[n]
// BM=BN=128, BK=8, 256 threads, 8x8 per thread. All dims divisible.
template <typename TA, typename TC, int EPI>
__global__ __launch_bounds__(256) void gemm_kernel(const TA* __restrict__ A,
                                                   const float* __restrict__ W,
                                                   TC* __restrict__ Co,
                                                   const float* __restrict__ X,
                                                   int M, int N, int K,
                                                   long sA, long sW, long sC, long sX) {
    int bz = blockIdx.z;
    A  += (size_t)bz * sA;
    W  += (size_t)bz * sW;
    Co += (size_t)bz * sC;
    if (X) X += (size_t)bz * sX;

    int m0 = blockIdx.y * 128, n0 = blockIdx.x * 128;
    __shared__ float As[8][132];
    __shared__ float Bs[8][132];
    float acc[8][8] = {};
    int tid = threadIdx.x;
    int ty = tid >> 4, tx = tid & 15;

    for (int k0 = 0; k0 < K; k0 += 8) {
        #pragma unroll
        for (int i = 0; i < 4; i++) {
            int e = i * 256 + tid;
            int m = e >> 3, kk = e & 7;
            As[kk][m] = static_cast<float>(A[(size_t)(m0 + m) * K + k0 + kk]);
        }
        #pragma unroll
        for (int i = 0; i < 4; i++) {
            int e = i * 256 + tid;
            int kk = e >> 7, n = e & 127;
            Bs[kk][n] = W[(size_t)(k0 + kk) * N + n0 + n];
        }
        __syncthreads();
        #pragma unroll
        for (int kk = 0; kk < 8; kk++) {
            float a[8], bb[8];
            #pragma unroll
            for (int i = 0; i < 8; i++) a[i] = As[kk][ty * 8 + i];
            #pragma unroll
            for (int j = 0; j < 8; j++) bb[j] = Bs[kk][tx * 8 + j];
            #pragma unroll
            for (int i = 0; i < 8; i++)
                #pragma unroll
                for (int j = 0; j < 8; j++)
                    acc[i][j] += a[i] * bb[j];
        }
        __syncthreads();
    }

    #pragma unroll
    for (int i = 0; i < 8; i++) {
        int m = m0 + ty * 8 + i;
        #pragma unroll
        for (int j = 0; j < 8; j++) {
            int n = n0 + tx * 8 + j;
            float vv = acc[i][j];
            if (EPI == 1) vv += X[(size_t)m * N + n];
            if (EPI == 2) { vv += X[n]; vv = gelu_f(vv); }
            if (EPI == 3) vv += X[n];
            Co[(size_t)m * N + n] = (TC)vv;
        }
    }
}

// ---------------- Flash attention (fp32) -------------------------------------
// grid (S/64, NH, B), 256 threads. 4 threads per q-row, 16 keys each per tile.
__global__ __launch_bounds__(256) void attn_kernel(const float* __restrict__ q,
                                                   const float* __restrict__ k,
                                                   const float* __restrict__ v,
                                                   float* __restrict__ o) {
    int qt = blockIdx.x, hh = blockIdx.y, b = blockIdx.z;
    int q0 = qt * 64;
    __shared__ float qs[64][65], ks[64][65], vs[64][65];
    int tid = threadIdx.x;

    #pragma unroll
    for (int i = 0; i < 16; i++) {
        int e = i * 256 + tid;
        int r = e >> 6, d = e & 63;
        qs[r][d] = q[((size_t)(b * Sc + q0 + r)) * Hc + hh * 64 + d];
    }

    int r = tid >> 2, sub = tid & 3;
    float O[64];
    #pragma unroll
    for (int d = 0; d < 64; d++) O[d] = 0.f;
    float mrun = -INFINITY, lrun = 0.f;
    const float scale = 0.125f;  // dh^-0.5

    for (int kt = 0; kt < Sc / 64; kt++) {
        __syncthreads();
        #pragma unroll
        for (int i = 0; i < 16; i++) {
            int e = i * 256 + tid;
            int rr = e >> 6, d = e & 63;
            size_t gi = ((size_t)(b * Sc + kt * 64 + rr)) * Hc + hh * 64 + d;
            ks[rr][d] = k[gi];
            vs[rr][d] = v[gi];
        }
        __syncthreads();

        float s[16];
        #pragma unroll
        for (int j = 0; j < 16; j++) s[j] = 0.f;
        for (int d = 0; d < 64; d++) {
            float qv = qs[r][d];
            #pragma unroll
            for (int j = 0; j < 16; j++) s[j] += qv * ks[sub * 16 + j][d];
        }
        float mt = -INFINITY;
        #pragma unroll
        for (int j = 0; j < 16; j++) { s[j] *= scale; mt = fmaxf(mt, s[j]); }
        mt = fmaxf(mt, __shfl_xor(mt, 1));
        mt = fmaxf(mt, __shfl_xor(mt, 2));
        float mnew = fmaxf(mrun, mt);
        float sc = (mrun == -INFINITY) ? 0.f : expf(mrun - mnew);
        float p[16];
        float ps = 0.f;
        #pragma unroll
        for (int j = 0; j < 16; j++) { p[j] = expf(s[j] - mnew); ps += p[j]; }
        ps += __shfl_xor(ps, 1);
        ps += __shfl_xor(ps, 2);
        lrun = lrun * sc + ps;
        mrun = mnew;
        #pragma unroll
        for (int d = 0; d < 64; d++) O[d] *= sc;
        #pragma unroll
        for (int j = 0; j < 16; j++) {
            float pj = p[j];
            #pragma unroll
            for (int d = 0; d < 64; d++) O[d] += pj * vs[sub * 16 + j][d];
        }
    }

    #pragma unroll
    for (int d = 0; d < 64; d++) {
        O[d] += __shfl_xor(O[d], 1);
        O[d] += __shfl_xor(O[d], 2);
    }
    float inv = 1.0f / lrun;
    #pragma unroll
    for (int dd = 0; dd < 16; dd++) {
        int d = sub * 16 + dd;
        o[((size_t)(b * Sc + q0 + r)) * Hc + hh * 64 + d] = O[d] * inv;
    }
}

// ---------------- Router GEMM + softmax + top-2 ------------------------------
// 4 waves per block, one token per wave; lane = expert.
__global__ __launch_bounds__(256) void router_top2_kernel(const float* __restrict__ x2,
                                                          const float* __restrict__ wr,
                                                          int* __restrict__ ef,
                                                          float* __restrict__ gf) {
    int t = blockIdx.x * 4 + (threadIdx.x >> 6);
    int l = threadIdx.x & 63;
    const float* xr = x2 + (size_t)t * Hc;
    float acc = 0.f;
    for (int hhh = 0; hhh < Hc; hhh++) acc += xr[hhh] * wr[hhh * Ec + l];

    float mx = acc;
    for (int off = 32; off; off >>= 1) mx = fmaxf(mx, __shfl_xor(mx, off));
    float p = expf(acc - mx);
    float sum = p;
    for (int off = 32; off; off >>= 1) sum += __shfl_xor(sum, off);
    p /= sum;

    float v1 = p; int i1 = l;
    for (int off = 32; off; off >>= 1) {
        float ov = __shfl_xor(v1, off);
        int   oi = __shfl_xor(i1, off);
        if (ov > v1 || (ov == v1 && oi < i1)) { v1 = ov; i1 = oi; }
    }
    float v2 = (l == i1) ? -INFINITY : p; int i2 = l;
    for (int off = 32; off; off >>= 1) {
        float ov = __shfl_xor(v2, off);
        int   oi = __shfl_xor(i2, off);
        if (ov > v2 || (ov == v2 && oi < i2)) { v2 = ov; i2 = oi; }
    }
    if (l == 0) {
        float inv = 1.0f / (v1 + v2);
        ef[t * 2]     = i1;
        ef[t * 2 + 1] = i2;
        gf[t * 2]     = v1 * inv;
        gf[t * 2 + 1] = v2 * inv;
    }
}

// ---------------- pos: rank of each slot within its expert (slot order) ------
// grid = E blocks; each block scans all 8192 slots for its expert.
__global__ __launch_bounds__(256) void pos_kernel(const int* __restrict__ ef,
                                                  int* __restrict__ pos) {
    int e = blockIdx.x;
    __shared__ int cnts[257];
    int tid = threadIdx.x;
    int base = tid * 32;  // 8192 / 256
    int c = 0;
    for (int i = 0; i < 32; i++) c += (ef[base + i] == e) ? 1 : 0;
    cnts[tid + 1] = c;
    if (tid == 0) cnts[0] = 0;
    __syncthreads();
    if (tid == 0) {
        for (int i = 1; i <= 256; i++) cnts[i] += cnts[i - 1];
    }
    __syncthreads();
    int run = cnts[tid];
    for (int i = 0; i < 32; i++) {
        if (ef[base + i] == e) pos[base + i] = run++;
    }
}

// ---------------- dispatch: copy kept tokens into expert buffers -------------
__global__ __launch_bounds__(128) void dispatch_kernel(const float* __restrict__ x2,
                                                       const int* __restrict__ ef,
                                                       const int* __restrict__ pos,
                                                       float* __restrict__ buf) {
    int s = blockIdx.x;
    int p = pos[s];
    if (p >= Cap) return;
    int e = ef[s];
    int t = s >> 1;
    const float4* src = (const float4*)(x2 + (size_t)t * Hc);
    float4* dst = (float4*)(buf + ((size_t)e * Cap + p) * Hc);
    dst[threadIdx.x] = src[threadIdx.x];
}

// ---------------- combine: out = xa + sum_k gate * y[ef,pos] -----------------
__global__ __launch_bounds__(128) void combine_kernel(const float* __restrict__ xa,
                                                      const float* __restrict__ y,
                                                      const int* __restrict__ ef,
                                                      const int* __restrict__ pos,
                                                      const float* __restrict__ gf,
                                                      float* __restrict__ out) {
    int t = blockIdx.x;
    int d = threadIdx.x;
    float4 acc = ((const float4*)(xa + (size_t)t * Hc))[d];
    #pragma unroll
    for (int kk = 0; kk < 2; kk++) {
        int s = t * 2 + kk;
        int p = pos[s];
        if (p < Cap) {
            float w = gf[s];
            float4 yv = ((const float4*)(y + ((size_t)ef[s] * Cap + p) * Hc))[d];
            acc.x += w * yv.x;
            acc.y += w * yv.y;
            acc.z += w * yv.z;
            acc.w += w * yv.w;
        }
    }
    ((float4*)(out + (size_t)t * Hc))[d] = acc;
}

// ---------------- launch -----------------------------------------------------
extern "C" void kernel_launch(void* const* d_in, const int* in_sizes, int n_in,
                              void* d_out, int out_size, void* d_ws, size_t ws_size,
                              hipStream_t stream) {
    const float* x     = (const float*)d_in[0];
    const float* ln1_g = (const float*)d_in[1];
    const float* ln1_b = (const float*)d_in[2];
    const float* wq    = (const float*)d_in[3];
    const float* wk    = (const float*)d_in[4];
    const float* wv    = (const float*)d_in[5];
    const float* wo    = (const float*)d_in[6];
    const float* ln2_g = (const float*)d_in[7];
    const float* ln2_b = (const float*)d_in[8];
    const float* wr    = (const float*)d_in[9];
    const float* w1    = (const float*)d_in[10];
    const float* b1    = (const float*)d_in[11];
    const float* w2    = (const float*)d_in[12];
    const float* b2    = (const float*)d_in[13];
    float* out = (float*)d_out;

    const size_t TH  = (size_t)Tc * Hc;       // 2,097,152
    const size_t ECH = (size_t)Ec * Cap * Hc; // 8,388,608
    const size_t ECF = (size_t)Ec * Cap * Fc; // 33,554,432

    // ws layout (floats): x1 | q | k | v | xa | buf(=y) | h(bf16)
    size_t need = TH * 5 * 4 + ECH * 4 + ECF * 2;
    if (ws_size < need) return;  // insufficient workspace -> fail loudly

    float* ws  = (float*)d_ws;
    float* x1  = ws;
    float* q   = ws + TH;
    float* k   = ws + 2 * TH;
    float* v   = ws + 3 * TH;
    float* xa  = ws + 4 * TH;
    float* attn = x1;          // reuse (x1 dead after QKV)
    float* x2  = q;            // reuse (q dead after attention)
    float* gf  = k;            // reuse (k dead after attention)
    int*   ef  = (int*)v;      // reuse (v dead after attention)
    int*   pos = ef + Tc * 2;
    float* buf = ws + 5 * TH;  // expert input buffers; later reused as y
    float* y   = buf;
    __hip_bfloat16* h = (__hip_bfloat16*)(ws + 5 * TH + ECH);

    dim3 blk(256);

    // 1. LN1
    ln_kernel<<<Tc, blk, 0, stream>>>(x, ln1_g, ln1_b, x1);

    // 2. QKV projections
    gemm_kernel<float, float, 0><<<dim3(Hc / 128, Tc / 128, 1), blk, 0, stream>>>(
        x1, wq, q, nullptr, Tc, Hc, Hc, 0, 0, 0, 0);
    gemm_kernel<float, float, 0><<<dim3(Hc / 128, Tc / 128, 1), blk, 0, stream>>>(
        x1, wk, k, nullptr, Tc, Hc, Hc, 0, 0, 0, 0);
    gemm_kernel<float, float, 0><<<dim3(Hc / 128, Tc / 128, 1), blk, 0, stream>>>(
        x1, wv, v, nullptr, Tc, Hc, Hc, 0, 0, 0, 0);

    // 3. attention
    attn_kernel<<<dim3(Sc / 64, NHc, Bc), blk, 0, stream>>>(q, k, v, attn);

    // 4. output projection + residual: xa = attn @ wo + x
    gemm_kernel<float, float, 1><<<dim3(Hc / 128, Tc / 128, 1), blk, 0, stream>>>(
        attn, wo, xa, x, Tc, Hc, Hc, 0, 0, 0, 0);

    // 5. LN2
    ln_kernel<<<Tc, blk, 0, stream>>>(xa, ln2_g, ln2_b, x2);

    // 6. router + top2
    router_top2_kernel<<<Tc / 4, blk, 0, stream>>>(x2, wr, ef, gf);

    // 7. positions within expert queues
    pos_kernel<<<Ec, blk, 0, stream>>>(ef, pos);

    // 8. dispatch tokens to expert buffers
    dispatch_kernel<<<Tc * 2, dim3(128), 0, stream>>>(x2, ef, pos, buf);

    // 9. expert GEMM1 + bias + gelu -> h (bf16)
    gemm_kernel<float, __hip_bfloat16, 2><<<dim3(Fc / 128, Cap / 128, Ec), blk, 0, stream>>>(
        buf, w1, h, b1, Cap, Fc, Hc,
        (long)Cap * Hc, (long)Hc * Fc, (long)Cap * Fc, (long)Fc);

    // 10. expert GEMM2 + bias -> y (fp32, overwrites buf)
    gemm_kernel<__hip_bfloat16, float, 3><<<dim3(Hc / 128, Cap / 128, Ec), blk, 0, stream>>>(
        h, w2, y, b2, Cap, Hc, Fc,
        (long)Cap * Fc, (long)Fc * Hc, (long)Cap * Hc, (long)Hc);

    // 11. combine + final residual
    combine_kernel<<<Tc, dim3(128), 0, stream>>>(xa, y, ef, pos, gf, out);
}

// Round 2
// 1421.007 us; speedup vs baseline: 1.9955x; 1.9955x over previous
//
#include <hip/hip_runtime.h>
#include <hip/hip_bf16.h>
#include <math.h>

// Problem constants (from reference setup_inputs)
constexpr int Bc  = 2;
constexpr int Sc  = 2048;
constexpr int Hc  = 512;
constexpr int NHc = 8;
constexpr int DHc = 64;
constexpr int Tc  = Bc * Sc;      // 4096 tokens
constexpr int Ec  = 64;           // experts
constexpr int Fc  = 2048;         // ffn dim
constexpr int Cap = 256;          // capacity = 2 * T * 2 / E

typedef __attribute__((ext_vector_type(8))) short bf16x8;
typedef __attribute__((ext_vector_type(4))) float f32x4;

__device__ __forceinline__ unsigned short f2b(float f) {
    union { float f; unsigned u; } v; v.f = f;
    unsigned r = v.u + 0x7FFF + ((v.u >> 16) & 1);   // RTNE
    return (unsigned short)(r >> 16);
}

__device__ __forceinline__ float gelu_f(float x) {
    // jax.nn.gelu default approximate=True (tanh)
    float x3 = x * x * x;
    return 0.5f * x * (1.0f + tanhf(0.7978845608028654f * (x + 0.044715f * x3)));
}

// ---------------- LayerNorm: one block per row (H=512, 256 threads) ----------
__global__ __launch_bounds__(256) void ln_kernel(const float* __restrict__ x,
                                                 const float* __restrict__ g,
                                                 const float* __restrict__ b,
                                                 float* __restrict__ o) {
    int t = blockIdx.x;
    const float* row = x + (size_t)t * Hc;
    int tid = threadIdx.x;
    float v0 = row[tid];
    float v1 = row[tid + 256];
    float s = v0 + v1, s2 = v0 * v0 + v1 * v1;
    for (int off = 32; off; off >>= 1) {
        s  += __shfl_down(s,  off);
        s2 += __shfl_down(s2, off);
    }
    __shared__ float ls[4], ls2[4];
    int wid = tid >> 6, lane = tid & 63;
    if (lane == 0) { ls[wid] = s; ls2[wid] = s2; }
    __syncthreads();
    if (tid == 0) {
        float a = 0.f, a2 = 0.f;
        for (int i = 0; i < 4; i++) { a += ls[i]; a2 += ls2[i]; }
        ls[0] = a; ls2[0] = a2;
    }
    __syncthreads();
    float mean = ls[0] * (1.0f / Hc);
    float var  = ls2[0] * (1.0f / Hc) - mean * mean;
    float r = rsqrtf(var + 1e-5f);
    o[(size_t)t * Hc + tid]       = (v0 - mean) * r * g[tid]       + b[tid];
    o[(size_t)t * Hc + tid + 256] = (v1 - mean) * r * g[tid + 256] + b[tid + 256];
}

// ---------------- Generic tiled fp32 GEMM ------------------------------------
// C[M,N] = A[M,K] @ W[K,N]  (+ epilogue), batched via blockIdx.z with strides.
// EPI: 0=none, 1=+X[m,n] residual, 2=gelu(acc + X[n]) , 3=acc + X[n]
template <typename TA, typename TC, int EPI>
__global__ __launch_bounds__(256) void gemm_kernel(const TA* __restrict__ A,
                                                   const float* __restrict__ W,
                                                   TC* __restrict__ Co,
                                                   const float* __restrict__ X,
                                                   int M, int N, int K,
                                                   long sA, long sW, long sC, long sX) {
    int bz = blockIdx.z;
    A  += (size_t)bz * sA;
    W  += (size_t)bz * sW;
    Co += (size_t)bz * sC;
    if (X) X += (size_t)bz * sX;

    int m0 = blockIdx.y * 128, n0 = blockIdx.x * 128;
    __shared__ float As[8][132];
    __shared__ float Bs[8][132];
    float acc[8][8] = {};
    int tid = threadIdx.x;
    int ty = tid >> 4, tx = tid & 15;

    for (int k0 = 0; k0 < K; k0 += 8) {
        #pragma unroll
        for (int i = 0; i < 4; i++) {
            int e = i * 256 + tid;
            int m = e >> 3, kk = e & 7;
            As[kk][m] = static_cast<float>(A[(size_t)(m0 + m) * K + k0 + kk]);
        }
        #pragma unroll
        for (int i = 0; i < 4; i++) {
            int e = i * 256 + tid;
            int kk = e >> 7, n = e & 127;
            Bs[kk][n] = W[(size_t)(k0 + kk) * N + n0 + n];
        }
        __syncthreads();
        #pragma unroll
        for (int kk = 0; kk < 8; kk++) {
            float a[8], bb[8];
            #pragma unroll
            for (int i = 0; i < 8; i++) a[i] = As[kk][ty * 8 + i];
            #pragma unroll
            for (int j = 0; j < 8; j++) bb[j] = Bs[kk][tx * 8 + j];
            #pragma unroll
            for (int i = 0; i < 8; i++)
                #pragma unroll
                for (int j = 0; j < 8; j++)
                    acc[i][j] += a[i] * bb[j];
        }
        __syncthreads();
    }

    #pragma unroll
    for (int i = 0; i < 8; i++) {
        int m = m0 + ty * 8 + i;
        #pragma unroll
        for (int j = 0; j < 8; j++) {
            int n = n0 + tx * 8 + j;
            float vv = acc[i][j];
            if (EPI == 1) vv += X[(size_t)m * N + n];
            if (EPI == 2) { vv += X[n]; vv = gelu_f(vv); }
            if (EPI == 3) vv += X[n];
            Co[(size_t)m * N + n] = (TC)vv;
        }
    }
}

// ---------------- MFMA flash attention ---------------------------------------
// grid (S/64, NH, B), 256 threads = 4 waves; each wave owns 16 q-rows.
// Q,K,V fp32 in HBM -> bf16 on the fly. fp32 accumulate. Online softmax.
// MFMA 16x16x32 bf16. A: row=lane%16, k=8*(lane/16)+j. B: col=lane%16, same k.
// C/D: col=lane&15, row=(lane>>4)*4+reg.
__global__ __launch_bounds__(256) void attn_mfma_kernel(const float* __restrict__ q,
                                                        const float* __restrict__ k,
                                                        const float* __restrict__ v,
                                                        float* __restrict__ o) {
    constexpr int LDK = 72;  // bf16 row stride: 144B -> 4-bank row advance, <=2-way
    __shared__ unsigned short Ks[64 * LDK];       // [key][d]
    __shared__ unsigned short Vt[64 * LDK];       // [d][key]  (transposed)
    __shared__ unsigned short Ps[4 * 16 * LDK];   // per-wave [q][key]

    int qt = blockIdx.x, hh = blockIdx.y, b = blockIdx.z;
    int q0 = qt * 64;
    int tid = threadIdx.x;
    int wid = tid >> 6, lane = tid & 63;
    int lr = lane & 15;   // frag row/col selector
    int lg = lane >> 4;   // k-group (0..3)

    // Q fragments (held in registers): rows q0+wid*16+lr, d = 32*s + 8*lg + j
    bf16x8 qf[2];
    {
        const float* qrow = q + ((size_t)(b * Sc + q0 + wid * 16 + lr)) * Hc + hh * 64;
        #pragma unroll
        for (int s = 0; s < 2; s++) {
            #pragma unroll
            for (int j = 0; j < 8; j++) qf[s][j] = (short)f2b(qrow[32 * s + 8 * lg + j]);
        }
    }

    f32x4 Oacc[4];
    #pragma unroll
    for (int nb = 0; nb < 4; nb++) Oacc[nb] = (f32x4){0.f, 0.f, 0.f, 0.f};
    float mrun[4] = {-1e30f, -1e30f, -1e30f, -1e30f};
    float lrun[4] = {0.f, 0.f, 0.f, 0.f};
    const float scale = 0.125f;  // dh^-0.5

    for (int kt = 0; kt < Sc / 64; kt++) {
        __syncthreads();  // previous iteration's Vt/Ks reads complete
        // ---- stage K (row-major) and V (transposed) as bf16 ----
        #pragma unroll
        for (int i = 0; i < 4; i++) {
            int e = i * 256 + tid;
            int key = e >> 4, d4 = (e & 15) * 4;
            size_t gi = ((size_t)(b * Sc + kt * 64 + key)) * Hc + hh * 64 + d4;
            float4 kv = *(const float4*)(k + gi);
            ushort4 kb;
            kb.x = f2b(kv.x); kb.y = f2b(kv.y); kb.z = f2b(kv.z); kb.w = f2b(kv.w);
            *(ushort4*)&Ks[key * LDK + d4] = kb;
            float4 vv = *(const float4*)(v + gi);
            Vt[(d4 + 0) * LDK + key] = f2b(vv.x);
            Vt[(d4 + 1) * LDK + key] = f2b(vv.y);
            Vt[(d4 + 2) * LDK + key] = f2b(vv.z);
            Vt[(d4 + 3) * LDK + key] = f2b(vv.w);
        }
        __syncthreads();

        // ---- S = Q K^T (scaled) ----
        f32x4 sacc[4];
        #pragma unroll
        for (int kb = 0; kb < 4; kb++) sacc[kb] = (f32x4){0.f, 0.f, 0.f, 0.f};
        #pragma unroll
        for (int kb = 0; kb < 4; kb++) {
            #pragma unroll
            for (int s = 0; s < 2; s++) {
                bf16x8 kf = *(const bf16x8*)&Ks[(kb * 16 + lr) * LDK + 32 * s + 8 * lg];
                sacc[kb] = __builtin_amdgcn_mfma_f32_16x16x32_bf16(qf[s], kf, sacc[kb], 0, 0, 0);
            }
        }

        // ---- online softmax (rows live across 16 lanes of same lg) ----
        float sc_[4];
        #pragma unroll
        for (int r = 0; r < 4; r++) {
            float mt = -1e30f;
            #pragma unroll
            for (int kb = 0; kb < 4; kb++) {
                float z = sacc[kb][r] * scale;
                sacc[kb][r] = z;
                mt = fmaxf(mt, z);
            }
            mt = fmaxf(mt, __shfl_xor(mt, 1));
            mt = fmaxf(mt, __shfl_xor(mt, 2));
            mt = fmaxf(mt, __shfl_xor(mt, 4));
            mt = fmaxf(mt, __shfl_xor(mt, 8));
            float mnew = fmaxf(mrun[r], mt);
            float sc = expf(mrun[r] - mnew);
            float ps = 0.f;
            #pragma unroll
            for (int kb = 0; kb < 4; kb++) {
                float p = expf(sacc[kb][r] - mnew);
                ps += p;
                Ps[(wid * 16 + lg * 4 + r) * LDK + kb * 16 + lr] = f2b(p);
            }
            ps += __shfl_xor(ps, 1);
            ps += __shfl_xor(ps, 2);
            ps += __shfl_xor(ps, 4);
            ps += __shfl_xor(ps, 8);
            lrun[r] = lrun[r] * sc + ps;
            mrun[r] = mnew;
            sc_[r] = sc;
        }
        __syncthreads();  // Ps visible to all lanes of the wave

        // ---- O = O*sc + P V ----
        #pragma unroll
        for (int nb = 0; nb < 4; nb++) {
            f32x4 oa = Oacc[nb];
            #pragma unroll
            for (int r = 0; r < 4; r++) oa[r] *= sc_[r];
            #pragma unroll
            for (int s = 0; s < 2; s++) {
                bf16x8 pf = *(const bf16x8*)&Ps[(wid * 16 + lr) * LDK + 32 * s + 8 * lg];
                bf16x8 vf = *(const bf16x8*)&Vt[(nb * 16 + lr) * LDK + 32 * s + 8 * lg];
                oa = __builtin_amdgcn_mfma_f32_16x16x32_bf16(pf, vf, oa, 0, 0, 0);
            }
            Oacc[nb] = oa;
        }
    }

    // ---- epilogue: divide by l, store ----
    float* ob = o + ((size_t)(b * Sc + q0 + wid * 16)) * Hc + hh * 64;
    #pragma unroll
    for (int r = 0; r < 4; r++) {
        float inv = 1.0f / lrun[r];
        int qq = lg * 4 + r;
        #pragma unroll
        for (int nb = 0; nb < 4; nb++) {
            ob[(size_t)qq * Hc + nb * 16 + lr] = Oacc[nb][r] * inv;
        }
    }
}

// ---------------- Router GEMM + softmax + top-2 ------------------------------
__global__ __launch_bounds__(256) void router_top2_kernel(const float* __restrict__ x2,
                                                          const float* __restrict__ wr,
                                                          int* __restrict__ ef,
                                                          float* __restrict__ gf) {
    int t = blockIdx.x * 4 + (threadIdx.x >> 6);
    int l = threadIdx.x & 63;
    const float* xr = x2 + (size_t)t * Hc;
    float acc = 0.f;
    for (int hhh = 0; hhh < Hc; hhh++) acc += xr[hhh] * wr[hhh * Ec + l];

    float mx = acc;
    for (int off = 32; off; off >>= 1) mx = fmaxf(mx, __shfl_xor(mx, off));
    float p = expf(acc - mx);
    float sum = p;
    for (int off = 32; off; off >>= 1) sum += __shfl_xor(sum, off);
    p /= sum;

    float v1 = p; int i1 = l;
    for (int off = 32; off; off >>= 1) {
        float ov = __shfl_xor(v1, off);
        int   oi = __shfl_xor(i1, off);
        if (ov > v1 || (ov == v1 && oi < i1)) { v1 = ov; i1 = oi; }
    }
    float v2 = (l == i1) ? -INFINITY : p; int i2 = l;
    for (int off = 32; off; off >>= 1) {
        float ov = __shfl_xor(v2, off);
        int   oi = __shfl_xor(i2, off);
        if (ov > v2 || (ov == v2 && oi < i2)) { v2 = ov; i2 = oi; }
    }
    if (l == 0) {
        float inv = 1.0f / (v1 + v2);
        ef[t * 2]     = i1;
        ef[t * 2 + 1] = i2;
        gf[t * 2]     = v1 * inv;
        gf[t * 2 + 1] = v2 * inv;
    }
}

// ---------------- pos: rank of each slot within its expert (slot order) ------
__global__ __launch_bounds__(256) void pos_kernel(const int* __restrict__ ef,
                                                  int* __restrict__ pos) {
    int e = blockIdx.x;
    __shared__ int cnts[257];
    int tid = threadIdx.x;
    int base = tid * 32;  // 8192 / 256
    int c = 0;
    for (int i = 0; i < 32; i++) c += (ef[base + i] == e) ? 1 : 0;
    cnts[tid + 1] = c;
    if (tid == 0) cnts[0] = 0;
    __syncthreads();
    if (tid == 0) {
        for (int i = 1; i <= 256; i++) cnts[i] += cnts[i - 1];
    }
    __syncthreads();
    int run = cnts[tid];
    for (int i = 0; i < 32; i++) {
        if (ef[base + i] == e) pos[base + i] = run++;
    }
}

// ---------------- dispatch: copy kept tokens into expert buffers -------------
__global__ __launch_bounds__(128) void dispatch_kernel(const float* __restrict__ x2,
                                                       const int* __restrict__ ef,
                                                       const int* __restrict__ pos,
                                                       float* __restrict__ buf) {
    int s = blockIdx.x;
    int p = pos[s];
    if (p >= Cap) return;
    int e = ef[s];
    int t = s >> 1;
    const float4* src = (const float4*)(x2 + (size_t)t * Hc);
    float4* dst = (float4*)(buf + ((size_t)e * Cap + p) * Hc);
    dst[threadIdx.x] = src[threadIdx.x];
}

// ---------------- combine: out = xa + sum_k gate * y[ef,pos] -----------------
__global__ __launch_bounds__(128) void combine_kernel(const float* __restrict__ xa,
                                                      const float* __restrict__ y,
                                                      const int* __restrict__ ef,
                                                      const int* __restrict__ pos,
                                                      const float* __restrict__ gf,
                                                      float* __restrict__ out) {
    int t = blockIdx.x;
    int d = threadIdx.x;
    float4 acc = ((const float4*)(xa + (size_t)t * Hc))[d];
    #pragma unroll
    for (int kk = 0; kk < 2; kk++) {
        int s = t * 2 + kk;
        int p = pos[s];
        if (p < Cap) {
            float w = gf[s];
            float4 yv = ((const float4*)(y + ((size_t)ef[s] * Cap + p) * Hc))[d];
            acc.x += w * yv.x;
            acc.y += w * yv.y;
            acc.z += w * yv.z;
            acc.w += w * yv.w;
        }
    }
    ((float4*)(out + (size_t)t * Hc))[d] = acc;
}

// ---------------- launch -----------------------------------------------------
extern "C" void kernel_launch(void* const* d_in, const int* in_sizes, int n_in,
                              void* d_out, int out_size, void* d_ws, size_t ws_size,
                              hipStream_t stream) {
    const float* x     = (const float*)d_in[0];
    const float* ln1_g = (const float*)d_in[1];
    const float* ln1_b = (const float*)d_in[2];
    const float* wq    = (const float*)d_in[3];
    const float* wk    = (const float*)d_in[4];
    const float* wv    = (const float*)d_in[5];
    const float* wo    = (const float*)d_in[6];
    const float* ln2_g = (const float*)d_in[7];
    const float* ln2_b = (const float*)d_in[8];
    const float* wr    = (const float*)d_in[9];
    const float* w1    = (const float*)d_in[10];
    const float* b1    = (const float*)d_in[11];
    const float* w2    = (const float*)d_in[12];
    const float* b2    = (const float*)d_in[13];
    float* out = (float*)d_out;

    const size_t TH  = (size_t)Tc * Hc;       // 2,097,152
    const size_t ECH = (size_t)Ec * Cap * Hc; // 8,388,608
    const size_t ECF = (size_t)Ec * Cap * Fc; // 33,554,432

    size_t need = TH * 5 * 4 + ECH * 4 + ECF * 2;
    if (ws_size < need) return;

    float* ws  = (float*)d_ws;
    float* x1  = ws;
    float* q   = ws + TH;
    float* k   = ws + 2 * TH;
    float* v   = ws + 3 * TH;
    float* xa  = ws + 4 * TH;
    float* attn = x1;          // reuse (x1 dead after QKV)
    float* x2  = q;            // reuse (q dead after attention)
    float* gf  = k;            // reuse (k dead after attention)
    int*   ef  = (int*)v;      // reuse (v dead after attention)
    int*   pos = ef + Tc * 2;
    float* buf = ws + 5 * TH;  // expert input buffers; later reused as y
    float* y   = buf;
    __hip_bfloat16* h = (__hip_bfloat16*)(ws + 5 * TH + ECH);

    dim3 blk(256);

    // 1. LN1
    ln_kernel<<<Tc, blk, 0, stream>>>(x, ln1_g, ln1_b, x1);

    // 2. QKV projections
    gemm_kernel<float, float, 0><<<dim3(Hc / 128, Tc / 128, 1), blk, 0, stream>>>(
        x1, wq, q, nullptr, Tc, Hc, Hc, 0, 0, 0, 0);
    gemm_kernel<float, float, 0><<<dim3(Hc / 128, Tc / 128, 1), blk, 0, stream>>>(
        x1, wk, k, nullptr, Tc, Hc, Hc, 0, 0, 0, 0);
    gemm_kernel<float, float, 0><<<dim3(Hc / 128, Tc / 128, 1), blk, 0, stream>>>(
        x1, wv, v, nullptr, Tc, Hc, Hc, 0, 0, 0, 0);

    // 3. attention (MFMA)
    attn_mfma_kernel<<<dim3(Sc / 64, NHc, Bc), blk, 0, stream>>>(q, k, v, attn);

    // 4. output projection + residual: xa = attn @ wo + x
    gemm_kernel<float, float, 1><<<dim3(Hc / 128, Tc / 128, 1), blk, 0, stream>>>(
        attn, wo, xa, x, Tc, Hc, Hc, 0, 0, 0, 0);

    // 5. LN2
    ln_kernel<<<Tc, blk, 0, stream>>>(xa, ln2_g, ln2_b, x2);

    // 6. router + top2
    router_top2_kernel<<<Tc / 4, blk, 0, stream>>>(x2, wr, ef, gf);

    // 7. positions within expert queues
    pos_kernel<<<Ec, blk, 0, stream>>>(ef, pos);

    // 8. dispatch tokens to expert buffers
    dispatch_kernel<<<Tc * 2, dim3(128), 0, stream>>>(x2, ef, pos, buf);

    // 9. expert GEMM1 + bias + gelu -> h (bf16)
    gemm_kernel<float, __hip_bfloat16, 2><<<dim3(Fc / 128, Cap / 128, Ec), blk, 0, stream>>>(
        buf, w1, h, b1, Cap, Fc, Hc,
        (long)Cap * Hc, (long)Hc * Fc, (long)Cap * Fc, (long)Fc);

    // 10. expert GEMM2 + bias -> y (fp32, overwrites buf)
    gemm_kernel<__hip_bfloat16, float, 3><<<dim3(Hc / 128, Cap / 128, Ec), blk, 0, stream>>>(
        h, w2, y, b2, Cap, Hc, Fc,
        (long)Cap * Fc, (long)Fc * Hc, (long)Cap * Hc, (long)Hc);

    // 11. combine + final residual
    combine_kernel<<<Tc, dim3(128), 0, stream>>>(xa, y, ef, pos, gf, out);
}

// Round 3
// 590.547 us; speedup vs baseline: 4.8017x; 2.4063x over previous
//
#include <hip/hip_runtime.h>
#include <hip/hip_bf16.h>
#include <math.h>

// Problem constants (from reference setup_inputs)
constexpr int Bc  = 2;
constexpr int Sc  = 2048;
constexpr int Hc  = 512;
constexpr int NHc = 8;
constexpr int Tc  = Bc * Sc;      // 4096 tokens
constexpr int Ec  = 64;           // experts
constexpr int Fc  = 2048;         // ffn dim
constexpr int Cap = 256;          // capacity = 2 * T * 2 / E

typedef __attribute__((ext_vector_type(8))) short bf16x8;
typedef __attribute__((ext_vector_type(4))) float f32x4;

__device__ __forceinline__ unsigned short f2b(float f) {
    union { float f; unsigned u; } v; v.f = f;
    unsigned r = v.u + 0x7FFF + ((v.u >> 16) & 1);   // RTNE
    return (unsigned short)(r >> 16);
}

__device__ __forceinline__ float gelu_f(float x) {
    // jax.nn.gelu default approximate=True (tanh)
    float x3 = x * x * x;
    return 0.5f * x * (1.0f + tanhf(0.7978845608028654f * (x + 0.044715f * x3)));
}

// ---------------- LayerNorm: one block per row (H=512, 256 threads) ----------
template <typename TO>
__global__ __launch_bounds__(256) void ln_kernel(const float* __restrict__ x,
                                                 const float* __restrict__ g,
                                                 const float* __restrict__ b,
                                                 TO* __restrict__ o) {
    int t = blockIdx.x;
    const float* row = x + (size_t)t * Hc;
    int tid = threadIdx.x;
    float v0 = row[tid];
    float v1 = row[tid + 256];
    float s = v0 + v1, s2 = v0 * v0 + v1 * v1;
    for (int off = 32; off; off >>= 1) {
        s  += __shfl_down(s,  off);
        s2 += __shfl_down(s2, off);
    }
    __shared__ float ls[4], ls2[4];
    int wid = tid >> 6, lane = tid & 63;
    if (lane == 0) { ls[wid] = s; ls2[wid] = s2; }
    __syncthreads();
    if (tid == 0) {
        float a = 0.f, a2 = 0.f;
        for (int i = 0; i < 4; i++) { a += ls[i]; a2 += ls2[i]; }
        ls[0] = a; ls2[0] = a2;
    }
    __syncthreads();
    float mean = ls[0] * (1.0f / Hc);
    float var  = ls2[0] * (1.0f / Hc) - mean * mean;
    float r = rsqrtf(var + 1e-5f);
    float o0 = (v0 - mean) * r * g[tid]       + b[tid];
    float o1 = (v1 - mean) * r * g[tid + 256] + b[tid + 256];
    if constexpr (sizeof(TO) == 2) {
        o[(size_t)t * Hc + tid]       = (TO)f2b(o0);
        o[(size_t)t * Hc + tid + 256] = (TO)f2b(o1);
    } else {
        o[(size_t)t * Hc + tid]       = o0;
        o[(size_t)t * Hc + tid + 256] = o1;
    }
}

// ---------------- Transpose + fp32->bf16 convert -----------------------------
// out[c][r] = (bf16) in[r][c]; batched via blockIdx.z. 64x64 tiles.
__global__ __launch_bounds__(256) void transpose_conv_kernel(const float* __restrict__ in,
                                                             unsigned short* __restrict__ out,
                                                             int R, int Cn, long sIn, long sOut) {
    in  += (size_t)blockIdx.z * sIn;
    out += (size_t)blockIdx.z * sOut;
    int r0 = blockIdx.y * 64, c0 = blockIdx.x * 64;
    __shared__ float T[64][65];
    int tid = threadIdx.x;
    int row = tid >> 4, col4 = (tid & 15) * 4;
    #pragma unroll
    for (int p = 0; p < 4; p++) {
        float4 vv = *(const float4*)(in + (size_t)(r0 + p * 16 + row) * Cn + c0 + col4);
        T[p * 16 + row][col4 + 0] = vv.x;
        T[p * 16 + row][col4 + 1] = vv.y;
        T[p * 16 + row][col4 + 2] = vv.z;
        T[p * 16 + row][col4 + 3] = vv.w;
    }
    __syncthreads();
    int crow = tid >> 5, r2 = (tid & 31) * 2;
    #pragma unroll
    for (int p = 0; p < 8; p++) {
        int cc = p * 8 + crow;
        ushort2 o;
        o.x = f2b(T[r2 + 0][cc]);
        o.y = f2b(T[r2 + 1][cc]);
        *(ushort2*)(out + (size_t)(c0 + cc) * R + r0 + r2) = o;
    }
}

// ---------------- MFMA bf16 GEMM ---------------------------------------------
// C[M,N] = A[M,K] @ Wt[N,K]^T  (both bf16 row-major), batched via blockIdx.z.
// EPI: 0=none, 1=+X[m*N+n] (fp32), 2=gelu(acc+X[n]) -> bf16, 3=acc+X[n] -> fp32
// 128x128 tile, BK=64, 4 waves (2x2 of 64x64), LDS stride 72 (conflict-free).
template <int EPI, typename TC>
__global__ __launch_bounds__(256) void gemm_mfma(const unsigned short* __restrict__ A,
                                                 const unsigned short* __restrict__ Wt,
                                                 TC* __restrict__ C,
                                                 const float* __restrict__ X,
                                                 int M, int N, int K,
                                                 long sA, long sW, long sC, long sX) {
    int bz = blockIdx.z;
    A  += (size_t)bz * sA;
    Wt += (size_t)bz * sW;
    C  += (size_t)bz * sC;
    if (X) X += (size_t)bz * sX;
    int m0 = blockIdx.y * 128, n0 = blockIdx.x * 128;

    __shared__ unsigned short As[128 * 72];
    __shared__ unsigned short Bs[128 * 72];

    int tid = threadIdx.x;
    int wid = tid >> 6, lane = tid & 63;
    int wr = (wid >> 1) * 64, wc = (wid & 1) * 64;
    int lr = lane & 15, lg = lane >> 4;

    f32x4 acc[4][4];
    #pragma unroll
    for (int i = 0; i < 4; i++)
        #pragma unroll
        for (int j = 0; j < 4; j++) acc[i][j] = (f32x4){0.f, 0.f, 0.f, 0.f};

    for (int k0 = 0; k0 < K; k0 += 64) {
        #pragma unroll
        for (int p = 0; p < 4; p++) {
            int e = p * 2048 + tid * 8;
            int row = e >> 6, col = e & 63;
            *(bf16x8*)&As[row * 72 + col] =
                *(const bf16x8*)&A[(size_t)(m0 + row) * K + k0 + col];
            *(bf16x8*)&Bs[row * 72 + col] =
                *(const bf16x8*)&Wt[(size_t)(n0 + row) * K + k0 + col];
        }
        __syncthreads();
        #pragma unroll
        for (int kk = 0; kk < 64; kk += 32) {
            bf16x8 af[4], bfr[4];
            #pragma unroll
            for (int i = 0; i < 4; i++) {
                af[i]  = *(const bf16x8*)&As[(wr + i * 16 + lr) * 72 + kk + 8 * lg];
                bfr[i] = *(const bf16x8*)&Bs[(wc + i * 16 + lr) * 72 + kk + 8 * lg];
            }
            #pragma unroll
            for (int i = 0; i < 4; i++)
                #pragma unroll
                for (int j = 0; j < 4; j++)
                    acc[i][j] = __builtin_amdgcn_mfma_f32_16x16x32_bf16(af[i], bfr[j], acc[i][j], 0, 0, 0);
        }
        __syncthreads();
    }

    #pragma unroll
    for (int i = 0; i < 4; i++) {
        #pragma unroll
        for (int r = 0; r < 4; r++) {
            int m = m0 + wr + i * 16 + lg * 4 + r;
            #pragma unroll
            for (int j = 0; j < 4; j++) {
                int n = n0 + wc + j * 16 + lr;
                float vv = acc[i][j][r];
                if (EPI == 1) vv += X[(size_t)m * N + n];
                if (EPI == 2) { vv += X[n]; vv = gelu_f(vv); }
                if (EPI == 3) vv += X[n];
                if constexpr (sizeof(TC) == 2) C[(size_t)m * N + n] = (TC)f2b(vv);
                else                            C[(size_t)m * N + n] = vv;
            }
        }
    }
}

// ---------------- MFMA flash attention (bf16 in/out) -------------------------
// grid (S/64, NH, B), 256 threads = 4 waves; each wave owns 16 q-rows.
__global__ __launch_bounds__(256) void attn_mfma_kernel(const unsigned short* __restrict__ q,
                                                        const unsigned short* __restrict__ k,
                                                        const unsigned short* __restrict__ v,
                                                        unsigned short* __restrict__ o) {
    constexpr int LDK = 72;
    __shared__ unsigned short Ks[64 * LDK];       // [key][d]
    __shared__ unsigned short Vt[64 * LDK];       // [d][key]  (transposed)
    __shared__ unsigned short Ps[64 * LDK];       // per-wave [q][key]

    int qt = blockIdx.x, hh = blockIdx.y, b = blockIdx.z;
    int q0 = qt * 64;
    int tid = threadIdx.x;
    int wid = tid >> 6, lane = tid & 63;
    int lr = lane & 15;
    int lg = lane >> 4;

    bf16x8 qf[2];
    {
        const unsigned short* qrow = q + ((size_t)(b * Sc + q0 + wid * 16 + lr)) * Hc + hh * 64;
        qf[0] = *(const bf16x8*)&qrow[8 * lg];
        qf[1] = *(const bf16x8*)&qrow[32 + 8 * lg];
    }

    f32x4 Oacc[4];
    #pragma unroll
    for (int nb = 0; nb < 4; nb++) Oacc[nb] = (f32x4){0.f, 0.f, 0.f, 0.f};
    float mrun[4] = {-1e30f, -1e30f, -1e30f, -1e30f};
    float lrun[4] = {0.f, 0.f, 0.f, 0.f};
    const float scale = 0.125f;

    for (int kt = 0; kt < Sc / 64; kt++) {
        __syncthreads();
        // ---- stage K rows ----
        #pragma unroll
        for (int p = 0; p < 2; p++) {
            int e = p * 2048 + tid * 8;
            int row = e >> 6, col = e & 63;
            *(bf16x8*)&Ks[row * LDK + col] =
                *(const bf16x8*)&k[((size_t)(b * Sc + kt * 64 + row)) * Hc + hh * 64 + col];
        }
        // ---- stage V transposed (2 keys x 4 dims per item) ----
        #pragma unroll
        for (int p = 0; p < 2; p++) {
            int item = p * 256 + tid;
            int k2 = (item >> 4) * 2, d4 = (item & 15) * 4;
            const unsigned short* v0 = v + ((size_t)(b * Sc + kt * 64 + k2)) * Hc + hh * 64 + d4;
            ushort4 a = *(const ushort4*)v0;
            ushort4 bb = *(const ushort4*)(v0 + Hc);
            *(ushort2*)&Vt[(d4 + 0) * LDK + k2] = (ushort2){a.x, bb.x};
            *(ushort2*)&Vt[(d4 + 1) * LDK + k2] = (ushort2){a.y, bb.y};
            *(ushort2*)&Vt[(d4 + 2) * LDK + k2] = (ushort2){a.z, bb.z};
            *(ushort2*)&Vt[(d4 + 3) * LDK + k2] = (ushort2){a.w, bb.w};
        }
        __syncthreads();

        // ---- S = Q K^T (scaled) ----
        f32x4 sacc[4];
        #pragma unroll
        for (int kb = 0; kb < 4; kb++) sacc[kb] = (f32x4){0.f, 0.f, 0.f, 0.f};
        #pragma unroll
        for (int kb = 0; kb < 4; kb++) {
            #pragma unroll
            for (int s = 0; s < 2; s++) {
                bf16x8 kf = *(const bf16x8*)&Ks[(kb * 16 + lr) * LDK + 32 * s + 8 * lg];
                sacc[kb] = __builtin_amdgcn_mfma_f32_16x16x32_bf16(qf[s], kf, sacc[kb], 0, 0, 0);
            }
        }

        // ---- online softmax ----
        float sc_[4];
        #pragma unroll
        for (int r = 0; r < 4; r++) {
            float mt = -1e30f;
            #pragma unroll
            for (int kb = 0; kb < 4; kb++) {
                float z = sacc[kb][r] * scale;
                sacc[kb][r] = z;
                mt = fmaxf(mt, z);
            }
            mt = fmaxf(mt, __shfl_xor(mt, 1));
            mt = fmaxf(mt, __shfl_xor(mt, 2));
            mt = fmaxf(mt, __shfl_xor(mt, 4));
            mt = fmaxf(mt, __shfl_xor(mt, 8));
            float mnew = fmaxf(mrun[r], mt);
            float sc = expf(mrun[r] - mnew);
            float ps = 0.f;
            #pragma unroll
            for (int kb = 0; kb < 4; kb++) {
                float p = expf(sacc[kb][r] - mnew);
                ps += p;
                Ps[(wid * 16 + lg * 4 + r) * LDK + kb * 16 + lr] = f2b(p);
            }
            ps += __shfl_xor(ps, 1);
            ps += __shfl_xor(ps, 2);
            ps += __shfl_xor(ps, 4);
            ps += __shfl_xor(ps, 8);
            lrun[r] = lrun[r] * sc + ps;
            mrun[r] = mnew;
            sc_[r] = sc;
        }
        __syncthreads();

        // ---- O = O*sc + P V ----
        #pragma unroll
        for (int nb = 0; nb < 4; nb++) {
            f32x4 oa = Oacc[nb];
            #pragma unroll
            for (int r = 0; r < 4; r++) oa[r] *= sc_[r];
            #pragma unroll
            for (int s = 0; s < 2; s++) {
                bf16x8 pf = *(const bf16x8*)&Ps[(wid * 16 + lr) * LDK + 32 * s + 8 * lg];
                bf16x8 vf = *(const bf16x8*)&Vt[(nb * 16 + lr) * LDK + 32 * s + 8 * lg];
                oa = __builtin_amdgcn_mfma_f32_16x16x32_bf16(pf, vf, oa, 0, 0, 0);
            }
            Oacc[nb] = oa;
        }
    }

    unsigned short* ob = o + ((size_t)(b * Sc + q0 + wid * 16)) * Hc + hh * 64;
    #pragma unroll
    for (int r = 0; r < 4; r++) {
        float inv = 1.0f / lrun[r];
        int qq = lg * 4 + r;
        #pragma unroll
        for (int nb = 0; nb < 4; nb++) {
            ob[(size_t)qq * Hc + nb * 16 + lr] = f2b(Oacc[nb][r] * inv);
        }
    }
}

// ---------------- Router GEMM + softmax + top-2 ------------------------------
__global__ __launch_bounds__(256) void router_top2_kernel(const float* __restrict__ x2,
                                                          const float* __restrict__ wr,
                                                          int* __restrict__ ef,
                                                          float* __restrict__ gf) {
    int t = blockIdx.x * 4 + (threadIdx.x >> 6);
    int l = threadIdx.x & 63;
    const float* xr = x2 + (size_t)t * Hc;
    float acc = 0.f;
    for (int hhh = 0; hhh < Hc; hhh++) acc += xr[hhh] * wr[hhh * Ec + l];

    float mx = acc;
    for (int off = 32; off; off >>= 1) mx = fmaxf(mx, __shfl_xor(mx, off));
    float p = expf(acc - mx);
    float sum = p;
    for (int off = 32; off; off >>= 1) sum += __shfl_xor(sum, off);
    p /= sum;

    float v1 = p; int i1 = l;
    for (int off = 32; off; off >>= 1) {
        float ov = __shfl_xor(v1, off);
        int   oi = __shfl_xor(i1, off);
        if (ov > v1 || (ov == v1 && oi < i1)) { v1 = ov; i1 = oi; }
    }
    float v2 = (l == i1) ? -INFINITY : p; int i2 = l;
    for (int off = 32; off; off >>= 1) {
        float ov = __shfl_xor(v2, off);
        int   oi = __shfl_xor(i2, off);
        if (ov > v2 || (ov == v2 && oi < i2)) { v2 = ov; i2 = oi; }
    }
    if (l == 0) {
        float inv = 1.0f / (v1 + v2);
        ef[t * 2]     = i1;
        ef[t * 2 + 1] = i2;
        gf[t * 2]     = v1 * inv;
        gf[t * 2 + 1] = v2 * inv;
    }
}

// ---------------- pos: rank of each slot within its expert (slot order) ------
__global__ __launch_bounds__(256) void pos_kernel(const int* __restrict__ ef,
                                                  int* __restrict__ pos) {
    int e = blockIdx.x;
    __shared__ int cnts[257];
    int tid = threadIdx.x;
    int base = tid * 32;  // 8192 / 256
    int c = 0;
    for (int i = 0; i < 32; i++) c += (ef[base + i] == e) ? 1 : 0;
    cnts[tid + 1] = c;
    if (tid == 0) cnts[0] = 0;
    __syncthreads();
    if (tid == 0) {
        for (int i = 1; i <= 256; i++) cnts[i] += cnts[i - 1];
    }
    __syncthreads();
    int run = cnts[tid];
    for (int i = 0; i < 32; i++) {
        if (ef[base + i] == e) pos[base + i] = run++;
    }
}

// ---------------- dispatch: copy kept tokens into expert buffers (bf16) ------
__global__ __launch_bounds__(128) void dispatch_kernel(const float* __restrict__ x2,
                                                       const int* __restrict__ ef,
                                                       const int* __restrict__ pos,
                                                       unsigned short* __restrict__ buf) {
    int s = blockIdx.x;
    int p = pos[s];
    if (p >= Cap) return;
    int e = ef[s];
    int t = s >> 1;
    float4 vv = ((const float4*)(x2 + (size_t)t * Hc))[threadIdx.x];
    ushort4 o;
    o.x = f2b(vv.x); o.y = f2b(vv.y); o.z = f2b(vv.z); o.w = f2b(vv.w);
    ((ushort4*)(buf + ((size_t)e * Cap + p) * Hc))[threadIdx.x] = o;
}

// ---------------- combine: out = xa + sum_k gate * y[ef,pos] -----------------
__global__ __launch_bounds__(128) void combine_kernel(const float* __restrict__ xa,
                                                      const float* __restrict__ y,
                                                      const int* __restrict__ ef,
                                                      const int* __restrict__ pos,
                                                      const float* __restrict__ gf,
                                                      float* __restrict__ out) {
    int t = blockIdx.x;
    int d = threadIdx.x;
    float4 acc = ((const float4*)(xa + (size_t)t * Hc))[d];
    #pragma unroll
    for (int kk = 0; kk < 2; kk++) {
        int s = t * 2 + kk;
        int p = pos[s];
        if (p < Cap) {
            float w = gf[s];
            float4 yv = ((const float4*)(y + ((size_t)ef[s] * Cap + p) * Hc))[d];
            acc.x += w * yv.x;
            acc.y += w * yv.y;
            acc.z += w * yv.z;
            acc.w += w * yv.w;
        }
    }
    ((float4*)(out + (size_t)t * Hc))[d] = acc;
}

// ---------------- launch -----------------------------------------------------
extern "C" void kernel_launch(void* const* d_in, const int* in_sizes, int n_in,
                              void* d_out, int out_size, void* d_ws, size_t ws_size,
                              hipStream_t stream) {
    const float* x     = (const float*)d_in[0];
    const float* ln1_g = (const float*)d_in[1];
    const float* ln1_b = (const float*)d_in[2];
    const float* wq    = (const float*)d_in[3];
    const float* wk    = (const float*)d_in[4];
    const float* wv    = (const float*)d_in[5];
    const float* wo    = (const float*)d_in[6];
    const float* ln2_g = (const float*)d_in[7];
    const float* ln2_b = (const float*)d_in[8];
    const float* wr    = (const float*)d_in[9];
    const float* w1    = (const float*)d_in[10];
    const float* b1    = (const float*)d_in[11];
    const float* w2    = (const float*)d_in[12];
    const float* b2    = (const float*)d_in[13];
    float* out = (float*)d_out;

    const size_t TH   = (size_t)Tc * Hc;        // 2,097,152
    const size_t ECH  = (size_t)Ec * Cap * Hc;  // 8,388,608
    const size_t HHs  = (size_t)Hc * Hc;        // 262,144
    const size_t HF   = (size_t)Hc * Fc;        // 1,048,576  (per-expert w size)
    const size_t halfE = 32;

    // ---- workspace carve (bytes, lifetimes overlap-checked) ----
    char* wsb = (char*)d_ws;
    size_t off = 0;
    auto alloc = [&](size_t bytes) { size_t r = off; off = (off + bytes + 255) & ~(size_t)255; return r; };
    size_t qb_off   = alloc(TH * 2);                 // bf16 q
    size_t kb_off   = alloc(TH * 2);                 // bf16 k
    size_t buf_off  = alloc(ECH * 2);                // bf16 expert inputs
    size_t vb_off   = alloc(TH * 2);                 // bf16 v   } x2 (fp32) overlays
    size_t x1b_off  = alloc(TH * 2);                 // bf16 x1/attn } these 8 MB
    size_t xa_off   = alloc(TH * 4);                 // fp32 attn residual out
    size_t ef_off   = alloc((size_t)Tc * 2 * 4);
    size_t pos_off  = alloc((size_t)Tc * 2 * 4);
    size_t gf_off   = alloc((size_t)Tc * 2 * 4);
    size_t h_off    = alloc(halfE * Cap * Fc * 2);   // bf16 h (half experts)
    size_t wta_off  = alloc(halfE * HF * 2);         // bf16 w1^T half
    size_t wtb_off  = alloc(halfE * HF * 2);         // bf16 w2^T half
    size_t wqt_off  = alloc(HHs * 2);
    size_t wkt_off  = alloc(HHs * 2);
    size_t wvt_off  = alloc(HHs * 2);
    size_t wot_off  = alloc(HHs * 2);
    if (ws_size < off) return;  // insufficient workspace

    unsigned short* qb   = (unsigned short*)(wsb + qb_off);
    unsigned short* kb   = (unsigned short*)(wsb + kb_off);
    unsigned short* vb   = (unsigned short*)(wsb + vb_off);
    unsigned short* x1b  = (unsigned short*)(wsb + x1b_off);   // also attnb
    unsigned short* bufb = (unsigned short*)(wsb + buf_off);
    float* x2  = (float*)(wsb + vb_off);    // overlays vb+x1b (dead by then)
    float* xa  = (float*)(wsb + xa_off);
    int*   ef  = (int*)(wsb + ef_off);
    int*   pos = (int*)(wsb + pos_off);
    float* gf  = (float*)(wsb + gf_off);
    unsigned short* h    = (unsigned short*)(wsb + h_off);
    unsigned short* wta  = (unsigned short*)(wsb + wta_off);
    unsigned short* wtb  = (unsigned short*)(wsb + wtb_off);
    unsigned short* wqt  = (unsigned short*)(wsb + wqt_off);
    unsigned short* wkt  = (unsigned short*)(wsb + wkt_off);
    unsigned short* wvt  = (unsigned short*)(wsb + wvt_off);
    unsigned short* wot  = (unsigned short*)(wsb + wot_off);
    float* y = (float*)wsb;                 // fp32 [E][Cap][H] overlays [0,32MB)

    dim3 blk(256);

    // 0. transpose attention weights -> bf16 W^T
    transpose_conv_kernel<<<dim3(8, 8, 1), blk, 0, stream>>>(wq, wqt, Hc, Hc, 0, 0);
    transpose_conv_kernel<<<dim3(8, 8, 1), blk, 0, stream>>>(wk, wkt, Hc, Hc, 0, 0);
    transpose_conv_kernel<<<dim3(8, 8, 1), blk, 0, stream>>>(wv, wvt, Hc, Hc, 0, 0);
    transpose_conv_kernel<<<dim3(8, 8, 1), blk, 0, stream>>>(wo, wot, Hc, Hc, 0, 0);

    // 1. LN1 -> bf16
    ln_kernel<unsigned short><<<Tc, blk, 0, stream>>>(x, ln1_g, ln1_b, x1b);

    // 2. QKV projections (bf16 out)
    gemm_mfma<0, unsigned short><<<dim3(Hc / 128, Tc / 128, 1), blk, 0, stream>>>(
        x1b, wqt, qb, nullptr, Tc, Hc, Hc, 0, 0, 0, 0);
    gemm_mfma<0, unsigned short><<<dim3(Hc / 128, Tc / 128, 1), blk, 0, stream>>>(
        x1b, wkt, kb, nullptr, Tc, Hc, Hc, 0, 0, 0, 0);
    gemm_mfma<0, unsigned short><<<dim3(Hc / 128, Tc / 128, 1), blk, 0, stream>>>(
        x1b, wvt, vb, nullptr, Tc, Hc, Hc, 0, 0, 0, 0);

    // 3. attention -> bf16 attnb (reuses x1b)
    attn_mfma_kernel<<<dim3(Sc / 64, NHc, Bc), blk, 0, stream>>>(qb, kb, vb, x1b);

    // 4. output projection + residual: xa = attn @ wo + x
    gemm_mfma<1, float><<<dim3(Hc / 128, Tc / 128, 1), blk, 0, stream>>>(
        x1b, wot, xa, x, Tc, Hc, Hc, 0, 0, 0, 0);

    // 5. LN2 -> fp32 (router needs exact-ish values for top-k)
    ln_kernel<float><<<Tc, blk, 0, stream>>>(xa, ln2_g, ln2_b, x2);

    // 6. router + top2
    router_top2_kernel<<<Tc / 4, blk, 0, stream>>>(x2, wr, ef, gf);

    // 7. positions within expert queues
    pos_kernel<<<Ec, blk, 0, stream>>>(ef, pos);

    // 8. dispatch tokens to expert buffers (bf16)
    dispatch_kernel<<<Tc * 2, dim3(128), 0, stream>>>(x2, ef, pos, bufb);

    // 9. MoE in two expert halves (keeps h + w^T in 128+32 MB)
    for (int half = 0; half < 2; half++) {
        long eo = (long)half * halfE;
        // transpose+convert w1[half]: [32][H][F] -> [32][F][H]
        transpose_conv_kernel<<<dim3(Fc / 64, Hc / 64, halfE), blk, 0, stream>>>(
            w1 + eo * HF, wta, Hc, Fc, HF, HF);
        // GEMM1: h = gelu(buf @ w1 + b1)   (bf16 out)
        gemm_mfma<2, unsigned short><<<dim3(Fc / 128, Cap / 128, halfE), blk, 0, stream>>>(
            bufb + eo * Cap * Hc, wta, h, b1 + eo * Fc,
            Cap, Fc, Hc, (long)Cap * Hc, (long)HF, (long)Cap * Fc, (long)Fc);
        // transpose+convert w2[half]: [32][F][H] -> [32][H][F]
        transpose_conv_kernel<<<dim3(Hc / 64, Fc / 64, halfE), blk, 0, stream>>>(
            w2 + eo * HF, wtb, Fc, Hc, HF, HF);
        // GEMM2: y = h @ w2 + b2   (fp32 out)
        gemm_mfma<3, float><<<dim3(Hc / 128, Cap / 128, halfE), blk, 0, stream>>>(
            h, wtb, y + eo * Cap * Hc, b2 + eo * Hc,
            Cap, Hc, Fc, (long)Cap * Fc, (long)HF, (long)Cap * Hc, (long)Hc);
    }

    // 10. combine + final residual
    combine_kernel<<<Tc, dim3(128), 0, stream>>>(xa, y, ef, pos, gf, out);
}

// Round 4
// 445.477 us; speedup vs baseline: 6.3653x; 1.3257x over previous
//
#include <hip/hip_runtime.h>
#include <hip/hip_bf16.h>
#include <math.h>

// Problem constants (from reference setup_inputs)
constexpr int Bc  = 2;
constexpr int Sc  = 2048;
constexpr int Hc  = 512;
constexpr int NHc = 8;
constexpr int Tc  = Bc * Sc;      // 4096 tokens
constexpr int Ec  = 64;           // experts
constexpr int Fc  = 2048;         // ffn dim
constexpr int Cap = 256;          // capacity = 2 * T * 2 / E

typedef __attribute__((ext_vector_type(8))) short bf16x8;
typedef __attribute__((ext_vector_type(4))) float f32x4;

__device__ __forceinline__ unsigned short f2b(float f) {
    union { float f; unsigned u; } v; v.f = f;
    unsigned r = v.u + 0x7FFF + ((v.u >> 16) & 1);   // RTNE
    return (unsigned short)(r >> 16);
}

__device__ __forceinline__ float gelu_f(float x) {
    // jax.nn.gelu default approximate=True (tanh)
    float x3 = x * x * x;
    return 0.5f * x * (1.0f + tanhf(0.7978845608028654f * (x + 0.044715f * x3)));
}

// ---------------- LayerNorm: one block per row (H=512, 256 threads) ----------
template <typename TO>
__global__ __launch_bounds__(256) void ln_kernel(const float* __restrict__ x,
                                                 const float* __restrict__ g,
                                                 const float* __restrict__ b,
                                                 TO* __restrict__ o) {
    int t = blockIdx.x;
    const float* row = x + (size_t)t * Hc;
    int tid = threadIdx.x;
    float v0 = row[tid];
    float v1 = row[tid + 256];
    float s = v0 + v1, s2 = v0 * v0 + v1 * v1;
    for (int off = 32; off; off >>= 1) {
        s  += __shfl_down(s,  off);
        s2 += __shfl_down(s2, off);
    }
    __shared__ float ls[4], ls2[4];
    int wid = tid >> 6, lane = tid & 63;
    if (lane == 0) { ls[wid] = s; ls2[wid] = s2; }
    __syncthreads();
    if (tid == 0) {
        float a = 0.f, a2 = 0.f;
        for (int i = 0; i < 4; i++) { a += ls[i]; a2 += ls2[i]; }
        ls[0] = a; ls2[0] = a2;
    }
    __syncthreads();
    float mean = ls[0] * (1.0f / Hc);
    float var  = ls2[0] * (1.0f / Hc) - mean * mean;
    float r = rsqrtf(var + 1e-5f);
    float o0 = (v0 - mean) * r * g[tid]       + b[tid];
    float o1 = (v1 - mean) * r * g[tid + 256] + b[tid + 256];
    if constexpr (sizeof(TO) == 2) {
        o[(size_t)t * Hc + tid]       = (TO)f2b(o0);
        o[(size_t)t * Hc + tid + 256] = (TO)f2b(o1);
    } else {
        o[(size_t)t * Hc + tid]       = o0;
        o[(size_t)t * Hc + tid + 256] = o1;
    }
}

// ---------------- MFMA bf16 GEMM with in-LDS weight transpose ---------------
// C[M,N] = A[M,K](bf16) @ W[K,N](fp32 row-major), batched via blockIdx.z.
// W is converted fp32->bf16 and transposed into LDS during staging.
// Bs swizzle: element (n,k) stored at Bs[n*72 + (k ^ 8*((n>>3)&7))] -- keeps
// ds_read_b128 aligned/unpermuted (k-base mult of 8) and spreads the
// transposed ushort2 writes across banks (~4-way instead of 16-way).
// EPI: 0=none, 1=+X[m*N+n] (fp32), 2=gelu(acc+X[n]) -> bf16, 3=acc+X[n] -> fp32
// BM in {128 (4 waves, 256 thr), 256 (8 waves, 512 thr)}; BN=128, BK=64.
template <int BM, int EPI, typename TC>
__global__ __launch_bounds__(BM * 2) void gemm_mfma(const unsigned short* __restrict__ A,
                                                    const float* __restrict__ W,
                                                    TC* __restrict__ C,
                                                    const float* __restrict__ X,
                                                    int M, int N, int K,
                                                    long sA, long sW, long sC, long sX) {
    int bz = blockIdx.z;
    A += (size_t)bz * sA;
    W += (size_t)bz * sW;
    C += (size_t)bz * sC;
    if (X) X += (size_t)bz * sX;
    int m0 = blockIdx.y * BM, n0 = blockIdx.x * 128;

    __shared__ unsigned short As[BM * 72];
    __shared__ unsigned short Bs[128 * 72];

    int tid = threadIdx.x;
    int wid = tid >> 6, lane = tid & 63;
    int wr = (wid >> 1) * 64, wc = (wid & 1) * 64;
    int lr = lane & 15, lg = lane >> 4;

    f32x4 acc[4][4];
    #pragma unroll
    for (int i = 0; i < 4; i++)
        #pragma unroll
        for (int j = 0; j < 4; j++) acc[i][j] = (f32x4){0.f, 0.f, 0.f, 0.f};

    for (int k0 = 0; k0 < K; k0 += 64) {
        // ---- stage A rows (bf16, vector) ----
        #pragma unroll
        for (int p = 0; p < 4; p++) {
            int e = p * 16 * BM + tid * 8;
            int row = e >> 6, col = e & 63;
            *(bf16x8*)&As[row * 72 + col] =
                *(const bf16x8*)&A[(size_t)(m0 + row) * K + k0 + col];
        }
        // ---- stage W tile [64][128] fp32 -> Bs[n][k] bf16 (transposed) ----
        #pragma unroll
        for (int p = 0; p < 512 / BM; p++) {
            int kp = (tid >> 5) + p * (BM / 16);   // k-pair 0..31
            int c  = (tid & 31) * 4;               // col base 0..124
            const float* w0 = &W[(size_t)(k0 + 2 * kp) * N + n0 + c];
            float4 a = *(const float4*)w0;
            float4 b = *(const float4*)(w0 + N);
            int q = 8 * ((c >> 3) & 7);            // uniform over c..c+3
            int kof = (2 * kp) ^ q;
            *(ushort2*)&Bs[(c + 0) * 72 + kof] = (ushort2){f2b(a.x), f2b(b.x)};
            *(ushort2*)&Bs[(c + 1) * 72 + kof] = (ushort2){f2b(a.y), f2b(b.y)};
            *(ushort2*)&Bs[(c + 2) * 72 + kof] = (ushort2){f2b(a.z), f2b(b.z)};
            *(ushort2*)&Bs[(c + 3) * 72 + kof] = (ushort2){f2b(a.w), f2b(b.w)};
        }
        __syncthreads();
        #pragma unroll
        for (int kk = 0; kk < 64; kk += 32) {
            bf16x8 af[4], bfr[4];
            #pragma unroll
            for (int i = 0; i < 4; i++) {
                af[i] = *(const bf16x8*)&As[(wr + i * 16 + lr) * 72 + kk + 8 * lg];
                int nrow = wc + i * 16 + lr;
                int qq = 8 * ((nrow >> 3) & 7);
                bfr[i] = *(const bf16x8*)&Bs[nrow * 72 + ((kk + 8 * lg) ^ qq)];
            }
            #pragma unroll
            for (int i = 0; i < 4; i++)
                #pragma unroll
                for (int j = 0; j < 4; j++)
                    acc[i][j] = __builtin_amdgcn_mfma_f32_16x16x32_bf16(af[i], bfr[j], acc[i][j], 0, 0, 0);
        }
        __syncthreads();
    }

    #pragma unroll
    for (int i = 0; i < 4; i++) {
        #pragma unroll
        for (int r = 0; r < 4; r++) {
            int m = m0 + wr + i * 16 + lg * 4 + r;
            #pragma unroll
            for (int j = 0; j < 4; j++) {
                int n = n0 + wc + j * 16 + lr;
                float vv = acc[i][j][r];
                if (EPI == 1) vv += X[(size_t)m * N + n];
                if (EPI == 2) { vv += X[n]; vv = gelu_f(vv); }
                if (EPI == 3) vv += X[n];
                if constexpr (sizeof(TC) == 2) C[(size_t)m * N + n] = (TC)f2b(vv);
                else                            C[(size_t)m * N + n] = vv;
            }
        }
    }
}

// ---------------- MFMA flash attention (bf16 in/out) -------------------------
// grid (S/64, NH, B), 256 threads = 4 waves; each wave owns 16 q-rows.
__global__ __launch_bounds__(256) void attn_mfma_kernel(const unsigned short* __restrict__ q,
                                                        const unsigned short* __restrict__ k,
                                                        const unsigned short* __restrict__ v,
                                                        unsigned short* __restrict__ o) {
    constexpr int LDK = 72;
    __shared__ unsigned short Ks[64 * LDK];       // [key][d]
    __shared__ unsigned short Vt[64 * LDK];       // [d][key]  (transposed)
    __shared__ unsigned short Ps[64 * LDK];       // per-wave [q][key]

    int qt = blockIdx.x, hh = blockIdx.y, b = blockIdx.z;
    int q0 = qt * 64;
    int tid = threadIdx.x;
    int wid = tid >> 6, lane = tid & 63;
    int lr = lane & 15;
    int lg = lane >> 4;

    bf16x8 qf[2];
    {
        const unsigned short* qrow = q + ((size_t)(b * Sc + q0 + wid * 16 + lr)) * Hc + hh * 64;
        qf[0] = *(const bf16x8*)&qrow[8 * lg];
        qf[1] = *(const bf16x8*)&qrow[32 + 8 * lg];
    }

    f32x4 Oacc[4];
    #pragma unroll
    for (int nb = 0; nb < 4; nb++) Oacc[nb] = (f32x4){0.f, 0.f, 0.f, 0.f};
    float mrun[4] = {-1e30f, -1e30f, -1e30f, -1e30f};
    float lrun[4] = {0.f, 0.f, 0.f, 0.f};
    const float scale = 0.125f;

    for (int kt = 0; kt < Sc / 64; kt++) {
        __syncthreads();
        // ---- stage K rows ----
        #pragma unroll
        for (int p = 0; p < 2; p++) {
            int e = p * 2048 + tid * 8;
            int row = e >> 6, col = e & 63;
            *(bf16x8*)&Ks[row * LDK + col] =
                *(const bf16x8*)&k[((size_t)(b * Sc + kt * 64 + row)) * Hc + hh * 64 + col];
        }
        // ---- stage V transposed (2 keys x 4 dims per item) ----
        #pragma unroll
        for (int p = 0; p < 2; p++) {
            int item = p * 256 + tid;
            int k2 = (item >> 4) * 2, d4 = (item & 15) * 4;
            const unsigned short* v0 = v + ((size_t)(b * Sc + kt * 64 + k2)) * Hc + hh * 64 + d4;
            ushort4 a = *(const ushort4*)v0;
            ushort4 bb = *(const ushort4*)(v0 + Hc);
            *(ushort2*)&Vt[(d4 + 0) * LDK + k2] = (ushort2){a.x, bb.x};
            *(ushort2*)&Vt[(d4 + 1) * LDK + k2] = (ushort2){a.y, bb.y};
            *(ushort2*)&Vt[(d4 + 2) * LDK + k2] = (ushort2){a.z, bb.z};
            *(ushort2*)&Vt[(d4 + 3) * LDK + k2] = (ushort2){a.w, bb.w};
        }
        __syncthreads();

        // ---- S = Q K^T (scaled) ----
        f32x4 sacc[4];
        #pragma unroll
        for (int kb = 0; kb < 4; kb++) sacc[kb] = (f32x4){0.f, 0.f, 0.f, 0.f};
        #pragma unroll
        for (int kb = 0; kb < 4; kb++) {
            #pragma unroll
            for (int s = 0; s < 2; s++) {
                bf16x8 kf = *(const bf16x8*)&Ks[(kb * 16 + lr) * LDK + 32 * s + 8 * lg];
                sacc[kb] = __builtin_amdgcn_mfma_f32_16x16x32_bf16(qf[s], kf, sacc[kb], 0, 0, 0);
            }
        }

        // ---- online softmax ----
        float sc_[4];
        #pragma unroll
        for (int r = 0; r < 4; r++) {
            float mt = -1e30f;
            #pragma unroll
            for (int kb = 0; kb < 4; kb++) {
                float z = sacc[kb][r] * scale;
                sacc[kb][r] = z;
                mt = fmaxf(mt, z);
            }
            mt = fmaxf(mt, __shfl_xor(mt, 1));
            mt = fmaxf(mt, __shfl_xor(mt, 2));
            mt = fmaxf(mt, __shfl_xor(mt, 4));
            mt = fmaxf(mt, __shfl_xor(mt, 8));
            float mnew = fmaxf(mrun[r], mt);
            float sc = expf(mrun[r] - mnew);
            float ps = 0.f;
            #pragma unroll
            for (int kb = 0; kb < 4; kb++) {
                float p = expf(sacc[kb][r] - mnew);
                ps += p;
                Ps[(wid * 16 + lg * 4 + r) * LDK + kb * 16 + lr] = f2b(p);
            }
            ps += __shfl_xor(ps, 1);
            ps += __shfl_xor(ps, 2);
            ps += __shfl_xor(ps, 4);
            ps += __shfl_xor(ps, 8);
            lrun[r] = lrun[r] * sc + ps;
            mrun[r] = mnew;
            sc_[r] = sc;
        }
        __syncthreads();

        // ---- O = O*sc + P V ----
        #pragma unroll
        for (int nb = 0; nb < 4; nb++) {
            f32x4 oa = Oacc[nb];
            #pragma unroll
            for (int r = 0; r < 4; r++) oa[r] *= sc_[r];
            #pragma unroll
            for (int s = 0; s < 2; s++) {
                bf16x8 pf = *(const bf16x8*)&Ps[(wid * 16 + lr) * LDK + 32 * s + 8 * lg];
                bf16x8 vf = *(const bf16x8*)&Vt[(nb * 16 + lr) * LDK + 32 * s + 8 * lg];
                oa = __builtin_amdgcn_mfma_f32_16x16x32_bf16(pf, vf, oa, 0, 0, 0);
            }
            Oacc[nb] = oa;
        }
    }

    unsigned short* ob = o + ((size_t)(b * Sc + q0 + wid * 16)) * Hc + hh * 64;
    #pragma unroll
    for (int r = 0; r < 4; r++) {
        float inv = 1.0f / lrun[r];
        int qq = lg * 4 + r;
        #pragma unroll
        for (int nb = 0; nb < 4; nb++) {
            ob[(size_t)qq * Hc + nb * 16 + lr] = f2b(Oacc[nb][r] * inv);
        }
    }
}

// ---------------- Router GEMM + softmax + top-2 ------------------------------
__global__ __launch_bounds__(256) void router_top2_kernel(const float* __restrict__ x2,
                                                          const float* __restrict__ wr,
                                                          int* __restrict__ ef,
                                                          float* __restrict__ gf) {
    int t = blockIdx.x * 4 + (threadIdx.x >> 6);
    int l = threadIdx.x & 63;
    const float* xr = x2 + (size_t)t * Hc;
    float acc = 0.f;
    for (int hhh = 0; hhh < Hc; hhh++) acc += xr[hhh] * wr[hhh * Ec + l];

    float mx = acc;
    for (int off = 32; off; off >>= 1) mx = fmaxf(mx, __shfl_xor(mx, off));
    float p = expf(acc - mx);
    float sum = p;
    for (int off = 32; off; off >>= 1) sum += __shfl_xor(sum, off);
    p /= sum;

    float v1 = p; int i1 = l;
    for (int off = 32; off; off >>= 1) {
        float ov = __shfl_xor(v1, off);
        int   oi = __shfl_xor(i1, off);
        if (ov > v1 || (ov == v1 && oi < i1)) { v1 = ov; i1 = oi; }
    }
    float v2 = (l == i1) ? -INFINITY : p; int i2 = l;
    for (int off = 32; off; off >>= 1) {
        float ov = __shfl_xor(v2, off);
        int   oi = __shfl_xor(i2, off);
        if (ov > v2 || (ov == v2 && oi < i2)) { v2 = ov; i2 = oi; }
    }
    if (l == 0) {
        float inv = 1.0f / (v1 + v2);
        ef[t * 2]     = i1;
        ef[t * 2 + 1] = i2;
        gf[t * 2]     = v1 * inv;
        gf[t * 2 + 1] = v2 * inv;
    }
}

// ---------------- pos: rank of each slot within its expert (slot order) ------
__global__ __launch_bounds__(256) void pos_kernel(const int* __restrict__ ef,
                                                  int* __restrict__ pos) {
    int e = blockIdx.x;
    __shared__ int cnts[257];
    int tid = threadIdx.x;
    int base = tid * 32;  // 8192 / 256
    int c = 0;
    for (int i = 0; i < 32; i++) c += (ef[base + i] == e) ? 1 : 0;
    cnts[tid + 1] = c;
    if (tid == 0) cnts[0] = 0;
    __syncthreads();
    if (tid == 0) {
        for (int i = 1; i <= 256; i++) cnts[i] += cnts[i - 1];
    }
    __syncthreads();
    int run = cnts[tid];
    for (int i = 0; i < 32; i++) {
        if (ef[base + i] == e) pos[base + i] = run++;
    }
}

// ---------------- dispatch: copy kept tokens into expert buffers (bf16) ------
__global__ __launch_bounds__(128) void dispatch_kernel(const float* __restrict__ x2,
                                                       const int* __restrict__ ef,
                                                       const int* __restrict__ pos,
                                                       unsigned short* __restrict__ buf) {
    int s = blockIdx.x;
    int p = pos[s];
    if (p >= Cap) return;
    int e = ef[s];
    int t = s >> 1;
    float4 vv = ((const float4*)(x2 + (size_t)t * Hc))[threadIdx.x];
    ushort4 o;
    o.x = f2b(vv.x); o.y = f2b(vv.y); o.z = f2b(vv.z); o.w = f2b(vv.w);
    ((ushort4*)(buf + ((size_t)e * Cap + p) * Hc))[threadIdx.x] = o;
}

// ---------------- combine: out = xa + sum_k gate * y[ef,pos] -----------------
__global__ __launch_bounds__(128) void combine_kernel(const float* __restrict__ xa,
                                                      const float* __restrict__ y,
                                                      const int* __restrict__ ef,
                                                      const int* __restrict__ pos,
                                                      const float* __restrict__ gf,
                                                      float* __restrict__ out) {
    int t = blockIdx.x;
    int d = threadIdx.x;
    float4 acc = ((const float4*)(xa + (size_t)t * Hc))[d];
    #pragma unroll
    for (int kk = 0; kk < 2; kk++) {
        int s = t * 2 + kk;
        int p = pos[s];
        if (p < Cap) {
            float w = gf[s];
            float4 yv = ((const float4*)(y + ((size_t)ef[s] * Cap + p) * Hc))[d];
            acc.x += w * yv.x;
            acc.y += w * yv.y;
            acc.z += w * yv.z;
            acc.w += w * yv.w;
        }
    }
    ((float4*)(out + (size_t)t * Hc))[d] = acc;
}

// ---------------- launch -----------------------------------------------------
extern "C" void kernel_launch(void* const* d_in, const int* in_sizes, int n_in,
                              void* d_out, int out_size, void* d_ws, size_t ws_size,
                              hipStream_t stream) {
    const float* x     = (const float*)d_in[0];
    const float* ln1_g = (const float*)d_in[1];
    const float* ln1_b = (const float*)d_in[2];
    const float* wq    = (const float*)d_in[3];
    const float* wk    = (const float*)d_in[4];
    const float* wv    = (const float*)d_in[5];
    const float* wo    = (const float*)d_in[6];
    const float* ln2_g = (const float*)d_in[7];
    const float* ln2_b = (const float*)d_in[8];
    const float* wr    = (const float*)d_in[9];
    const float* w1    = (const float*)d_in[10];
    const float* b1    = (const float*)d_in[11];
    const float* w2    = (const float*)d_in[12];
    const float* b2    = (const float*)d_in[13];
    float* out = (float*)d_out;

    const size_t TH   = (size_t)Tc * Hc;        // 2,097,152
    const size_t ECH  = (size_t)Ec * Cap * Hc;  // 8,388,608
    const size_t ECF  = (size_t)Ec * Cap * Fc;  // 33,554,432
    const size_t HF   = (size_t)Hc * Fc;        // 1,048,576 (per-expert w size)

    // ---- workspace carve (bytes) ----
    char* wsb = (char*)d_ws;
    size_t off = 0;
    auto alloc = [&](size_t bytes) { size_t r = off; off = (off + bytes + 255) & ~(size_t)255; return r; };
    size_t x1b_off = alloc(TH * 2);   // bf16 x1, later attn out
    size_t qb_off  = alloc(TH * 2);
    size_t kb_off  = alloc(TH * 2);
    size_t vb_off  = alloc(TH * 2);
    size_t ab_off  = alloc(TH * 2);   // bf16 attention output
    size_t xa_off  = alloc(TH * 4);   // fp32 attn residual out
    size_t x2_off  = alloc(TH * 4);   // fp32 LN2 out
    size_t ef_off  = alloc((size_t)Tc * 2 * 4);
    size_t pos_off = alloc((size_t)Tc * 2 * 4);
    size_t gf_off  = alloc((size_t)Tc * 2 * 4);
    size_t buf_off = alloc(ECH * 2);  // bf16 expert inputs
    size_t h_off   = alloc(ECF * 2);  // bf16 h (all experts)
    size_t y_off   = alloc(ECH * 4);  // fp32 expert outputs
    if (ws_size < off) return;        // insufficient workspace

    unsigned short* x1b  = (unsigned short*)(wsb + x1b_off);
    unsigned short* qb   = (unsigned short*)(wsb + qb_off);
    unsigned short* kb   = (unsigned short*)(wsb + kb_off);
    unsigned short* vb   = (unsigned short*)(wsb + vb_off);
    unsigned short* ab   = (unsigned short*)(wsb + ab_off);
    float* xa  = (float*)(wsb + xa_off);
    float* x2  = (float*)(wsb + x2_off);
    int*   ef  = (int*)(wsb + ef_off);
    int*   pos = (int*)(wsb + pos_off);
    float* gf  = (float*)(wsb + gf_off);
    unsigned short* bufb = (unsigned short*)(wsb + buf_off);
    unsigned short* h    = (unsigned short*)(wsb + h_off);
    float* y = (float*)(wsb + y_off);

    dim3 blk(256);

    // 1. LN1 -> bf16
    ln_kernel<unsigned short><<<Tc, blk, 0, stream>>>(x, ln1_g, ln1_b, x1b);

    // 2. QKV projections (bf16 out), fp32 weights transposed in-GEMM
    gemm_mfma<128, 0, unsigned short><<<dim3(Hc / 128, Tc / 128, 1), blk, 0, stream>>>(
        x1b, wq, qb, nullptr, Tc, Hc, Hc, 0, 0, 0, 0);
    gemm_mfma<128, 0, unsigned short><<<dim3(Hc / 128, Tc / 128, 1), blk, 0, stream>>>(
        x1b, wk, kb, nullptr, Tc, Hc, Hc, 0, 0, 0, 0);
    gemm_mfma<128, 0, unsigned short><<<dim3(Hc / 128, Tc / 128, 1), blk, 0, stream>>>(
        x1b, wv, vb, nullptr, Tc, Hc, Hc, 0, 0, 0, 0);

    // 3. attention -> bf16 ab
    attn_mfma_kernel<<<dim3(Sc / 64, NHc, Bc), blk, 0, stream>>>(qb, kb, vb, ab);

    // 4. output projection + residual: xa = attn @ wo + x
    gemm_mfma<128, 1, float><<<dim3(Hc / 128, Tc / 128, 1), blk, 0, stream>>>(
        ab, wo, xa, x, Tc, Hc, Hc, 0, 0, 0, 0);

    // 5. LN2 -> fp32
    ln_kernel<float><<<Tc, blk, 0, stream>>>(xa, ln2_g, ln2_b, x2);

    // 6. router + top2
    router_top2_kernel<<<Tc / 4, blk, 0, stream>>>(x2, wr, ef, gf);

    // 7. positions within expert queues
    pos_kernel<<<Ec, blk, 0, stream>>>(ef, pos);

    // 8. dispatch tokens to expert buffers (bf16)
    dispatch_kernel<<<Tc * 2, dim3(128), 0, stream>>>(x2, ef, pos, bufb);

    // 9. expert GEMM1: h = gelu(buf @ w1 + b1), BM=256 so w1 read exactly once
    gemm_mfma<256, 2, unsigned short><<<dim3(Fc / 128, Cap / 256, Ec), dim3(512), 0, stream>>>(
        bufb, w1, h, b1, Cap, Fc, Hc,
        (long)Cap * Hc, (long)HF, (long)Cap * Fc, (long)Fc);

    // 10. expert GEMM2: y = h @ w2 + b2
    gemm_mfma<256, 3, float><<<dim3(Hc / 128, Cap / 256, Ec), dim3(512), 0, stream>>>(
        h, w2, y, b2, Cap, Hc, Fc,
        (long)Cap * Fc, (long)HF, (long)Cap * Hc, (long)Hc);

    // 11. combine + final residual
    combine_kernel<<<Tc, dim3(128), 0, stream>>>(xa, y, ef, pos, gf, out);
}

// Round 5
// 365.413 us; speedup vs baseline: 7.7600x; 1.2191x over previous
//
#include <hip/hip_runtime.h>
#include <hip/hip_bf16.h>
#include <math.h>

// Problem constants (from reference setup_inputs)
constexpr int Bc  = 2;
constexpr int Sc  = 2048;
constexpr int Hc  = 512;
constexpr int NHc = 8;
constexpr int Tc  = Bc * Sc;      // 4096 tokens
constexpr int Ec  = 64;           // experts
constexpr int Fc  = 2048;         // ffn dim
constexpr int Cap = 256;          // capacity = 2 * T * 2 / E

typedef __attribute__((ext_vector_type(8))) short bf16x8;
typedef __attribute__((ext_vector_type(4))) float f32x4;

__device__ __forceinline__ unsigned short f2b(float f) {
    union { float f; unsigned u; } v; v.f = f;
    unsigned r = v.u + 0x7FFF + ((v.u >> 16) & 1);   // RTNE
    return (unsigned short)(r >> 16);
}

__device__ __forceinline__ unsigned cvt_pk_bf16(float lo, float hi) {
    unsigned r;
    asm volatile("v_cvt_pk_bf16_f32 %0, %1, %2" : "=v"(r) : "v"(lo), "v"(hi));
    return r;
}

__device__ __forceinline__ float gelu_f(float x) {
    // jax.nn.gelu default approximate=True (tanh)
    float x3 = x * x * x;
    return 0.5f * x * (1.0f + tanhf(0.7978845608028654f * (x + 0.044715f * x3)));
}

// ---------------- LayerNorm: one block per row (H=512, 256 threads) ----------
template <typename TO>
__global__ __launch_bounds__(256) void ln_kernel(const float* __restrict__ x,
                                                 const float* __restrict__ g,
                                                 const float* __restrict__ b,
                                                 TO* __restrict__ o) {
    int t = blockIdx.x;
    const float* row = x + (size_t)t * Hc;
    int tid = threadIdx.x;
    float v0 = row[tid];
    float v1 = row[tid + 256];
    float s = v0 + v1, s2 = v0 * v0 + v1 * v1;
    for (int off = 32; off; off >>= 1) {
        s  += __shfl_down(s,  off);
        s2 += __shfl_down(s2, off);
    }
    __shared__ float ls[4], ls2[4];
    int wid = tid >> 6, lane = tid & 63;
    if (lane == 0) { ls[wid] = s; ls2[wid] = s2; }
    __syncthreads();
    if (tid == 0) {
        float a = 0.f, a2 = 0.f;
        for (int i = 0; i < 4; i++) { a += ls[i]; a2 += ls2[i]; }
        ls[0] = a; ls2[0] = a2;
    }
    __syncthreads();
    float mean = ls[0] * (1.0f / Hc);
    float var  = ls2[0] * (1.0f / Hc) - mean * mean;
    float r = rsqrtf(var + 1e-5f);
    float o0 = (v0 - mean) * r * g[tid]       + b[tid];
    float o1 = (v1 - mean) * r * g[tid + 256] + b[tid + 256];
    if constexpr (sizeof(TO) == 2) {
        o[(size_t)t * Hc + tid]       = (TO)f2b(o0);
        o[(size_t)t * Hc + tid + 256] = (TO)f2b(o1);
    } else {
        o[(size_t)t * Hc + tid]       = o0;
        o[(size_t)t * Hc + tid + 256] = o1;
    }
}

// ---------------- MFMA bf16 GEMM with in-LDS weight transpose ---------------
// C[M,N] = A[M,K](bf16) @ W[K,N](fp32 row-major), batched via blockIdx.z.
// If Wb != null: W selected per-z from {W, Wb, Wc} (QKV fusion), C += z*sC.
// EPI: 0=none, 1=+X[m*N+n] (fp32), 2=gelu(acc+X[n]) -> bf16, 3=acc+X[n] -> fp32
template <int BM, int EPI, typename TC>
__global__ __launch_bounds__(BM * 2) void gemm_mfma(const unsigned short* __restrict__ A,
                                                    const float* __restrict__ W,
                                                    TC* __restrict__ C,
                                                    const float* __restrict__ X,
                                                    int M, int N, int K,
                                                    long sA, long sW, long sC, long sX,
                                                    const float* __restrict__ Wb,
                                                    const float* __restrict__ Wc) {
    int bz = blockIdx.z;
    A += (size_t)bz * sA;
    if (Wb) W = (bz == 0) ? W : ((bz == 1) ? Wb : Wc);
    else    W += (size_t)bz * sW;
    C += (size_t)bz * sC;
    if (X) X += (size_t)bz * sX;
    int m0 = blockIdx.y * BM, n0 = blockIdx.x * 128;

    __shared__ unsigned short As[BM * 72];
    __shared__ unsigned short Bs[128 * 72];

    int tid = threadIdx.x;
    int wid = tid >> 6, lane = tid & 63;
    int wr = (wid >> 1) * 64, wc = (wid & 1) * 64;
    int lr = lane & 15, lg = lane >> 4;

    f32x4 acc[4][4];
    #pragma unroll
    for (int i = 0; i < 4; i++)
        #pragma unroll
        for (int j = 0; j < 4; j++) acc[i][j] = (f32x4){0.f, 0.f, 0.f, 0.f};

    for (int k0 = 0; k0 < K; k0 += 64) {
        // ---- stage A rows (bf16, vector) ----
        #pragma unroll
        for (int p = 0; p < 4; p++) {
            int e = p * 16 * BM + tid * 8;
            int row = e >> 6, col = e & 63;
            *(bf16x8*)&As[row * 72 + col] =
                *(const bf16x8*)&A[(size_t)(m0 + row) * K + k0 + col];
        }
        // ---- stage W tile [64][128] fp32 -> Bs[n][k] bf16 (transposed) ----
        #pragma unroll
        for (int p = 0; p < 512 / BM; p++) {
            int kp = (tid >> 5) + p * (BM / 16);   // k-pair 0..31
            int c  = (tid & 31) * 4;               // col base 0..124
            const float* w0 = &W[(size_t)(k0 + 2 * kp) * N + n0 + c];
            float4 a = *(const float4*)w0;
            float4 b = *(const float4*)(w0 + N);
            int qz = 8 * ((c >> 3) & 7);           // uniform over c..c+3
            int kof = (2 * kp) ^ qz;
            *(ushort2*)&Bs[(c + 0) * 72 + kof] = (ushort2){f2b(a.x), f2b(b.x)};
            *(ushort2*)&Bs[(c + 1) * 72 + kof] = (ushort2){f2b(a.y), f2b(b.y)};
            *(ushort2*)&Bs[(c + 2) * 72 + kof] = (ushort2){f2b(a.z), f2b(b.z)};
            *(ushort2*)&Bs[(c + 3) * 72 + kof] = (ushort2){f2b(a.w), f2b(b.w)};
        }
        __syncthreads();
        #pragma unroll
        for (int kk = 0; kk < 64; kk += 32) {
            bf16x8 af[4], bfr[4];
            #pragma unroll
            for (int i = 0; i < 4; i++) {
                af[i] = *(const bf16x8*)&As[(wr + i * 16 + lr) * 72 + kk + 8 * lg];
                int nrow = wc + i * 16 + lr;
                int qq = 8 * ((nrow >> 3) & 7);
                bfr[i] = *(const bf16x8*)&Bs[nrow * 72 + ((kk + 8 * lg) ^ qq)];
            }
            #pragma unroll
            for (int i = 0; i < 4; i++)
                #pragma unroll
                for (int j = 0; j < 4; j++)
                    acc[i][j] = __builtin_amdgcn_mfma_f32_16x16x32_bf16(af[i], bfr[j], acc[i][j], 0, 0, 0);
        }
        __syncthreads();
    }

    #pragma unroll
    for (int i = 0; i < 4; i++) {
        #pragma unroll
        for (int r = 0; r < 4; r++) {
            int m = m0 + wr + i * 16 + lg * 4 + r;
            #pragma unroll
            for (int j = 0; j < 4; j++) {
                int n = n0 + wc + j * 16 + lr;
                float vv = acc[i][j][r];
                if (EPI == 1) vv += X[(size_t)m * N + n];
                if (EPI == 2) { vv += X[n]; vv = gelu_f(vv); }
                if (EPI == 3) vv += X[n];
                if constexpr (sizeof(TC) == 2) C[(size_t)m * N + n] = (TC)f2b(vv);
                else                            C[(size_t)m * N + n] = vv;
            }
        }
    }
}

// ---------------- MFMA flash attention, swapped QK^T, in-lane softmax --------
// grid (S/64, NH, B), 256 threads = 4 waves; each wave owns 16 q-rows.
// S^T = mfma(K, Q): lane holds all 16 scores of q-row (lane&15); softmax is
// in-lane + 2 shfl. P wave-local through LDS (lgkmcnt fence, no barrier).
// K/V double-buffered with register prefetch: 1 barrier per tile.
__global__ __launch_bounds__(256) void attn_mfma_kernel(const unsigned short* __restrict__ q,
                                                        const unsigned short* __restrict__ k,
                                                        const unsigned short* __restrict__ v,
                                                        unsigned short* __restrict__ o) {
    constexpr int LDK = 72;
    constexpr int NT  = Sc / 64;
    __shared__ unsigned short Ks[2][64 * LDK];   // [key][d]
    __shared__ unsigned short Vt[2][64 * LDK];   // [d][key]
    __shared__ unsigned short Ps[64 * LDK];      // per-wave [q][key]

    int qt = blockIdx.x, hh = blockIdx.y, b = blockIdx.z;
    int q0 = qt * 64;
    int tid = threadIdx.x;
    int wid = tid >> 6, lane = tid & 63;
    int lr = lane & 15, lg = lane >> 4;

    const unsigned short* kbase = k + (size_t)(b * Sc) * Hc + hh * 64;
    const unsigned short* vbase = v + (size_t)(b * Sc) * Hc + hh * 64;

    // Q fragment (B-operand): col=q=lr, k-elem d=32s+8lg+j
    bf16x8 qf[2];
    {
        const unsigned short* qrow = q + ((size_t)(b * Sc + q0 + wid * 16 + lr)) * Hc + hh * 64;
        qf[0] = *(const bf16x8*)&qrow[8 * lg];
        qf[1] = *(const bf16x8*)&qrow[32 + 8 * lg];
    }

    // staging geometry
    int krow = tid >> 3;            // 0..31
    int kcol = (tid & 7) * 8;       // 0..56
    int vk2  = (tid >> 4) * 2;      // 0..30
    int vd4  = (tid & 15) * 4;      // 0..60

    bf16x8 kr[2];
    ushort4 va[2], vb2[2];

    auto load_tile = [&](int kt) {
        #pragma unroll
        for (int p = 0; p < 2; p++) {
            kr[p] = *(const bf16x8*)&kbase[(size_t)(kt * 64 + p * 32 + krow) * Hc + kcol];
            const unsigned short* vp = &vbase[(size_t)(kt * 64 + p * 32 + vk2) * Hc + vd4];
            va[p]  = *(const ushort4*)vp;
            vb2[p] = *(const ushort4*)(vp + Hc);
        }
    };
    auto store_tile = [&](int bu) {
        #pragma unroll
        for (int p = 0; p < 2; p++) {
            *(bf16x8*)&Ks[bu][(p * 32 + krow) * LDK + kcol] = kr[p];
            int k2 = p * 32 + vk2;
            *(ushort2*)&Vt[bu][(vd4 + 0) * LDK + k2] = (ushort2){va[p].x, vb2[p].x};
            *(ushort2*)&Vt[bu][(vd4 + 1) * LDK + k2] = (ushort2){va[p].y, vb2[p].y};
            *(ushort2*)&Vt[bu][(vd4 + 2) * LDK + k2] = (ushort2){va[p].z, vb2[p].z};
            *(ushort2*)&Vt[bu][(vd4 + 3) * LDK + k2] = (ushort2){va[p].w, vb2[p].w};
        }
    };

    f32x4 Oacc[4];
    #pragma unroll
    for (int nb = 0; nb < 4; nb++) Oacc[nb] = (f32x4){0.f, 0.f, 0.f, 0.f};
    float mrun = -1e30f, lrun = 0.f;   // per-lane: q-row = lr
    const float scale = 0.125f;

    load_tile(0);
    store_tile(0);
    __syncthreads();

    for (int kt = 0; kt < NT; kt++) {
        int cur = kt & 1;
        if (kt + 1 < NT) load_tile(kt + 1);   // prefetch (vmcnt pending)

        // ---- S^T = K Q^T : sacc[kb] row=key(lg*4+r), col=q(lr) ----
        f32x4 sacc[4];
        #pragma unroll
        for (int kb = 0; kb < 4; kb++) sacc[kb] = (f32x4){0.f, 0.f, 0.f, 0.f};
        #pragma unroll
        for (int kb = 0; kb < 4; kb++) {
            #pragma unroll
            for (int s = 0; s < 2; s++) {
                bf16x8 kf = *(const bf16x8*)&Ks[cur][(kb * 16 + lr) * LDK + 32 * s + 8 * lg];
                sacc[kb] = __builtin_amdgcn_mfma_f32_16x16x32_bf16(kf, qf[s], sacc[kb], 0, 0, 0);
            }
        }

        // ---- in-lane softmax (16 scores of q-row lr live in this lane) ----
        float z[4][4];
        float mt = -1e30f;
        #pragma unroll
        for (int kb = 0; kb < 4; kb++)
            #pragma unroll
            for (int r = 0; r < 4; r++) {
                z[kb][r] = sacc[kb][r] * scale;
                mt = fmaxf(mt, z[kb][r]);
            }
        mt = fmaxf(mt, __shfl_xor(mt, 16));
        mt = fmaxf(mt, __shfl_xor(mt, 32));
        float mnew = fmaxf(mrun, mt);
        float sc = __expf(mrun - mnew);
        float ps = 0.f;
        float pv[4][4];
        #pragma unroll
        for (int kb = 0; kb < 4; kb++)
            #pragma unroll
            for (int r = 0; r < 4; r++) {
                pv[kb][r] = __expf(z[kb][r] - mnew);
                ps += pv[kb][r];
            }
        ps += __shfl_xor(ps, 16);
        ps += __shfl_xor(ps, 32);
        lrun = lrun * sc + ps;
        mrun = mnew;

        // ---- P -> LDS (wave-local): row q=lr, cols kb*16+lg*4+(0..3) ----
        #pragma unroll
        for (int kb = 0; kb < 4; kb++) {
            unsigned lo = cvt_pk_bf16(pv[kb][0], pv[kb][1]);
            unsigned hi = cvt_pk_bf16(pv[kb][2], pv[kb][3]);
            *(uint2*)&Ps[(wid * 16 + lr) * LDK + kb * 16 + lg * 4] = (uint2){lo, hi};
        }
        asm volatile("s_waitcnt lgkmcnt(0)" ::: "memory");
        __builtin_amdgcn_sched_barrier(0);

        // broadcast rescale factor to C-layout rows (q = lg*4+r)
        float scb[4];
        #pragma unroll
        for (int r = 0; r < 4; r++) scb[r] = __shfl(sc, lg * 4 + r);

        // ---- O = O*sc + P V ----
        #pragma unroll
        for (int nb = 0; nb < 4; nb++) {
            f32x4 oa = Oacc[nb];
            #pragma unroll
            for (int r = 0; r < 4; r++) oa[r] *= scb[r];
            #pragma unroll
            for (int s = 0; s < 2; s++) {
                bf16x8 pf = *(const bf16x8*)&Ps[(wid * 16 + lr) * LDK + 32 * s + 8 * lg];
                bf16x8 vf = *(const bf16x8*)&Vt[cur][(nb * 16 + lr) * LDK + 32 * s + 8 * lg];
                oa = __builtin_amdgcn_mfma_f32_16x16x32_bf16(pf, vf, oa, 0, 0, 0);
            }
            Oacc[nb] = oa;
        }

        if (kt + 1 < NT) store_tile(cur ^ 1);  // compiler inserts vmcnt waits
        __syncthreads();
    }

    // ---- epilogue ----
    float linv = 1.0f / lrun;
    unsigned short* ob = o + ((size_t)(b * Sc + q0 + wid * 16)) * Hc + hh * 64;
    #pragma unroll
    for (int r = 0; r < 4; r++) {
        float invB = __shfl(linv, lg * 4 + r);
        #pragma unroll
        for (int nb = 0; nb < 4; nb++) {
            ob[(size_t)(lg * 4 + r) * Hc + nb * 16 + lr] = f2b(Oacc[nb][r] * invB);
        }
    }
}

// ---------------- Router GEMM + softmax + top-2 ------------------------------
__global__ __launch_bounds__(256) void router_top2_kernel(const float* __restrict__ x2,
                                                          const float* __restrict__ wr,
                                                          int* __restrict__ ef,
                                                          float* __restrict__ gf) {
    int t = blockIdx.x * 4 + (threadIdx.x >> 6);
    int l = threadIdx.x & 63;
    const float* xr = x2 + (size_t)t * Hc;
    float acc = 0.f;
    for (int hhh = 0; hhh < Hc; hhh++) acc += xr[hhh] * wr[hhh * Ec + l];

    float mx = acc;
    for (int off = 32; off; off >>= 1) mx = fmaxf(mx, __shfl_xor(mx, off));
    float p = expf(acc - mx);
    float sum = p;
    for (int off = 32; off; off >>= 1) sum += __shfl_xor(sum, off);
    p /= sum;

    float v1 = p; int i1 = l;
    for (int off = 32; off; off >>= 1) {
        float ov = __shfl_xor(v1, off);
        int   oi = __shfl_xor(i1, off);
        if (ov > v1 || (ov == v1 && oi < i1)) { v1 = ov; i1 = oi; }
    }
    float v2 = (l == i1) ? -INFINITY : p; int i2 = l;
    for (int off = 32; off; off >>= 1) {
        float ov = __shfl_xor(v2, off);
        int   oi = __shfl_xor(i2, off);
        if (ov > v2 || (ov == v2 && oi < i2)) { v2 = ov; i2 = oi; }
    }
    if (l == 0) {
        float inv = 1.0f / (v1 + v2);
        ef[t * 2]     = i1;
        ef[t * 2 + 1] = i2;
        gf[t * 2]     = v1 * inv;
        gf[t * 2 + 1] = v2 * inv;
    }
}

// ---------------- pos: rank of each slot within its expert (slot order) ------
__global__ __launch_bounds__(256) void pos_kernel(const int* __restrict__ ef,
                                                  int* __restrict__ pos) {
    int e = blockIdx.x;
    __shared__ int cnts[257];
    int tid = threadIdx.x;
    int base = tid * 32;  // 8192 / 256
    int c = 0;
    for (int i = 0; i < 32; i++) c += (ef[base + i] == e) ? 1 : 0;
    cnts[tid + 1] = c;
    if (tid == 0) cnts[0] = 0;
    __syncthreads();
    if (tid == 0) {
        for (int i = 1; i <= 256; i++) cnts[i] += cnts[i - 1];
    }
    __syncthreads();
    int run = cnts[tid];
    for (int i = 0; i < 32; i++) {
        if (ef[base + i] == e) pos[base + i] = run++;
    }
}

// ---------------- dispatch: copy kept tokens into expert buffers (bf16) ------
__global__ __launch_bounds__(128) void dispatch_kernel(const float* __restrict__ x2,
                                                       const int* __restrict__ ef,
                                                       const int* __restrict__ pos,
                                                       unsigned short* __restrict__ buf) {
    int s = blockIdx.x;
    int p = pos[s];
    if (p >= Cap) return;
    int e = ef[s];
    int t = s >> 1;
    float4 vv = ((const float4*)(x2 + (size_t)t * Hc))[threadIdx.x];
    ushort4 o;
    o.x = f2b(vv.x); o.y = f2b(vv.y); o.z = f2b(vv.z); o.w = f2b(vv.w);
    ((ushort4*)(buf + ((size_t)e * Cap + p) * Hc))[threadIdx.x] = o;
}

// ---------------- combine: out = xa + sum_k gate * y[ef,pos] -----------------
__global__ __launch_bounds__(128) void combine_kernel(const float* __restrict__ xa,
                                                      const float* __restrict__ y,
                                                      const int* __restrict__ ef,
                                                      const int* __restrict__ pos,
                                                      const float* __restrict__ gf,
                                                      float* __restrict__ out) {
    int t = blockIdx.x;
    int d = threadIdx.x;
    float4 acc = ((const float4*)(xa + (size_t)t * Hc))[d];
    #pragma unroll
    for (int kk = 0; kk < 2; kk++) {
        int s = t * 2 + kk;
        int p = pos[s];
        if (p < Cap) {
            float w = gf[s];
            float4 yv = ((const float4*)(y + ((size_t)ef[s] * Cap + p) * Hc))[d];
            acc.x += w * yv.x;
            acc.y += w * yv.y;
            acc.z += w * yv.z;
            acc.w += w * yv.w;
        }
    }
    ((float4*)(out + (size_t)t * Hc))[d] = acc;
}

// ---------------- launch -----------------------------------------------------
extern "C" void kernel_launch(void* const* d_in, const int* in_sizes, int n_in,
                              void* d_out, int out_size, void* d_ws, size_t ws_size,
                              hipStream_t stream) {
    const float* x     = (const float*)d_in[0];
    const float* ln1_g = (const float*)d_in[1];
    const float* ln1_b = (const float*)d_in[2];
    const float* wq    = (const float*)d_in[3];
    const float* wk    = (const float*)d_in[4];
    const float* wv    = (const float*)d_in[5];
    const float* wo    = (const float*)d_in[6];
    const float* ln2_g = (const float*)d_in[7];
    const float* ln2_b = (const float*)d_in[8];
    const float* wr    = (const float*)d_in[9];
    const float* w1    = (const float*)d_in[10];
    const float* b1    = (const float*)d_in[11];
    const float* w2    = (const float*)d_in[12];
    const float* b2    = (const float*)d_in[13];
    float* out = (float*)d_out;

    const size_t TH   = (size_t)Tc * Hc;        // 2,097,152
    const size_t ECH  = (size_t)Ec * Cap * Hc;  // 8,388,608
    const size_t ECF  = (size_t)Ec * Cap * Fc;  // 33,554,432
    const size_t HF   = (size_t)Hc * Fc;        // 1,048,576 (per-expert w size)

    // ---- workspace carve (bytes) ----
    char* wsb = (char*)d_ws;
    size_t off = 0;
    auto alloc = [&](size_t bytes) { size_t r = off; off = (off + bytes + 255) & ~(size_t)255; return r; };
    size_t x1b_off = alloc(TH * 2);       // bf16 x1
    size_t qkv_off = alloc(TH * 2 * 3);   // bf16 q|k|v contiguous
    size_t ab_off  = alloc(TH * 2);       // bf16 attention output
    size_t xa_off  = alloc(TH * 4);       // fp32 attn residual out
    size_t x2_off  = alloc(TH * 4);       // fp32 LN2 out
    size_t ef_off  = alloc((size_t)Tc * 2 * 4);
    size_t pos_off = alloc((size_t)Tc * 2 * 4);
    size_t gf_off  = alloc((size_t)Tc * 2 * 4);
    size_t buf_off = alloc(ECH * 2);      // bf16 expert inputs
    size_t h_off   = alloc(ECF * 2);      // bf16 h (all experts)
    size_t y_off   = alloc(ECH * 4);      // fp32 expert outputs
    if (ws_size < off) return;            // insufficient workspace

    unsigned short* x1b  = (unsigned short*)(wsb + x1b_off);
    unsigned short* qb   = (unsigned short*)(wsb + qkv_off);
    unsigned short* kb   = qb + TH;
    unsigned short* vb   = qb + 2 * TH;
    unsigned short* ab   = (unsigned short*)(wsb + ab_off);
    float* xa  = (float*)(wsb + xa_off);
    float* x2  = (float*)(wsb + x2_off);
    int*   ef  = (int*)(wsb + ef_off);
    int*   pos = (int*)(wsb + pos_off);
    float* gf  = (float*)(wsb + gf_off);
    unsigned short* bufb = (unsigned short*)(wsb + buf_off);
    unsigned short* h    = (unsigned short*)(wsb + h_off);
    float* y = (float*)(wsb + y_off);

    dim3 blk(256);

    // 1. LN1 -> bf16
    ln_kernel<unsigned short><<<Tc, blk, 0, stream>>>(x, ln1_g, ln1_b, x1b);

    // 2. fused QKV projections: one launch, z selects {wq,wk,wv} -> q|k|v
    gemm_mfma<128, 0, unsigned short><<<dim3(Hc / 128, Tc / 128, 3), blk, 0, stream>>>(
        x1b, wq, qb, nullptr, Tc, Hc, Hc, 0, 0, (long)TH, 0, wk, wv);

    // 3. attention -> bf16 ab
    attn_mfma_kernel<<<dim3(Sc / 64, NHc, Bc), blk, 0, stream>>>(qb, kb, vb, ab);

    // 4. output projection + residual: xa = attn @ wo + x
    gemm_mfma<128, 1, float><<<dim3(Hc / 128, Tc / 128, 1), blk, 0, stream>>>(
        ab, wo, xa, x, Tc, Hc, Hc, 0, 0, 0, 0, nullptr, nullptr);

    // 5. LN2 -> fp32
    ln_kernel<float><<<Tc, blk, 0, stream>>>(xa, ln2_g, ln2_b, x2);

    // 6. router + top2
    router_top2_kernel<<<Tc / 4, blk, 0, stream>>>(x2, wr, ef, gf);

    // 7. positions within expert queues
    pos_kernel<<<Ec, blk, 0, stream>>>(ef, pos);

    // 8. dispatch tokens to expert buffers (bf16)
    dispatch_kernel<<<Tc * 2, dim3(128), 0, stream>>>(x2, ef, pos, bufb);

    // 9. expert GEMM1: h = gelu(buf @ w1 + b1), BM=256 so w1 read exactly once
    gemm_mfma<256, 2, unsigned short><<<dim3(Fc / 128, Cap / 256, Ec), dim3(512), 0, stream>>>(
        bufb, w1, h, b1, Cap, Fc, Hc,
        (long)Cap * Hc, (long)HF, (long)Cap * Fc, (long)Fc, nullptr, nullptr);

    // 10. expert GEMM2: y = h @ w2 + b2
    gemm_mfma<256, 3, float><<<dim3(Hc / 128, Cap / 256, Ec), dim3(512), 0, stream>>>(
        h, w2, y, b2, Cap, Hc, Fc,
        (long)Cap * Fc, (long)HF, (long)Cap * Hc, (long)Hc, nullptr, nullptr);

    // 11. combine + final residual
    combine_kernel<<<Tc, dim3(128), 0, stream>>>(xa, y, ef, pos, gf, out);
}

// Round 6
// 350.352 us; speedup vs baseline: 8.0936x; 1.0430x over previous
//
#include <hip/hip_runtime.h>
#include <hip/hip_bf16.h>
#include <math.h>

// Problem constants (from reference setup_inputs)
constexpr int Bc  = 2;
constexpr int Sc  = 2048;
constexpr int Hc  = 512;
constexpr int NHc = 8;
constexpr int Tc  = Bc * Sc;      // 4096 tokens
constexpr int Ec  = 64;           // experts
constexpr int Fc  = 2048;         // ffn dim
constexpr int Cap = 256;          // capacity = 2 * T * 2 / E

typedef __attribute__((ext_vector_type(8))) short bf16x8;
typedef __attribute__((ext_vector_type(4))) float f32x4;

__device__ __forceinline__ unsigned short f2b(float f) {
    union { float f; unsigned u; } v; v.f = f;
    unsigned r = v.u + 0x7FFF + ((v.u >> 16) & 1);   // RTNE
    return (unsigned short)(r >> 16);
}

__device__ __forceinline__ unsigned cvt_pk_bf16(float lo, float hi) {
    unsigned r;
    asm volatile("v_cvt_pk_bf16_f32 %0, %1, %2" : "=v"(r) : "v"(lo), "v"(hi));
    return r;
}

__device__ __forceinline__ float gelu_f(float x) {
    // jax.nn.gelu default approximate=True (tanh)
    float x3 = x * x * x;
    return 0.5f * x * (1.0f + tanhf(0.7978845608028654f * (x + 0.044715f * x3)));
}

// ---------------- LayerNorm: one block per row (H=512, 256 threads) ----------
template <typename TO>
__global__ __launch_bounds__(256) void ln_kernel(const float* __restrict__ x,
                                                 const float* __restrict__ g,
                                                 const float* __restrict__ b,
                                                 TO* __restrict__ o) {
    int t = blockIdx.x;
    const float* row = x + (size_t)t * Hc;
    int tid = threadIdx.x;
    float v0 = row[tid];
    float v1 = row[tid + 256];
    float s = v0 + v1, s2 = v0 * v0 + v1 * v1;
    for (int off = 32; off; off >>= 1) {
        s  += __shfl_down(s,  off);
        s2 += __shfl_down(s2, off);
    }
    __shared__ float ls[4], ls2[4];
    int wid = tid >> 6, lane = tid & 63;
    if (lane == 0) { ls[wid] = s; ls2[wid] = s2; }
    __syncthreads();
    if (tid == 0) {
        float a = 0.f, a2 = 0.f;
        for (int i = 0; i < 4; i++) { a += ls[i]; a2 += ls2[i]; }
        ls[0] = a; ls2[0] = a2;
    }
    __syncthreads();
    float mean = ls[0] * (1.0f / Hc);
    float var  = ls2[0] * (1.0f / Hc) - mean * mean;
    float r = rsqrtf(var + 1e-5f);
    float o0 = (v0 - mean) * r * g[tid]       + b[tid];
    float o1 = (v1 - mean) * r * g[tid + 256] + b[tid + 256];
    if constexpr (sizeof(TO) == 2) {
        o[(size_t)t * Hc + tid]       = (TO)f2b(o0);
        o[(size_t)t * Hc + tid + 256] = (TO)f2b(o1);
    } else {
        o[(size_t)t * Hc + tid]       = o0;
        o[(size_t)t * Hc + tid + 256] = o1;
    }
}

// ---------------- MFMA bf16 GEMM with in-LDS weight transpose ---------------
// C[M,N] = A[M,K](bf16) @ W[K,N](fp32 row-major), batched via blockIdx.z.
// If Wb != null: W selected per-z from {W, Wb, Wc} (QKV fusion), C += z*sC.
// SWZ=1: bijective XCD remap of (x,z) so same-z (same-expert) blocks share
// an XCD L2 (A-tile fetched once per XCD). Requires gridDim.y==1, nwg%8==0.
// EPI: 0=none, 1=+X[m*N+n] (fp32), 2=gelu(acc+X[n]) -> bf16, 3=acc+X[n] -> fp32
template <int BM, int EPI, int SWZ, typename TC>
__global__ __launch_bounds__(BM * 2) void gemm_mfma(const unsigned short* __restrict__ A,
                                                    const float* __restrict__ W,
                                                    TC* __restrict__ C,
                                                    const float* __restrict__ X,
                                                    int M, int N, int K,
                                                    long sA, long sW, long sC, long sX,
                                                    const float* __restrict__ Wb,
                                                    const float* __restrict__ Wc) {
    int bx = blockIdx.x, bz = blockIdx.z, by = blockIdx.y;
    if (SWZ) {
        int gx = gridDim.x;
        int nwg = gx * gridDim.z;
        int flat = bx + gx * bz;
        int wg = (flat & 7) * (nwg >> 3) + (flat >> 3);
        bx = wg % gx; bz = wg / gx;
    }
    A += (size_t)bz * sA;
    if (Wb) W = (bz == 0) ? W : ((bz == 1) ? Wb : Wc);
    else    W += (size_t)bz * sW;
    C += (size_t)bz * sC;
    if (X) X += (size_t)bz * sX;
    int m0 = by * BM, n0 = bx * 128;

    __shared__ unsigned short As[BM * 72];
    __shared__ unsigned short Bs[128 * 72];

    int tid = threadIdx.x;
    int wid = tid >> 6, lane = tid & 63;
    int wr = (wid >> 1) * 64, wc = (wid & 1) * 64;
    int lr = lane & 15, lg = lane >> 4;

    f32x4 acc[4][4];
    #pragma unroll
    for (int i = 0; i < 4; i++)
        #pragma unroll
        for (int j = 0; j < 4; j++) acc[i][j] = (f32x4){0.f, 0.f, 0.f, 0.f};

    for (int k0 = 0; k0 < K; k0 += 64) {
        // ---- stage A rows (bf16, vector) ----
        #pragma unroll
        for (int p = 0; p < 4; p++) {
            int e = p * 16 * BM + tid * 8;
            int row = e >> 6, col = e & 63;
            *(bf16x8*)&As[row * 72 + col] =
                *(const bf16x8*)&A[(size_t)(m0 + row) * K + k0 + col];
        }
        // ---- stage W tile [64][128] fp32 -> Bs[n][k] bf16 (transposed) ----
        #pragma unroll
        for (int p = 0; p < 512 / BM; p++) {
            int kp = (tid >> 5) + p * (BM / 16);   // k-pair 0..31
            int c  = (tid & 31) * 4;               // col base 0..124
            const float* w0 = &W[(size_t)(k0 + 2 * kp) * N + n0 + c];
            float4 a = *(const float4*)w0;
            float4 b = *(const float4*)(w0 + N);
            int qz = 8 * ((c >> 3) & 7);           // uniform over c..c+3
            int kof = (2 * kp) ^ qz;
            *(ushort2*)&Bs[(c + 0) * 72 + kof] = (ushort2){f2b(a.x), f2b(b.x)};
            *(ushort2*)&Bs[(c + 1) * 72 + kof] = (ushort2){f2b(a.y), f2b(b.y)};
            *(ushort2*)&Bs[(c + 2) * 72 + kof] = (ushort2){f2b(a.z), f2b(b.z)};
            *(ushort2*)&Bs[(c + 3) * 72 + kof] = (ushort2){f2b(a.w), f2b(b.w)};
        }
        __syncthreads();
        #pragma unroll
        for (int kk = 0; kk < 64; kk += 32) {
            bf16x8 af[4], bfr[4];
            #pragma unroll
            for (int i = 0; i < 4; i++) {
                af[i] = *(const bf16x8*)&As[(wr + i * 16 + lr) * 72 + kk + 8 * lg];
                int nrow = wc + i * 16 + lr;
                int qq = 8 * ((nrow >> 3) & 7);
                bfr[i] = *(const bf16x8*)&Bs[nrow * 72 + ((kk + 8 * lg) ^ qq)];
            }
            #pragma unroll
            for (int i = 0; i < 4; i++)
                #pragma unroll
                for (int j = 0; j < 4; j++)
                    acc[i][j] = __builtin_amdgcn_mfma_f32_16x16x32_bf16(af[i], bfr[j], acc[i][j], 0, 0, 0);
        }
        __syncthreads();
    }

    #pragma unroll
    for (int i = 0; i < 4; i++) {
        #pragma unroll
        for (int r = 0; r < 4; r++) {
            int m = m0 + wr + i * 16 + lg * 4 + r;
            #pragma unroll
            for (int j = 0; j < 4; j++) {
                int n = n0 + wc + j * 16 + lr;
                float vv = acc[i][j][r];
                if (EPI == 1) vv += X[(size_t)m * N + n];
                if (EPI == 2) { vv += X[n]; vv = gelu_f(vv); }
                if (EPI == 3) vv += X[n];
                if constexpr (sizeof(TC) == 2) C[(size_t)m * N + n] = (TC)f2b(vv);
                else                            C[(size_t)m * N + n] = vv;
            }
        }
    }
}

// ---------------- MFMA flash attention, swapped QK^T, in-lane softmax --------
// 1-D grid 512 blocks, 256 threads = 4 waves; each wave owns 16 q-rows.
// XCD-bijective remap: each XCD owns 2 complete (h,b) groups -> K/V stay in
// its L2 (saves ~8x K/V HBM re-fetch). Vt stores XOR-swizzled (bank spread).
__global__ __launch_bounds__(256) void attn_mfma_kernel(const unsigned short* __restrict__ q,
                                                        const unsigned short* __restrict__ k,
                                                        const unsigned short* __restrict__ v,
                                                        unsigned short* __restrict__ o) {
    constexpr int LDK = 72;
    constexpr int NT  = Sc / 64;
    __shared__ unsigned short Ks[2][64 * LDK];   // [key][d]
    __shared__ unsigned short Vt[2][64 * LDK];   // [d][key^swz]
    __shared__ unsigned short Ps[64 * LDK];      // per-wave [q][key]

    // bijective XCD swizzle: flat%8 = XCD; each XCD gets 64 consecutive wg
    int flat = blockIdx.x;
    int wg = (flat & 7) * 64 + (flat >> 3);
    int qt = wg & 31;
    int hb = wg >> 5;            // 0..15
    int hh = hb & 7, b = hb >> 3;

    int q0 = qt * 64;
    int tid = threadIdx.x;
    int wid = tid >> 6, lane = tid & 63;
    int lr = lane & 15, lg = lane >> 4;

    const unsigned short* kbase = k + (size_t)(b * Sc) * Hc + hh * 64;
    const unsigned short* vbase = v + (size_t)(b * Sc) * Hc + hh * 64;

    // Q fragment (B-operand): col=q=lr, k-elem d=32s+8lg+j
    bf16x8 qf[2];
    {
        const unsigned short* qrow = q + ((size_t)(b * Sc + q0 + wid * 16 + lr)) * Hc + hh * 64;
        qf[0] = *(const bf16x8*)&qrow[8 * lg];
        qf[1] = *(const bf16x8*)&qrow[32 + 8 * lg];
    }

    // staging geometry
    int krow = tid >> 3;            // 0..31
    int kcol = (tid & 7) * 8;       // 0..56
    int vk2  = (tid >> 4) * 2;      // 0..30
    int vd4  = (tid & 15) * 4;      // 0..60

    bf16x8 kr[2];
    ushort4 va[2], vb2[2];

    auto load_tile = [&](int kt) {
        #pragma unroll
        for (int p = 0; p < 2; p++) {
            kr[p] = *(const bf16x8*)&kbase[(size_t)(kt * 64 + p * 32 + krow) * Hc + kcol];
            const unsigned short* vp = &vbase[(size_t)(kt * 64 + p * 32 + vk2) * Hc + vd4];
            va[p]  = *(const ushort4*)vp;
            vb2[p] = *(const ushort4*)(vp + Hc);
        }
    };
    auto vswz = [](int d, int c) { return c ^ (8 * ((d >> 3) & 7)); };
    auto store_tile = [&](int bu) {
        #pragma unroll
        for (int p = 0; p < 2; p++) {
            *(bf16x8*)&Ks[bu][(p * 32 + krow) * LDK + kcol] = kr[p];
            int k2 = p * 32 + vk2;
            *(ushort2*)&Vt[bu][(vd4 + 0) * LDK + vswz(vd4 + 0, k2)] = (ushort2){va[p].x, vb2[p].x};
            *(ushort2*)&Vt[bu][(vd4 + 1) * LDK + vswz(vd4 + 1, k2)] = (ushort2){va[p].y, vb2[p].y};
            *(ushort2*)&Vt[bu][(vd4 + 2) * LDK + vswz(vd4 + 2, k2)] = (ushort2){va[p].z, vb2[p].z};
            *(ushort2*)&Vt[bu][(vd4 + 3) * LDK + vswz(vd4 + 3, k2)] = (ushort2){va[p].w, vb2[p].w};
        }
    };

    f32x4 Oacc[4];
    #pragma unroll
    for (int nb = 0; nb < 4; nb++) Oacc[nb] = (f32x4){0.f, 0.f, 0.f, 0.f};
    float mrun = -1e30f, lrun = 0.f;   // per-lane: q-row = lr
    const float scale = 0.125f;

    load_tile(0);
    store_tile(0);
    __syncthreads();

    for (int kt = 0; kt < NT; kt++) {
        int cur = kt & 1;
        if (kt + 1 < NT) load_tile(kt + 1);   // prefetch (vmcnt pending)

        // ---- S^T = K Q^T : sacc[kb] row=key(lg*4+r), col=q(lr) ----
        f32x4 sacc[4];
        #pragma unroll
        for (int kb = 0; kb < 4; kb++) sacc[kb] = (f32x4){0.f, 0.f, 0.f, 0.f};
        __builtin_amdgcn_s_setprio(1);
        #pragma unroll
        for (int kb = 0; kb < 4; kb++) {
            #pragma unroll
            for (int s = 0; s < 2; s++) {
                bf16x8 kf = *(const bf16x8*)&Ks[cur][(kb * 16 + lr) * LDK + 32 * s + 8 * lg];
                sacc[kb] = __builtin_amdgcn_mfma_f32_16x16x32_bf16(kf, qf[s], sacc[kb], 0, 0, 0);
            }
        }
        __builtin_amdgcn_s_setprio(0);

        // ---- in-lane softmax (16 scores of q-row lr live in this lane) ----
        float z[4][4];
        float mt = -1e30f;
        #pragma unroll
        for (int kb = 0; kb < 4; kb++)
            #pragma unroll
            for (int r = 0; r < 4; r++) {
                z[kb][r] = sacc[kb][r] * scale;
                mt = fmaxf(mt, z[kb][r]);
            }
        mt = fmaxf(mt, __shfl_xor(mt, 16));
        mt = fmaxf(mt, __shfl_xor(mt, 32));
        float mnew = fmaxf(mrun, mt);
        float sc = __expf(mrun - mnew);
        float ps = 0.f;
        float pv[4][4];
        #pragma unroll
        for (int kb = 0; kb < 4; kb++)
            #pragma unroll
            for (int r = 0; r < 4; r++) {
                pv[kb][r] = __expf(z[kb][r] - mnew);
                ps += pv[kb][r];
            }
        ps += __shfl_xor(ps, 16);
        ps += __shfl_xor(ps, 32);
        lrun = lrun * sc + ps;
        mrun = mnew;

        // ---- P -> LDS (wave-local): row q=lr, cols kb*16+lg*4+(0..3) ----
        #pragma unroll
        for (int kb = 0; kb < 4; kb++) {
            unsigned lo = cvt_pk_bf16(pv[kb][0], pv[kb][1]);
            unsigned hi = cvt_pk_bf16(pv[kb][2], pv[kb][3]);
            *(uint2*)&Ps[(wid * 16 + lr) * LDK + kb * 16 + lg * 4] = (uint2){lo, hi};
        }
        asm volatile("s_waitcnt lgkmcnt(0)" ::: "memory");
        __builtin_amdgcn_sched_barrier(0);

        // broadcast rescale factor to C-layout rows (q = lg*4+r)
        float scb[4];
        #pragma unroll
        for (int r = 0; r < 4; r++) scb[r] = __shfl(sc, lg * 4 + r);

        // ---- O = O*sc + P V ----
        bf16x8 pf0 = *(const bf16x8*)&Ps[(wid * 16 + lr) * LDK + 8 * lg];
        bf16x8 pf1 = *(const bf16x8*)&Ps[(wid * 16 + lr) * LDK + 32 + 8 * lg];
        __builtin_amdgcn_s_setprio(1);
        #pragma unroll
        for (int nb = 0; nb < 4; nb++) {
            f32x4 oa = Oacc[nb];
            #pragma unroll
            for (int r = 0; r < 4; r++) oa[r] *= scb[r];
            int vrow = nb * 16 + lr;
            bf16x8 vf0 = *(const bf16x8*)&Vt[cur][vrow * LDK + vswz(vrow, 8 * lg)];
            bf16x8 vf1 = *(const bf16x8*)&Vt[cur][vrow * LDK + vswz(vrow, 32 + 8 * lg)];
            oa = __builtin_amdgcn_mfma_f32_16x16x32_bf16(pf0, vf0, oa, 0, 0, 0);
            oa = __builtin_amdgcn_mfma_f32_16x16x32_bf16(pf1, vf1, oa, 0, 0, 0);
            Oacc[nb] = oa;
        }
        __builtin_amdgcn_s_setprio(0);

        if (kt + 1 < NT) store_tile(cur ^ 1);  // compiler inserts vmcnt waits
        __syncthreads();
    }

    // ---- epilogue ----
    float linv = 1.0f / lrun;
    unsigned short* ob = o + ((size_t)(b * Sc + q0 + wid * 16)) * Hc + hh * 64;
    #pragma unroll
    for (int r = 0; r < 4; r++) {
        float invB = __shfl(linv, lg * 4 + r);
        #pragma unroll
        for (int nb = 0; nb < 4; nb++) {
            ob[(size_t)(lg * 4 + r) * Hc + nb * 16 + lr] = f2b(Oacc[nb][r] * invB);
        }
    }
}

// ---------------- Router GEMM + softmax + top-2 ------------------------------
__global__ __launch_bounds__(256) void router_top2_kernel(const float* __restrict__ x2,
                                                          const float* __restrict__ wr,
                                                          int* __restrict__ ef,
                                                          float* __restrict__ gf) {
    int t = blockIdx.x * 4 + (threadIdx.x >> 6);
    int l = threadIdx.x & 63;
    const float* xr = x2 + (size_t)t * Hc;
    float acc = 0.f;
    for (int hhh = 0; hhh < Hc; hhh++) acc += xr[hhh] * wr[hhh * Ec + l];

    float mx = acc;
    for (int off = 32; off; off >>= 1) mx = fmaxf(mx, __shfl_xor(mx, off));
    float p = expf(acc - mx);
    float sum = p;
    for (int off = 32; off; off >>= 1) sum += __shfl_xor(sum, off);
    p /= sum;

    float v1 = p; int i1 = l;
    for (int off = 32; off; off >>= 1) {
        float ov = __shfl_xor(v1, off);
        int   oi = __shfl_xor(i1, off);
        if (ov > v1 || (ov == v1 && oi < i1)) { v1 = ov; i1 = oi; }
    }
    float v2 = (l == i1) ? -INFINITY : p; int i2 = l;
    for (int off = 32; off; off >>= 1) {
        float ov = __shfl_xor(v2, off);
        int   oi = __shfl_xor(i2, off);
        if (ov > v2 || (ov == v2 && oi < i2)) { v2 = ov; i2 = oi; }
    }
    if (l == 0) {
        float inv = 1.0f / (v1 + v2);
        ef[t * 2]     = i1;
        ef[t * 2 + 1] = i2;
        gf[t * 2]     = v1 * inv;
        gf[t * 2 + 1] = v2 * inv;
    }
}

// ---------------- pos: rank of each slot within its expert (slot order) ------
__global__ __launch_bounds__(256) void pos_kernel(const int* __restrict__ ef,
                                                  int* __restrict__ pos) {
    int e = blockIdx.x;
    __shared__ int cnts[257];
    int tid = threadIdx.x;
    int base = tid * 32;  // 8192 / 256
    int c = 0;
    for (int i = 0; i < 32; i++) c += (ef[base + i] == e) ? 1 : 0;
    cnts[tid + 1] = c;
    if (tid == 0) cnts[0] = 0;
    __syncthreads();
    if (tid == 0) {
        for (int i = 1; i <= 256; i++) cnts[i] += cnts[i - 1];
    }
    __syncthreads();
    int run = cnts[tid];
    for (int i = 0; i < 32; i++) {
        if (ef[base + i] == e) pos[base + i] = run++;
    }
}

// ---------------- dispatch: copy kept tokens into expert buffers (bf16) ------
__global__ __launch_bounds__(128) void dispatch_kernel(const float* __restrict__ x2,
                                                       const int* __restrict__ ef,
                                                       const int* __restrict__ pos,
                                                       unsigned short* __restrict__ buf) {
    int s = blockIdx.x;
    int p = pos[s];
    if (p >= Cap) return;
    int e = ef[s];
    int t = s >> 1;
    float4 vv = ((const float4*)(x2 + (size_t)t * Hc))[threadIdx.x];
    ushort4 o;
    o.x = f2b(vv.x); o.y = f2b(vv.y); o.z = f2b(vv.z); o.w = f2b(vv.w);
    ((ushort4*)(buf + ((size_t)e * Cap + p) * Hc))[threadIdx.x] = o;
}

// ---------------- combine: out = xa + sum_k gate * y[ef,pos] -----------------
__global__ __launch_bounds__(128) void combine_kernel(const float* __restrict__ xa,
                                                      const float* __restrict__ y,
                                                      const int* __restrict__ ef,
                                                      const int* __restrict__ pos,
                                                      const float* __restrict__ gf,
                                                      float* __restrict__ out) {
    int t = blockIdx.x;
    int d = threadIdx.x;
    float4 acc = ((const float4*)(xa + (size_t)t * Hc))[d];
    #pragma unroll
    for (int kk = 0; kk < 2; kk++) {
        int s = t * 2 + kk;
        int p = pos[s];
        if (p < Cap) {
            float w = gf[s];
            float4 yv = ((const float4*)(y + ((size_t)ef[s] * Cap + p) * Hc))[d];
            acc.x += w * yv.x;
            acc.y += w * yv.y;
            acc.z += w * yv.z;
            acc.w += w * yv.w;
        }
    }
    ((float4*)(out + (size_t)t * Hc))[d] = acc;
}

// ---------------- launch -----------------------------------------------------
extern "C" void kernel_launch(void* const* d_in, const int* in_sizes, int n_in,
                              void* d_out, int out_size, void* d_ws, size_t ws_size,
                              hipStream_t stream) {
    const float* x     = (const float*)d_in[0];
    const float* ln1_g = (const float*)d_in[1];
    const float* ln1_b = (const float*)d_in[2];
    const float* wq    = (const float*)d_in[3];
    const float* wk    = (const float*)d_in[4];
    const float* wv    = (const float*)d_in[5];
    const float* wo    = (const float*)d_in[6];
    const float* ln2_g = (const float*)d_in[7];
    const float* ln2_b = (const float*)d_in[8];
    const float* wr    = (const float*)d_in[9];
    const float* w1    = (const float*)d_in[10];
    const float* b1    = (const float*)d_in[11];
    const float* w2    = (const float*)d_in[12];
    const float* b2    = (const float*)d_in[13];
    float* out = (float*)d_out;

    const size_t TH   = (size_t)Tc * Hc;        // 2,097,152
    const size_t ECH  = (size_t)Ec * Cap * Hc;  // 8,388,608
    const size_t ECF  = (size_t)Ec * Cap * Fc;  // 33,554,432
    const size_t HF   = (size_t)Hc * Fc;        // 1,048,576 (per-expert w size)

    // ---- workspace carve (bytes) ----
    char* wsb = (char*)d_ws;
    size_t off = 0;
    auto alloc = [&](size_t bytes) { size_t r = off; off = (off + bytes + 255) & ~(size_t)255; return r; };
    size_t x1b_off = alloc(TH * 2);       // bf16 x1
    size_t qkv_off = alloc(TH * 2 * 3);   // bf16 q|k|v contiguous
    size_t ab_off  = alloc(TH * 2);       // bf16 attention output
    size_t xa_off  = alloc(TH * 4);       // fp32 attn residual out
    size_t x2_off  = alloc(TH * 4);       // fp32 LN2 out
    size_t ef_off  = alloc((size_t)Tc * 2 * 4);
    size_t pos_off = alloc((size_t)Tc * 2 * 4);
    size_t gf_off  = alloc((size_t)Tc * 2 * 4);
    size_t buf_off = alloc(ECH * 2);      // bf16 expert inputs
    size_t h_off   = alloc(ECF * 2);      // bf16 h (all experts)
    size_t y_off   = alloc(ECH * 4);      // fp32 expert outputs
    if (ws_size < off) return;            // insufficient workspace

    unsigned short* x1b  = (unsigned short*)(wsb + x1b_off);
    unsigned short* qb   = (unsigned short*)(wsb + qkv_off);
    unsigned short* kb   = qb + TH;
    unsigned short* vb   = qb + 2 * TH;
    unsigned short* ab   = (unsigned short*)(wsb + ab_off);
    float* xa  = (float*)(wsb + xa_off);
    float* x2  = (float*)(wsb + x2_off);
    int*   ef  = (int*)(wsb + ef_off);
    int*   pos = (int*)(wsb + pos_off);
    float* gf  = (float*)(wsb + gf_off);
    unsigned short* bufb = (unsigned short*)(wsb + buf_off);
    unsigned short* h    = (unsigned short*)(wsb + h_off);
    float* y = (float*)(wsb + y_off);

    dim3 blk(256);

    // 1. LN1 -> bf16
    ln_kernel<unsigned short><<<Tc, blk, 0, stream>>>(x, ln1_g, ln1_b, x1b);

    // 2. fused QKV projections: one launch, z selects {wq,wk,wv} -> q|k|v
    gemm_mfma<128, 0, 0, unsigned short><<<dim3(Hc / 128, Tc / 128, 3), blk, 0, stream>>>(
        x1b, wq, qb, nullptr, Tc, Hc, Hc, 0, 0, (long)TH, 0, wk, wv);

    // 3. attention -> bf16 ab (1-D grid, XCD-swizzled)
    attn_mfma_kernel<<<dim3(512), blk, 0, stream>>>(qb, kb, vb, ab);

    // 4. output projection + residual: xa = attn @ wo + x
    gemm_mfma<128, 1, 0, float><<<dim3(Hc / 128, Tc / 128, 1), blk, 0, stream>>>(
        ab, wo, xa, x, Tc, Hc, Hc, 0, 0, 0, 0, nullptr, nullptr);

    // 5. LN2 -> fp32
    ln_kernel<float><<<Tc, blk, 0, stream>>>(xa, ln2_g, ln2_b, x2);

    // 6. router + top2
    router_top2_kernel<<<Tc / 4, blk, 0, stream>>>(x2, wr, ef, gf);

    // 7. positions within expert queues
    pos_kernel<<<Ec, blk, 0, stream>>>(ef, pos);

    // 8. dispatch tokens to expert buffers (bf16)
    dispatch_kernel<<<Tc * 2, dim3(128), 0, stream>>>(x2, ef, pos, bufb);

    // 9. expert GEMM1: h = gelu(buf @ w1 + b1), BM=256 (w1 read exactly once),
    //    XCD-swizzled so each expert's 16 N-blocks share an L2
    gemm_mfma<256, 2, 1, unsigned short><<<dim3(Fc / 128, Cap / 256, Ec), dim3(512), 0, stream>>>(
        bufb, w1, h, b1, Cap, Fc, Hc,
        (long)Cap * Hc, (long)HF, (long)Cap * Fc, (long)Fc, nullptr, nullptr);

    // 10. expert GEMM2: y = h @ w2 + b2 (XCD-swizzled)
    gemm_mfma<256, 3, 1, float><<<dim3(Hc / 128, Cap / 256, Ec), dim3(512), 0, stream>>>(
        h, w2, y, b2, Cap, Hc, Fc,
        (long)Cap * Fc, (long)HF, (long)Cap * Hc, (long)Hc, nullptr, nullptr);

    // 11. combine + final residual
    combine_kernel<<<Tc, dim3(128), 0, stream>>>(xa, y, ef, pos, gf, out);
}

// Round 7
// 348.261 us; speedup vs baseline: 8.1422x; 1.0060x over previous
//
#include <hip/hip_runtime.h>
#include <hip/hip_bf16.h>
#include <math.h>

// Problem constants (from reference setup_inputs)
constexpr int Bc  = 2;
constexpr int Sc  = 2048;
constexpr int Hc  = 512;
constexpr int NHc = 8;
constexpr int Tc  = Bc * Sc;      // 4096 tokens
constexpr int Ec  = 64;           // experts
constexpr int Fc  = 2048;         // ffn dim
constexpr int Cap = 256;          // capacity = 2 * T * 2 / E

typedef __attribute__((ext_vector_type(8))) short bf16x8;
typedef __attribute__((ext_vector_type(4))) float f32x4;

__device__ __forceinline__ unsigned short f2b(float f) {
    union { float f; unsigned u; } v; v.f = f;
    unsigned r = v.u + 0x7FFF + ((v.u >> 16) & 1);   // RTNE
    return (unsigned short)(r >> 16);
}

__device__ __forceinline__ unsigned cvt_pk_bf16(float lo, float hi) {
    unsigned r;
    asm volatile("v_cvt_pk_bf16_f32 %0, %1, %2" : "=v"(r) : "v"(lo), "v"(hi));
    return r;
}

__device__ __forceinline__ float gelu_f(float x) {
    // jax.nn.gelu default approximate=True (tanh)
    float x3 = x * x * x;
    return 0.5f * x * (1.0f + tanhf(0.7978845608028654f * (x + 0.044715f * x3)));
}

// ---------------- LayerNorm: one block per row (H=512, 256 threads) ----------
template <typename TO>
__global__ __launch_bounds__(256) void ln_kernel(const float* __restrict__ x,
                                                 const float* __restrict__ g,
                                                 const float* __restrict__ b,
                                                 TO* __restrict__ o) {
    int t = blockIdx.x;
    const float* row = x + (size_t)t * Hc;
    int tid = threadIdx.x;
    float v0 = row[tid];
    float v1 = row[tid + 256];
    float s = v0 + v1, s2 = v0 * v0 + v1 * v1;
    for (int off = 32; off; off >>= 1) {
        s  += __shfl_down(s,  off);
        s2 += __shfl_down(s2, off);
    }
    __shared__ float ls[4], ls2[4];
    int wid = tid >> 6, lane = tid & 63;
    if (lane == 0) { ls[wid] = s; ls2[wid] = s2; }
    __syncthreads();
    if (tid == 0) {
        float a = 0.f, a2 = 0.f;
        for (int i = 0; i < 4; i++) { a += ls[i]; a2 += ls2[i]; }
        ls[0] = a; ls2[0] = a2;
    }
    __syncthreads();
    float mean = ls[0] * (1.0f / Hc);
    float var  = ls2[0] * (1.0f / Hc) - mean * mean;
    float r = rsqrtf(var + 1e-5f);
    float o0 = (v0 - mean) * r * g[tid]       + b[tid];
    float o1 = (v1 - mean) * r * g[tid + 256] + b[tid + 256];
    if constexpr (sizeof(TO) == 2) {
        o[(size_t)t * Hc + tid]       = (TO)f2b(o0);
        o[(size_t)t * Hc + tid + 256] = (TO)f2b(o1);
    } else {
        o[(size_t)t * Hc + tid]       = o0;
        o[(size_t)t * Hc + tid + 256] = o1;
    }
}

// ---------------- MFMA bf16 GEMM with in-LDS weight transpose ---------------
// C[M,N] = A[M,K](bf16) @ W[K,N](fp32 row-major), batched via blockIdx.z.
// If Wb != null: W selected per-z from {W, Wb, Wc} (QKV fusion), C += z*sC.
// SWZ=1: bijective XCD remap of (x,z) so same-z (same-expert) blocks share
// an XCD L2 (A-tile fetched once per XCD). Requires gridDim.y==1, nwg%8==0.
// EPI: 0=none, 1=+X[m*N+n] (fp32), 2=gelu(acc+X[n]) -> bf16, 3=acc+X[n] -> fp32
template <int BM, int EPI, int SWZ, typename TC>
__global__ __launch_bounds__(BM * 2) void gemm_mfma(const unsigned short* __restrict__ A,
                                                    const float* __restrict__ W,
                                                    TC* __restrict__ C,
                                                    const float* __restrict__ X,
                                                    int M, int N, int K,
                                                    long sA, long sW, long sC, long sX,
                                                    const float* __restrict__ Wb,
                                                    const float* __restrict__ Wc) {
    int bx = blockIdx.x, bz = blockIdx.z, by = blockIdx.y;
    if (SWZ) {
        int gx = gridDim.x;
        int nwg = gx * gridDim.z;
        int flat = bx + gx * bz;
        int wg = (flat & 7) * (nwg >> 3) + (flat >> 3);
        bx = wg % gx; bz = wg / gx;
    }
    A += (size_t)bz * sA;
    if (Wb) W = (bz == 0) ? W : ((bz == 1) ? Wb : Wc);
    else    W += (size_t)bz * sW;
    C += (size_t)bz * sC;
    if (X) X += (size_t)bz * sX;
    int m0 = by * BM, n0 = bx * 128;

    __shared__ unsigned short As[BM * 72];
    __shared__ unsigned short Bs[128 * 72];

    int tid = threadIdx.x;
    int wid = tid >> 6, lane = tid & 63;
    int wr = (wid >> 1) * 64, wc = (wid & 1) * 64;
    int lr = lane & 15, lg = lane >> 4;

    f32x4 acc[4][4];
    #pragma unroll
    for (int i = 0; i < 4; i++)
        #pragma unroll
        for (int j = 0; j < 4; j++) acc[i][j] = (f32x4){0.f, 0.f, 0.f, 0.f};

    for (int k0 = 0; k0 < K; k0 += 64) {
        // ---- stage A rows (bf16, vector) ----
        #pragma unroll
        for (int p = 0; p < 4; p++) {
            int e = p * 16 * BM + tid * 8;
            int row = e >> 6, col = e & 63;
            *(bf16x8*)&As[row * 72 + col] =
                *(const bf16x8*)&A[(size_t)(m0 + row) * K + k0 + col];
        }
        // ---- stage W tile [64][128] fp32 -> Bs[n][k] bf16 (transposed) ----
        #pragma unroll
        for (int p = 0; p < 512 / BM; p++) {
            int kp = (tid >> 5) + p * (BM / 16);   // k-pair 0..31
            int c  = (tid & 31) * 4;               // col base 0..124
            const float* w0 = &W[(size_t)(k0 + 2 * kp) * N + n0 + c];
            float4 a = *(const float4*)w0;
            float4 b = *(const float4*)(w0 + N);
            int qz = 8 * ((c >> 3) & 7);           // uniform over c..c+3
            int kof = (2 * kp) ^ qz;
            *(ushort2*)&Bs[(c + 0) * 72 + kof] = (ushort2){f2b(a.x), f2b(b.x)};
            *(ushort2*)&Bs[(c + 1) * 72 + kof] = (ushort2){f2b(a.y), f2b(b.y)};
            *(ushort2*)&Bs[(c + 2) * 72 + kof] = (ushort2){f2b(a.z), f2b(b.z)};
            *(ushort2*)&Bs[(c + 3) * 72 + kof] = (ushort2){f2b(a.w), f2b(b.w)};
        }
        __syncthreads();
        #pragma unroll
        for (int kk = 0; kk < 64; kk += 32) {
            bf16x8 af[4], bfr[4];
            #pragma unroll
            for (int i = 0; i < 4; i++) {
                af[i] = *(const bf16x8*)&As[(wr + i * 16 + lr) * 72 + kk + 8 * lg];
                int nrow = wc + i * 16 + lr;
                int qq = 8 * ((nrow >> 3) & 7);
                bfr[i] = *(const bf16x8*)&Bs[nrow * 72 + ((kk + 8 * lg) ^ qq)];
            }
            #pragma unroll
            for (int i = 0; i < 4; i++)
                #pragma unroll
                for (int j = 0; j < 4; j++)
                    acc[i][j] = __builtin_amdgcn_mfma_f32_16x16x32_bf16(af[i], bfr[j], acc[i][j], 0, 0, 0);
        }
        __syncthreads();
    }

    #pragma unroll
    for (int i = 0; i < 4; i++) {
        #pragma unroll
        for (int r = 0; r < 4; r++) {
            int m = m0 + wr + i * 16 + lg * 4 + r;
            #pragma unroll
            for (int j = 0; j < 4; j++) {
                int n = n0 + wc + j * 16 + lr;
                float vv = acc[i][j][r];
                if (EPI == 1) vv += X[(size_t)m * N + n];
                if (EPI == 2) { vv += X[n]; vv = gelu_f(vv); }
                if (EPI == 3) vv += X[n];
                if constexpr (sizeof(TC) == 2) C[(size_t)m * N + n] = (TC)f2b(vv);
                else                            C[(size_t)m * N + n] = vv;
            }
        }
    }
}

// ---------------- MFMA flash attention v3 ------------------------------------
// Swapped QK^T + in-lane exp2 softmax + defer-max + P redistribution entirely
// in-register via cvt_pk + permlane32/16_swap (no P LDS round-trip, no fence).
// 1-D grid 512 blocks (XCD-bijective), 256 threads = 4 waves, 16 q-rows/wave.
__global__ __launch_bounds__(256) void attn_mfma_kernel(const unsigned short* __restrict__ q,
                                                        const unsigned short* __restrict__ k,
                                                        const unsigned short* __restrict__ v,
                                                        unsigned short* __restrict__ o) {
    constexpr int LDK = 72;
    constexpr int NT  = Sc / 64;
    __shared__ unsigned short Ks[2][64 * LDK];   // [key][d]
    __shared__ unsigned short Vt[2][64 * LDK];   // [d][key^swz]

    // bijective XCD swizzle: flat%8 = XCD; each XCD gets 64 consecutive wg
    int flat = blockIdx.x;
    int wg = (flat & 7) * 64 + (flat >> 3);
    int qt = wg & 31;
    int hb = wg >> 5;            // 0..15
    int hh = hb & 7, b = hb >> 3;

    int q0 = qt * 64;
    int tid = threadIdx.x;
    int wid = tid >> 6, lane = tid & 63;
    int lr = lane & 15, lg = lane >> 4;

    const unsigned short* kbase = k + (size_t)(b * Sc) * Hc + hh * 64;
    const unsigned short* vbase = v + (size_t)(b * Sc) * Hc + hh * 64;

    // Q fragment (B-operand): col=q=lr, k-elem d=32s+8lg+j
    bf16x8 qf[2];
    {
        const unsigned short* qrow = q + ((size_t)(b * Sc + q0 + wid * 16 + lr)) * Hc + hh * 64;
        qf[0] = *(const bf16x8*)&qrow[8 * lg];
        qf[1] = *(const bf16x8*)&qrow[32 + 8 * lg];
    }

    // staging geometry
    int krow = tid >> 3;            // 0..31
    int kcol = (tid & 7) * 8;       // 0..56
    int vk2  = (tid >> 4) * 2;      // 0..30
    int vd4  = (tid & 15) * 4;      // 0..60

    bf16x8 kr[2];
    ushort4 va[2], vb2[2];

    auto load_tile = [&](int kt) {
        #pragma unroll
        for (int p = 0; p < 2; p++) {
            kr[p] = *(const bf16x8*)&kbase[(size_t)(kt * 64 + p * 32 + krow) * Hc + kcol];
            const unsigned short* vp = &vbase[(size_t)(kt * 64 + p * 32 + vk2) * Hc + vd4];
            va[p]  = *(const ushort4*)vp;
            vb2[p] = *(const ushort4*)(vp + Hc);
        }
    };
    auto vswz = [](int d, int c) { return c ^ (8 * ((d >> 3) & 7)); };
    auto store_tile = [&](int bu) {
        #pragma unroll
        for (int p = 0; p < 2; p++) {
            *(bf16x8*)&Ks[bu][(p * 32 + krow) * LDK + kcol] = kr[p];
            int k2 = p * 32 + vk2;
            *(ushort2*)&Vt[bu][(vd4 + 0) * LDK + vswz(vd4 + 0, k2)] = (ushort2){va[p].x, vb2[p].x};
            *(ushort2*)&Vt[bu][(vd4 + 1) * LDK + vswz(vd4 + 1, k2)] = (ushort2){va[p].y, vb2[p].y};
            *(ushort2*)&Vt[bu][(vd4 + 2) * LDK + vswz(vd4 + 2, k2)] = (ushort2){va[p].z, vb2[p].z};
            *(ushort2*)&Vt[bu][(vd4 + 3) * LDK + vswz(vd4 + 3, k2)] = (ushort2){va[p].w, vb2[p].w};
        }
    };

    f32x4 Oacc[4];
    #pragma unroll
    for (int nb = 0; nb < 4; nb++) Oacc[nb] = (f32x4){0.f, 0.f, 0.f, 0.f};
    float mrun = -1e30f, lrun = 0.f;   // per-lane (q-row = lr), exp2 domain
    const float SCL2 = 0.125f * 1.4426950408889634f;  // dh^-0.5 * log2(e)

    load_tile(0);
    store_tile(0);
    __syncthreads();

    for (int kt = 0; kt < NT; kt++) {
        int cur = kt & 1;
        if (kt + 1 < NT) load_tile(kt + 1);   // prefetch (vmcnt pending)

        // ---- S^T = K Q^T : sacc[kb] row=key(lg*4+r), col=q(lr) ----
        f32x4 sacc[4];
        #pragma unroll
        for (int kb = 0; kb < 4; kb++) sacc[kb] = (f32x4){0.f, 0.f, 0.f, 0.f};
        __builtin_amdgcn_s_setprio(1);
        #pragma unroll
        for (int kb = 0; kb < 4; kb++) {
            #pragma unroll
            for (int s = 0; s < 2; s++) {
                bf16x8 kf = *(const bf16x8*)&Ks[cur][(kb * 16 + lr) * LDK + 32 * s + 8 * lg];
                sacc[kb] = __builtin_amdgcn_mfma_f32_16x16x32_bf16(kf, qf[s], sacc[kb], 0, 0, 0);
            }
        }
        __builtin_amdgcn_s_setprio(0);

        // ---- in-lane softmax, exp2 domain; lane holds 16 scores of q=lr ----
        float z[4][4];
        float mt = -1e30f;
        #pragma unroll
        for (int kb = 0; kb < 4; kb++)
            #pragma unroll
            for (int r = 0; r < 4; r++) {
                z[kb][r] = sacc[kb][r] * SCL2;
                mt = fmaxf(mt, z[kb][r]);
            }
        mt = fmaxf(mt, __shfl_xor(mt, 16));
        mt = fmaxf(mt, __shfl_xor(mt, 32));

        bool defer = __all(mt - mrun <= 11.0f);   // P bounded by 2^11
        float pv[4][4];
        float ps = 0.f;
        if (defer) {
            #pragma unroll
            for (int kb = 0; kb < 4; kb++)
                #pragma unroll
                for (int r = 0; r < 4; r++) {
                    pv[kb][r] = __builtin_amdgcn_exp2f(z[kb][r] - mrun);
                    ps += pv[kb][r];
                }
            ps += __shfl_xor(ps, 16);
            ps += __shfl_xor(ps, 32);
            lrun += ps;
        } else {
            float mnew = fmaxf(mrun, mt);
            float sc = __builtin_amdgcn_exp2f(mrun - mnew);
            #pragma unroll
            for (int kb = 0; kb < 4; kb++)
                #pragma unroll
                for (int r = 0; r < 4; r++) {
                    pv[kb][r] = __builtin_amdgcn_exp2f(z[kb][r] - mnew);
                    ps += pv[kb][r];
                }
            ps += __shfl_xor(ps, 16);
            ps += __shfl_xor(ps, 32);
            lrun = lrun * sc + ps;
            mrun = mnew;
            // rescale O (rows q = lg*4+r need sc from lane lr' = lg*4+r)
            float scb[4];
            #pragma unroll
            for (int r = 0; r < 4; r++) scb[r] = __shfl(sc, lg * 4 + r);
            #pragma unroll
            for (int nb = 0; nb < 4; nb++)
                #pragma unroll
                for (int r = 0; r < 4; r++) Oacc[nb][r] *= scb[r];
        }

        // ---- P -> A-operand layout fully in-register ----
        // pack: d[kb][h] = keys (16kb+4lg+2h, +1) of q=lr
        unsigned d_[4][2];
        #pragma unroll
        for (int kb = 0; kb < 4; kb++) {
            d_[kb][0] = cvt_pk_bf16(pv[kb][0], pv[kb][1]);
            d_[kb][1] = cvt_pk_bf16(pv[kb][2], pv[kb][3]);
        }
        // per (s,h): x=d[2s][h], y=d[2s+1][h];
        // permlane32_swap then permlane16_swap => x=T01(slot t=0,1), y=T23(t=2,3)
        unsigned pfw[2][4];   // [s][t-dword]
        #pragma unroll
        for (int s = 0; s < 2; s++) {
            #pragma unroll
            for (int h = 0; h < 2; h++) {
                unsigned xx = d_[2 * s][h], yy = d_[2 * s + 1][h];
                asm volatile("v_permlane32_swap_b32 %0, %1" : "+v"(xx), "+v"(yy));
                asm volatile("v_permlane16_swap_b32 %0, %1" : "+v"(xx), "+v"(yy));
                pfw[s][h]     = xx;   // t = h
                pfw[s][2 + h] = yy;   // t = 2 + h
            }
        }
        bf16x8 pf0, pf1;
        *(unsigned*)&((short*)&pf0)[0] = pfw[0][0];
        *(unsigned*)&((short*)&pf0)[2] = pfw[0][1];
        *(unsigned*)&((short*)&pf0)[4] = pfw[0][2];
        *(unsigned*)&((short*)&pf0)[6] = pfw[0][3];
        *(unsigned*)&((short*)&pf1)[0] = pfw[1][0];
        *(unsigned*)&((short*)&pf1)[2] = pfw[1][1];
        *(unsigned*)&((short*)&pf1)[4] = pfw[1][2];
        *(unsigned*)&((short*)&pf1)[6] = pfw[1][3];

        // ---- O += P V ----
        __builtin_amdgcn_s_setprio(1);
        #pragma unroll
        for (int nb = 0; nb < 4; nb++) {
            f32x4 oa = Oacc[nb];
            int vrow = nb * 16 + lr;
            bf16x8 vf0 = *(const bf16x8*)&Vt[cur][vrow * LDK + vswz(vrow, 8 * lg)];
            bf16x8 vf1 = *(const bf16x8*)&Vt[cur][vrow * LDK + vswz(vrow, 32 + 8 * lg)];
            oa = __builtin_amdgcn_mfma_f32_16x16x32_bf16(pf0, vf0, oa, 0, 0, 0);
            oa = __builtin_amdgcn_mfma_f32_16x16x32_bf16(pf1, vf1, oa, 0, 0, 0);
            Oacc[nb] = oa;
        }
        __builtin_amdgcn_s_setprio(0);

        if (kt + 1 < NT) store_tile(cur ^ 1);  // compiler inserts vmcnt waits
        __syncthreads();
    }

    // ---- epilogue ----
    float linv = 1.0f / lrun;
    unsigned short* ob = o + ((size_t)(b * Sc + q0 + wid * 16)) * Hc + hh * 64;
    #pragma unroll
    for (int r = 0; r < 4; r++) {
        float invB = __shfl(linv, lg * 4 + r);
        #pragma unroll
        for (int nb = 0; nb < 4; nb++) {
            ob[(size_t)(lg * 4 + r) * Hc + nb * 16 + lr] = f2b(Oacc[nb][r] * invB);
        }
    }
}

// ---------------- Router GEMM + softmax + top-2 ------------------------------
__global__ __launch_bounds__(256) void router_top2_kernel(const float* __restrict__ x2,
                                                          const float* __restrict__ wr,
                                                          int* __restrict__ ef,
                                                          float* __restrict__ gf) {
    int t = blockIdx.x * 4 + (threadIdx.x >> 6);
    int l = threadIdx.x & 63;
    const float* xr = x2 + (size_t)t * Hc;
    float acc = 0.f;
    for (int hhh = 0; hhh < Hc; hhh++) acc += xr[hhh] * wr[hhh * Ec + l];

    float mx = acc;
    for (int off = 32; off; off >>= 1) mx = fmaxf(mx, __shfl_xor(mx, off));
    float p = expf(acc - mx);
    float sum = p;
    for (int off = 32; off; off >>= 1) sum += __shfl_xor(sum, off);
    p /= sum;

    float v1 = p; int i1 = l;
    for (int off = 32; off; off >>= 1) {
        float ov = __shfl_xor(v1, off);
        int   oi = __shfl_xor(i1, off);
        if (ov > v1 || (ov == v1 && oi < i1)) { v1 = ov; i1 = oi; }
    }
    float v2 = (l == i1) ? -INFINITY : p; int i2 = l;
    for (int off = 32; off; off >>= 1) {
        float ov = __shfl_xor(v2, off);
        int   oi = __shfl_xor(i2, off);
        if (ov > v2 || (ov == v2 && oi < i2)) { v2 = ov; i2 = oi; }
    }
    if (l == 0) {
        float inv = 1.0f / (v1 + v2);
        ef[t * 2]     = i1;
        ef[t * 2 + 1] = i2;
        gf[t * 2]     = v1 * inv;
        gf[t * 2 + 1] = v2 * inv;
    }
}

// ---------------- pos: rank of each slot within its expert (slot order) ------
__global__ __launch_bounds__(256) void pos_kernel(const int* __restrict__ ef,
                                                  int* __restrict__ pos) {
    int e = blockIdx.x;
    __shared__ int cnts[257];
    int tid = threadIdx.x;
    int base = tid * 32;  // 8192 / 256
    int c = 0;
    for (int i = 0; i < 32; i++) c += (ef[base + i] == e) ? 1 : 0;
    cnts[tid + 1] = c;
    if (tid == 0) cnts[0] = 0;
    __syncthreads();
    if (tid == 0) {
        for (int i = 1; i <= 256; i++) cnts[i] += cnts[i - 1];
    }
    __syncthreads();
    int run = cnts[tid];
    for (int i = 0; i < 32; i++) {
        if (ef[base + i] == e) pos[base + i] = run++;
    }
}

// ---------------- dispatch: copy kept tokens into expert buffers (bf16) ------
__global__ __launch_bounds__(128) void dispatch_kernel(const float* __restrict__ x2,
                                                       const int* __restrict__ ef,
                                                       const int* __restrict__ pos,
                                                       unsigned short* __restrict__ buf) {
    int s = blockIdx.x;
    int p = pos[s];
    if (p >= Cap) return;
    int e = ef[s];
    int t = s >> 1;
    float4 vv = ((const float4*)(x2 + (size_t)t * Hc))[threadIdx.x];
    ushort4 o;
    o.x = f2b(vv.x); o.y = f2b(vv.y); o.z = f2b(vv.z); o.w = f2b(vv.w);
    ((ushort4*)(buf + ((size_t)e * Cap + p) * Hc))[threadIdx.x] = o;
}

// ---------------- combine: out = xa + sum_k gate * y[ef,pos] -----------------
__global__ __launch_bounds__(128) void combine_kernel(const float* __restrict__ xa,
                                                      const float* __restrict__ y,
                                                      const int* __restrict__ ef,
                                                      const int* __restrict__ pos,
                                                      const float* __restrict__ gf,
                                                      float* __restrict__ out) {
    int t = blockIdx.x;
    int d = threadIdx.x;
    float4 acc = ((const float4*)(xa + (size_t)t * Hc))[d];
    #pragma unroll
    for (int kk = 0; kk < 2; kk++) {
        int s = t * 2 + kk;
        int p = pos[s];
        if (p < Cap) {
            float w = gf[s];
            float4 yv = ((const float4*)(y + ((size_t)ef[s] * Cap + p) * Hc))[d];
            acc.x += w * yv.x;
            acc.y += w * yv.y;
            acc.z += w * yv.z;
            acc.w += w * yv.w;
        }
    }
    ((float4*)(out + (size_t)t * Hc))[d] = acc;
}

// ---------------- launch -----------------------------------------------------
extern "C" void kernel_launch(void* const* d_in, const int* in_sizes, int n_in,
                              void* d_out, int out_size, void* d_ws, size_t ws_size,
                              hipStream_t stream) {
    const float* x     = (const float*)d_in[0];
    const float* ln1_g = (const float*)d_in[1];
    const float* ln1_b = (const float*)d_in[2];
    const float* wq    = (const float*)d_in[3];
    const float* wk    = (const float*)d_in[4];
    const float* wv    = (const float*)d_in[5];
    const float* wo    = (const float*)d_in[6];
    const float* ln2_g = (const float*)d_in[7];
    const float* ln2_b = (const float*)d_in[8];
    const float* wr    = (const float*)d_in[9];
    const float* w1    = (const float*)d_in[10];
    const float* b1    = (const float*)d_in[11];
    const float* w2    = (const float*)d_in[12];
    const float* b2    = (const float*)d_in[13];
    float* out = (float*)d_out;

    const size_t TH   = (size_t)Tc * Hc;        // 2,097,152
    const size_t ECH  = (size_t)Ec * Cap * Hc;  // 8,388,608
    const size_t ECF  = (size_t)Ec * Cap * Fc;  // 33,554,432
    const size_t HF   = (size_t)Hc * Fc;        // 1,048,576 (per-expert w size)

    // ---- workspace carve (bytes) ----
    char* wsb = (char*)d_ws;
    size_t off = 0;
    auto alloc = [&](size_t bytes) { size_t r = off; off = (off + bytes + 255) & ~(size_t)255; return r; };
    size_t x1b_off = alloc(TH * 2);       // bf16 x1
    size_t qkv_off = alloc(TH * 2 * 3);   // bf16 q|k|v contiguous
    size_t ab_off  = alloc(TH * 2);       // bf16 attention output
    size_t xa_off  = alloc(TH * 4);       // fp32 attn residual out
    size_t x2_off  = alloc(TH * 4);       // fp32 LN2 out
    size_t ef_off  = alloc((size_t)Tc * 2 * 4);
    size_t pos_off = alloc((size_t)Tc * 2 * 4);
    size_t gf_off  = alloc((size_t)Tc * 2 * 4);
    size_t buf_off = alloc(ECH * 2);      // bf16 expert inputs
    size_t h_off   = alloc(ECF * 2);      // bf16 h (all experts)
    size_t y_off   = alloc(ECH * 4);      // fp32 expert outputs
    if (ws_size < off) return;            // insufficient workspace

    unsigned short* x1b  = (unsigned short*)(wsb + x1b_off);
    unsigned short* qb   = (unsigned short*)(wsb + qkv_off);
    unsigned short* kb   = qb + TH;
    unsigned short* vb   = qb + 2 * TH;
    unsigned short* ab   = (unsigned short*)(wsb + ab_off);
    float* xa  = (float*)(wsb + xa_off);
    float* x2  = (float*)(wsb + x2_off);
    int*   ef  = (int*)(wsb + ef_off);
    int*   pos = (int*)(wsb + pos_off);
    float* gf  = (float*)(wsb + gf_off);
    unsigned short* bufb = (unsigned short*)(wsb + buf_off);
    unsigned short* h    = (unsigned short*)(wsb + h_off);
    float* y = (float*)(wsb + y_off);

    dim3 blk(256);

    // 1. LN1 -> bf16
    ln_kernel<unsigned short><<<Tc, blk, 0, stream>>>(x, ln1_g, ln1_b, x1b);

    // 2. fused QKV projections: one launch, z selects {wq,wk,wv} -> q|k|v
    gemm_mfma<128, 0, 0, unsigned short><<<dim3(Hc / 128, Tc / 128, 3), blk, 0, stream>>>(
        x1b, wq, qb, nullptr, Tc, Hc, Hc, 0, 0, (long)TH, 0, wk, wv);

    // 3. attention -> bf16 ab (1-D grid, XCD-swizzled)
    attn_mfma_kernel<<<dim3(512), blk, 0, stream>>>(qb, kb, vb, ab);

    // 4. output projection + residual: xa = attn @ wo + x
    gemm_mfma<128, 1, 0, float><<<dim3(Hc / 128, Tc / 128, 1), blk, 0, stream>>>(
        ab, wo, xa, x, Tc, Hc, Hc, 0, 0, 0, 0, nullptr, nullptr);

    // 5. LN2 -> fp32
    ln_kernel<float><<<Tc, blk, 0, stream>>>(xa, ln2_g, ln2_b, x2);

    // 6. router + top2
    router_top2_kernel<<<Tc / 4, blk, 0, stream>>>(x2, wr, ef, gf);

    // 7. positions within expert queues
    pos_kernel<<<Ec, blk, 0, stream>>>(ef, pos);

    // 8. dispatch tokens to expert buffers (bf16)
    dispatch_kernel<<<Tc * 2, dim3(128), 0, stream>>>(x2, ef, pos, bufb);

    // 9. expert GEMM1: h = gelu(buf @ w1 + b1), BM=256 (w1 read exactly once),
    //    XCD-swizzled so each expert's 16 N-blocks share an L2
    gemm_mfma<256, 2, 1, unsigned short><<<dim3(Fc / 128, Cap / 256, Ec), dim3(512), 0, stream>>>(
        bufb, w1, h, b1, Cap, Fc, Hc,
        (long)Cap * Hc, (long)HF, (long)Cap * Fc, (long)Fc, nullptr, nullptr);

    // 10. expert GEMM2: y = h @ w2 + b2 (XCD-swizzled)
    gemm_mfma<256, 3, 1, float><<<dim3(Hc / 128, Cap / 256, Ec), dim3(512), 0, stream>>>(
        h, w2, y, b2, Cap, Hc, Fc,
        (long)Cap * Fc, (long)HF, (long)Cap * Hc, (long)Hc, nullptr, nullptr);

    // 11. combine + final residual
    combine_kernel<<<Tc, dim3(128), 0, stream>>>(xa, y, ef, pos, gf, out);
}

// Round 8
// 291.530 us; speedup vs baseline: 9.7266x; 1.1946x over previous
//
#include <hip/hip_runtime.h>
#include <hip/hip_bf16.h>
#include <math.h>

// Problem constants (from reference setup_inputs)
constexpr int Bc  = 2;
constexpr int Sc  = 2048;
constexpr int Hc  = 512;
constexpr int NHc = 8;
constexpr int Tc  = Bc * Sc;      // 4096 tokens
constexpr int Ec  = 64;           // experts
constexpr int Fc  = 2048;         // ffn dim
constexpr int Cap = 256;          // capacity = 2 * T * 2 / E

typedef __attribute__((ext_vector_type(8))) short bf16x8;
typedef __attribute__((ext_vector_type(4))) float f32x4;

__device__ __forceinline__ unsigned short f2b(float f) {
    union { float f; unsigned u; } v; v.f = f;
    unsigned r = v.u + 0x7FFF + ((v.u >> 16) & 1);   // RTNE
    return (unsigned short)(r >> 16);
}

__device__ __forceinline__ float b2f(unsigned short u) {
    union { unsigned u; float f; } v; v.u = ((unsigned)u) << 16; return v.f;
}

__device__ __forceinline__ unsigned cvt_pk_bf16(float lo, float hi) {
    unsigned r;
    asm volatile("v_cvt_pk_bf16_f32 %0, %1, %2" : "=v"(r) : "v"(lo), "v"(hi));
    return r;
}

__device__ __forceinline__ float gelu_f(float x) {
    // tanh-approx gelu via exp2: gelu = x / (1 + 2^(-k*(x+0.044715 x^3)))
    // k = 2*0.7978845608*log2(e). Saturates correctly at +/-inf.
    float u = x + 0.044715f * x * x * x;
    float r = __builtin_amdgcn_exp2f(-2.302211692851f * u);
    return x * __builtin_amdgcn_rcpf(1.0f + r);
}

// ---------------- LN1: one wave per row, 4 rows/block ------------------------
__global__ __launch_bounds__(256) void ln_rows_kernel(const float* __restrict__ x,
                                                      const float* __restrict__ g,
                                                      const float* __restrict__ b,
                                                      unsigned short* __restrict__ o) {
    int w = threadIdx.x >> 6, l = threadIdx.x & 63;
    int t = blockIdx.x * 4 + w;
    const float4* row = (const float4*)(x + (size_t)t * Hc);
    float4 a = row[l], c = row[l + 64];
    float s  = a.x + a.y + a.z + a.w + c.x + c.y + c.z + c.w;
    float s2 = a.x * a.x + a.y * a.y + a.z * a.z + a.w * a.w
             + c.x * c.x + c.y * c.y + c.z * c.z + c.w * c.w;
    #pragma unroll
    for (int off = 32; off; off >>= 1) {
        s  += __shfl_xor(s,  off);
        s2 += __shfl_xor(s2, off);
    }
    float mean = s * (1.0f / Hc);
    float var  = s2 * (1.0f / Hc) - mean * mean;
    float r = rsqrtf(var + 1e-5f);
    float4 g0 = ((const float4*)g)[l], g1 = ((const float4*)g)[l + 64];
    float4 b0 = ((const float4*)b)[l], b1 = ((const float4*)b)[l + 64];
    ushort4 u0, u1;
    u0.x = f2b((a.x - mean) * r * g0.x + b0.x);
    u0.y = f2b((a.y - mean) * r * g0.y + b0.y);
    u0.z = f2b((a.z - mean) * r * g0.z + b0.z);
    u0.w = f2b((a.w - mean) * r * g0.w + b0.w);
    u1.x = f2b((c.x - mean) * r * g1.x + b1.x);
    u1.y = f2b((c.y - mean) * r * g1.y + b1.y);
    u1.z = f2b((c.z - mean) * r * g1.z + b1.z);
    u1.w = f2b((c.w - mean) * r * g1.w + b1.w);
    ((ushort4*)(o + (size_t)t * Hc))[l]      = u0;
    ((ushort4*)(o + (size_t)t * Hc))[l + 64] = u1;
}

// ---------------- MFMA bf16 GEMM, software-prefetched K-loop ----------------
// C[M,N] = A[M,K](bf16) @ W[K,N](fp32 row-major), batched via blockIdx.z.
// K-loop: write_tile(regs_s); load_tile(s+1); [lgkmcnt0; s_barrier]; compute;
// [s_barrier]. Global loads stay in flight across barriers (no vmcnt drain) ->
// HBM streams during compute; ds_write's vmcnt wait hidden by one full step.
// If Wb != null: W selected per-z from {W, Wb, Wc} (QKV fusion), C += z*sC.
// SWZ=1: bijective XCD remap so same-expert blocks share an XCD L2.
// EPI: 0=none, 1=+X[m*N+n], 2=gelu(acc+X[n]), 3=acc+X[n]
template <int BM, int EPI, int SWZ, typename TC>
__global__ __launch_bounds__(BM * 2) void gemm_mfma(const unsigned short* __restrict__ A,
                                                    const float* __restrict__ W,
                                                    TC* __restrict__ C,
                                                    const float* __restrict__ X,
                                                    int M, int N, int K,
                                                    long sA, long sW, long sC, long sX,
                                                    const float* __restrict__ Wb,
                                                    const float* __restrict__ Wc) {
    int bx = blockIdx.x, bz = blockIdx.z, by = blockIdx.y;
    if (SWZ) {
        int gx = gridDim.x;
        int nwg = gx * gridDim.z;
        int flat = bx + gx * bz;
        int wg = (flat & 7) * (nwg >> 3) + (flat >> 3);
        bx = wg % gx; bz = wg / gx;
    }
    A += (size_t)bz * sA;
    if (Wb) W = (bz == 0) ? W : ((bz == 1) ? Wb : Wc);
    else    W += (size_t)bz * sW;
    C += (size_t)bz * sC;
    if (X) X += (size_t)bz * sX;
    int m0 = by * BM, n0 = bx * 128;

    __shared__ unsigned short As[BM * 72];
    __shared__ unsigned short Bs[128 * 72];

    int tid = threadIdx.x;
    int wid = tid >> 6, lane = tid & 63;
    int wr = (wid >> 1) * 64, wc = (wid & 1) * 64;
    int lr = lane & 15, lg = lane >> 4;

    constexpr int WP = 512 / BM;
    bf16x8 areg[4];
    float4 wa[WP], wb[WP];

    auto load_tile = [&](int k0) {
        #pragma unroll
        for (int p = 0; p < 4; p++) {
            int e = p * 16 * BM + tid * 8;
            int row = e >> 6, col = e & 63;
            areg[p] = *(const bf16x8*)&A[(size_t)(m0 + row) * K + k0 + col];
        }
        #pragma unroll
        for (int p = 0; p < WP; p++) {
            int kp = (tid >> 5) + p * (BM / 16);
            int c  = (tid & 31) * 4;
            const float* w0 = &W[(size_t)(k0 + 2 * kp) * N + n0 + c];
            wa[p] = *(const float4*)w0;
            wb[p] = *(const float4*)(w0 + N);
        }
    };
    auto write_tile = [&]() {
        #pragma unroll
        for (int p = 0; p < 4; p++) {
            int e = p * 16 * BM + tid * 8;
            int row = e >> 6, col = e & 63;
            *(bf16x8*)&As[row * 72 + col] = areg[p];
        }
        #pragma unroll
        for (int p = 0; p < WP; p++) {
            int kp = (tid >> 5) + p * (BM / 16);
            int c  = (tid & 31) * 4;
            int qz = 8 * ((c >> 3) & 7);
            int kof = (2 * kp) ^ qz;
            *(ushort2*)&Bs[(c + 0) * 72 + kof] = (ushort2){f2b(wa[p].x), f2b(wb[p].x)};
            *(ushort2*)&Bs[(c + 1) * 72 + kof] = (ushort2){f2b(wa[p].y), f2b(wb[p].y)};
            *(ushort2*)&Bs[(c + 2) * 72 + kof] = (ushort2){f2b(wa[p].z), f2b(wb[p].z)};
            *(ushort2*)&Bs[(c + 3) * 72 + kof] = (ushort2){f2b(wa[p].w), f2b(wb[p].w)};
        }
    };

    f32x4 acc[4][4];
    #pragma unroll
    for (int i = 0; i < 4; i++)
        #pragma unroll
        for (int j = 0; j < 4; j++) acc[i][j] = (f32x4){0.f, 0.f, 0.f, 0.f};

    load_tile(0);
    int nsteps = K >> 6;
    for (int s = 0; s < nsteps; s++) {
        write_tile();                       // vmcnt wait here is 1 step old -> hidden
        if (s + 1 < nsteps) load_tile((s + 1) << 6);   // prefetch next step
        asm volatile("s_waitcnt lgkmcnt(0)" ::: "memory");
        __builtin_amdgcn_s_barrier();       // no vmcnt drain: loads stay in flight
        #pragma unroll
        for (int kk = 0; kk < 64; kk += 32) {
            bf16x8 af[4], bfr[4];
            #pragma unroll
            for (int i = 0; i < 4; i++) {
                af[i] = *(const bf16x8*)&As[(wr + i * 16 + lr) * 72 + kk + 8 * lg];
                int nrow = wc + i * 16 + lr;
                int qq = 8 * ((nrow >> 3) & 7);
                bfr[i] = *(const bf16x8*)&Bs[nrow * 72 + ((kk + 8 * lg) ^ qq)];
            }
            #pragma unroll
            for (int i = 0; i < 4; i++)
                #pragma unroll
                for (int j = 0; j < 4; j++)
                    acc[i][j] = __builtin_amdgcn_mfma_f32_16x16x32_bf16(af[i], bfr[j], acc[i][j], 0, 0, 0);
        }
        asm volatile("s_waitcnt lgkmcnt(0)" ::: "memory");
        __builtin_amdgcn_s_barrier();       // reads done before next overwrite
    }

    #pragma unroll
    for (int i = 0; i < 4; i++) {
        #pragma unroll
        for (int r = 0; r < 4; r++) {
            int m = m0 + wr + i * 16 + lg * 4 + r;
            #pragma unroll
            for (int j = 0; j < 4; j++) {
                int n = n0 + wc + j * 16 + lr;
                float vv = acc[i][j][r];
                if (EPI == 1) vv += X[(size_t)m * N + n];
                if (EPI == 2) { vv += X[n]; vv = gelu_f(vv); }
                if (EPI == 3) vv += X[n];
                if constexpr (sizeof(TC) == 2) C[(size_t)m * N + n] = (TC)f2b(vv);
                else                            C[(size_t)m * N + n] = vv;
            }
        }
    }
}

// ---------------- MFMA flash attention (unchanged from R7) -------------------
__global__ __launch_bounds__(256) void attn_mfma_kernel(const unsigned short* __restrict__ q,
                                                        const unsigned short* __restrict__ k,
                                                        const unsigned short* __restrict__ v,
                                                        unsigned short* __restrict__ o) {
    constexpr int LDK = 72;
    constexpr int NT  = Sc / 64;
    __shared__ unsigned short Ks[2][64 * LDK];   // [key][d]
    __shared__ unsigned short Vt[2][64 * LDK];   // [d][key^swz]

    int flat = blockIdx.x;
    int wg = (flat & 7) * 64 + (flat >> 3);
    int qt = wg & 31;
    int hb = wg >> 5;
    int hh = hb & 7, b = hb >> 3;

    int q0 = qt * 64;
    int tid = threadIdx.x;
    int wid = tid >> 6, lane = tid & 63;
    int lr = lane & 15, lg = lane >> 4;

    const unsigned short* kbase = k + (size_t)(b * Sc) * Hc + hh * 64;
    const unsigned short* vbase = v + (size_t)(b * Sc) * Hc + hh * 64;

    bf16x8 qf[2];
    {
        const unsigned short* qrow = q + ((size_t)(b * Sc + q0 + wid * 16 + lr)) * Hc + hh * 64;
        qf[0] = *(const bf16x8*)&qrow[8 * lg];
        qf[1] = *(const bf16x8*)&qrow[32 + 8 * lg];
    }

    int krow = tid >> 3;
    int kcol = (tid & 7) * 8;
    int vk2  = (tid >> 4) * 2;
    int vd4  = (tid & 15) * 4;

    bf16x8 kr[2];
    ushort4 va[2], vb2[2];

    auto load_tile = [&](int kt) {
        #pragma unroll
        for (int p = 0; p < 2; p++) {
            kr[p] = *(const bf16x8*)&kbase[(size_t)(kt * 64 + p * 32 + krow) * Hc + kcol];
            const unsigned short* vp = &vbase[(size_t)(kt * 64 + p * 32 + vk2) * Hc + vd4];
            va[p]  = *(const ushort4*)vp;
            vb2[p] = *(const ushort4*)(vp + Hc);
        }
    };
    auto vswz = [](int d, int c) { return c ^ (8 * ((d >> 3) & 7)); };
    auto store_tile = [&](int bu) {
        #pragma unroll
        for (int p = 0; p < 2; p++) {
            *(bf16x8*)&Ks[bu][(p * 32 + krow) * LDK + kcol] = kr[p];
            int k2 = p * 32 + vk2;
            *(ushort2*)&Vt[bu][(vd4 + 0) * LDK + vswz(vd4 + 0, k2)] = (ushort2){va[p].x, vb2[p].x};
            *(ushort2*)&Vt[bu][(vd4 + 1) * LDK + vswz(vd4 + 1, k2)] = (ushort2){va[p].y, vb2[p].y};
            *(ushort2*)&Vt[bu][(vd4 + 2) * LDK + vswz(vd4 + 2, k2)] = (ushort2){va[p].z, vb2[p].z};
            *(ushort2*)&Vt[bu][(vd4 + 3) * LDK + vswz(vd4 + 3, k2)] = (ushort2){va[p].w, vb2[p].w};
        }
    };

    f32x4 Oacc[4];
    #pragma unroll
    for (int nb = 0; nb < 4; nb++) Oacc[nb] = (f32x4){0.f, 0.f, 0.f, 0.f};
    float mrun = -1e30f, lrun = 0.f;
    const float SCL2 = 0.125f * 1.4426950408889634f;

    load_tile(0);
    store_tile(0);
    __syncthreads();

    for (int kt = 0; kt < NT; kt++) {
        int cur = kt & 1;
        if (kt + 1 < NT) load_tile(kt + 1);

        f32x4 sacc[4];
        #pragma unroll
        for (int kb = 0; kb < 4; kb++) sacc[kb] = (f32x4){0.f, 0.f, 0.f, 0.f};
        __builtin_amdgcn_s_setprio(1);
        #pragma unroll
        for (int kb = 0; kb < 4; kb++) {
            #pragma unroll
            for (int s = 0; s < 2; s++) {
                bf16x8 kf = *(const bf16x8*)&Ks[cur][(kb * 16 + lr) * LDK + 32 * s + 8 * lg];
                sacc[kb] = __builtin_amdgcn_mfma_f32_16x16x32_bf16(kf, qf[s], sacc[kb], 0, 0, 0);
            }
        }
        __builtin_amdgcn_s_setprio(0);

        float z[4][4];
        float mt = -1e30f;
        #pragma unroll
        for (int kb = 0; kb < 4; kb++)
            #pragma unroll
            for (int r = 0; r < 4; r++) {
                z[kb][r] = sacc[kb][r] * SCL2;
                mt = fmaxf(mt, z[kb][r]);
            }
        mt = fmaxf(mt, __shfl_xor(mt, 16));
        mt = fmaxf(mt, __shfl_xor(mt, 32));

        bool defer = __all(mt - mrun <= 11.0f);
        float pv[4][4];
        float ps = 0.f;
        if (defer) {
            #pragma unroll
            for (int kb = 0; kb < 4; kb++)
                #pragma unroll
                for (int r = 0; r < 4; r++) {
                    pv[kb][r] = __builtin_amdgcn_exp2f(z[kb][r] - mrun);
                    ps += pv[kb][r];
                }
            ps += __shfl_xor(ps, 16);
            ps += __shfl_xor(ps, 32);
            lrun += ps;
        } else {
            float mnew = fmaxf(mrun, mt);
            float sc = __builtin_amdgcn_exp2f(mrun - mnew);
            #pragma unroll
            for (int kb = 0; kb < 4; kb++)
                #pragma unroll
                for (int r = 0; r < 4; r++) {
                    pv[kb][r] = __builtin_amdgcn_exp2f(z[kb][r] - mnew);
                    ps += pv[kb][r];
                }
            ps += __shfl_xor(ps, 16);
            ps += __shfl_xor(ps, 32);
            lrun = lrun * sc + ps;
            mrun = mnew;
            float scb[4];
            #pragma unroll
            for (int r = 0; r < 4; r++) scb[r] = __shfl(sc, lg * 4 + r);
            #pragma unroll
            for (int nb = 0; nb < 4; nb++)
                #pragma unroll
                for (int r = 0; r < 4; r++) Oacc[nb][r] *= scb[r];
        }

        unsigned d_[4][2];
        #pragma unroll
        for (int kb = 0; kb < 4; kb++) {
            d_[kb][0] = cvt_pk_bf16(pv[kb][0], pv[kb][1]);
            d_[kb][1] = cvt_pk_bf16(pv[kb][2], pv[kb][3]);
        }
        unsigned pfw[2][4];
        #pragma unroll
        for (int s = 0; s < 2; s++) {
            #pragma unroll
            for (int h = 0; h < 2; h++) {
                unsigned xx = d_[2 * s][h], yy = d_[2 * s + 1][h];
                asm volatile("v_permlane32_swap_b32 %0, %1" : "+v"(xx), "+v"(yy));
                asm volatile("v_permlane16_swap_b32 %0, %1" : "+v"(xx), "+v"(yy));
                pfw[s][h]     = xx;
                pfw[s][2 + h] = yy;
            }
        }
        bf16x8 pf0, pf1;
        *(unsigned*)&((short*)&pf0)[0] = pfw[0][0];
        *(unsigned*)&((short*)&pf0)[2] = pfw[0][1];
        *(unsigned*)&((short*)&pf0)[4] = pfw[0][2];
        *(unsigned*)&((short*)&pf0)[6] = pfw[0][3];
        *(unsigned*)&((short*)&pf1)[0] = pfw[1][0];
        *(unsigned*)&((short*)&pf1)[2] = pfw[1][1];
        *(unsigned*)&((short*)&pf1)[4] = pfw[1][2];
        *(unsigned*)&((short*)&pf1)[6] = pfw[1][3];

        __builtin_amdgcn_s_setprio(1);
        #pragma unroll
        for (int nb = 0; nb < 4; nb++) {
            f32x4 oa = Oacc[nb];
            int vrow = nb * 16 + lr;
            bf16x8 vf0 = *(const bf16x8*)&Vt[cur][vrow * LDK + vswz(vrow, 8 * lg)];
            bf16x8 vf1 = *(const bf16x8*)&Vt[cur][vrow * LDK + vswz(vrow, 32 + 8 * lg)];
            oa = __builtin_amdgcn_mfma_f32_16x16x32_bf16(pf0, vf0, oa, 0, 0, 0);
            oa = __builtin_amdgcn_mfma_f32_16x16x32_bf16(pf1, vf1, oa, 0, 0, 0);
            Oacc[nb] = oa;
        }
        __builtin_amdgcn_s_setprio(0);

        if (kt + 1 < NT) store_tile(cur ^ 1);
        __syncthreads();
    }

    float linv = 1.0f / lrun;
    unsigned short* ob = o + ((size_t)(b * Sc + q0 + wid * 16)) * Hc + hh * 64;
    #pragma unroll
    for (int r = 0; r < 4; r++) {
        float invB = __shfl(linv, lg * 4 + r);
        #pragma unroll
        for (int nb = 0; nb < 4; nb++) {
            ob[(size_t)(lg * 4 + r) * Hc + nb * 16 + lr] = f2b(Oacc[nb][r] * invB);
        }
    }
}

// ---------------- fused LN2 + router + top-2 (exact fp32 gates) --------------
// One block per token. Writes bf16 x2 (for dispatch) + ef/gf.
__global__ __launch_bounds__(256) void ln2_router_kernel(const float* __restrict__ xa,
                                                         const float* __restrict__ g,
                                                         const float* __restrict__ b,
                                                         const float* __restrict__ wr,
                                                         unsigned short* __restrict__ x2b,
                                                         int* __restrict__ ef,
                                                         float* __restrict__ gf) {
    int t = blockIdx.x;
    const float* row = xa + (size_t)t * Hc;
    int tid = threadIdx.x;
    int w = tid >> 6, l = tid & 63;
    float v0 = row[tid];
    float v1 = row[tid + 256];
    float s = v0 + v1, s2 = v0 * v0 + v1 * v1;
    for (int off = 32; off; off >>= 1) {
        s  += __shfl_down(s,  off);
        s2 += __shfl_down(s2, off);
    }
    __shared__ float ls[4], ls2[4];
    __shared__ float xn[512];
    __shared__ float part[4][64];
    if (l == 0) { ls[w] = s; ls2[w] = s2; }
    __syncthreads();
    if (tid == 0) {
        float a = 0.f, a2 = 0.f;
        for (int i = 0; i < 4; i++) { a += ls[i]; a2 += ls2[i]; }
        ls[0] = a; ls2[0] = a2;
    }
    __syncthreads();
    float mean = ls[0] * (1.0f / Hc);
    float var  = ls2[0] * (1.0f / Hc) - mean * mean;
    float r = rsqrtf(var + 1e-5f);
    float o0 = (v0 - mean) * r * g[tid]       + b[tid];
    float o1 = (v1 - mean) * r * g[tid + 256] + b[tid + 256];
    xn[tid] = o0; xn[tid + 256] = o1;
    x2b[(size_t)t * Hc + tid]       = f2b(o0);
    x2b[(size_t)t * Hc + tid + 256] = f2b(o1);
    __syncthreads();

    // router: wave w covers h in [w*128, w*128+128); lane = expert
    float acc = 0.f;
    const float* wrow = wr + (size_t)(w * 128) * Ec + l;
    #pragma unroll 8
    for (int hh = 0; hh < 128; hh++)
        acc += xn[w * 128 + hh] * wrow[(size_t)hh * Ec];
    part[w][l] = acc;
    __syncthreads();
    if (w == 0) {
        float logit = part[0][l] + part[1][l] + part[2][l] + part[3][l];
        float mx = logit;
        for (int off = 32; off; off >>= 1) mx = fmaxf(mx, __shfl_xor(mx, off));
        float p = __expf(logit - mx);
        float sum = p;
        for (int off = 32; off; off >>= 1) sum += __shfl_xor(sum, off);
        p /= sum;
        float v1_ = p; int i1 = l;
        for (int off = 32; off; off >>= 1) {
            float ov = __shfl_xor(v1_, off);
            int   oi = __shfl_xor(i1, off);
            if (ov > v1_ || (ov == v1_ && oi < i1)) { v1_ = ov; i1 = oi; }
        }
        float v2_ = (l == i1) ? -INFINITY : p; int i2 = l;
        for (int off = 32; off; off >>= 1) {
            float ov = __shfl_xor(v2_, off);
            int   oi = __shfl_xor(i2, off);
            if (ov > v2_ || (ov == v2_ && oi < i2)) { v2_ = ov; i2 = oi; }
        }
        if (l == 0) {
            float inv = 1.0f / (v1_ + v2_);
            ef[t * 2]     = i1;
            ef[t * 2 + 1] = i2;
            gf[t * 2]     = v1_ * inv;
            gf[t * 2 + 1] = v2_ * inv;
        }
    }
}

// ---------------- pos: rank of each slot within its expert (parallel scan) ---
__global__ __launch_bounds__(256) void pos_kernel(const int* __restrict__ ef,
                                                  int* __restrict__ pos) {
    int e = blockIdx.x;
    __shared__ int cnts[257];
    int tid = threadIdx.x;
    int base = tid * 32;  // 8192 / 256
    int c = 0;
    for (int i = 0; i < 32; i++) c += (ef[base + i] == e) ? 1 : 0;
    cnts[tid + 1] = c;
    if (tid == 0) cnts[0] = 0;
    __syncthreads();
    // Hillis-Steele inclusive scan over cnts[1..256]
    #pragma unroll
    for (int off = 1; off < 256; off <<= 1) {
        int v = cnts[tid + 1];
        int add = (tid + 1 > off) ? cnts[tid + 1 - off] : 0;
        __syncthreads();
        cnts[tid + 1] = v + add;
        __syncthreads();
    }
    int run = cnts[tid];
    for (int i = 0; i < 32; i++) {
        if (ef[base + i] == e) pos[base + i] = run++;
    }
}

// ---------------- dispatch: copy kept tokens (bf16 -> bf16) ------------------
__global__ __launch_bounds__(128) void dispatch_kernel(const unsigned short* __restrict__ x2b,
                                                       const int* __restrict__ ef,
                                                       const int* __restrict__ pos,
                                                       unsigned short* __restrict__ buf) {
    int s = blockIdx.x;
    int p = pos[s];
    if (p >= Cap) return;
    int e = ef[s];
    int t = s >> 1;
    ushort4 vv = ((const ushort4*)(x2b + (size_t)t * Hc))[threadIdx.x];
    ((ushort4*)(buf + ((size_t)e * Cap + p) * Hc))[threadIdx.x] = vv;
}

// ---------------- combine: out = xa + sum_k gate * y[ef,pos] (y bf16) --------
__global__ __launch_bounds__(128) void combine_kernel(const float* __restrict__ xa,
                                                      const unsigned short* __restrict__ y,
                                                      const int* __restrict__ ef,
                                                      const int* __restrict__ pos,
                                                      const float* __restrict__ gf,
                                                      float* __restrict__ out) {
    int t = blockIdx.x;
    int d = threadIdx.x;
    float4 acc = ((const float4*)(xa + (size_t)t * Hc))[d];
    #pragma unroll
    for (int kk = 0; kk < 2; kk++) {
        int s = t * 2 + kk;
        int p = pos[s];
        if (p < Cap) {
            float w = gf[s];
            ushort4 yv = ((const ushort4*)(y + ((size_t)ef[s] * Cap + p) * Hc))[d];
            acc.x += w * b2f(yv.x);
            acc.y += w * b2f(yv.y);
            acc.z += w * b2f(yv.z);
            acc.w += w * b2f(yv.w);
        }
    }
    ((float4*)(out + (size_t)t * Hc))[d] = acc;
}

// ---------------- launch -----------------------------------------------------
extern "C" void kernel_launch(void* const* d_in, const int* in_sizes, int n_in,
                              void* d_out, int out_size, void* d_ws, size_t ws_size,
                              hipStream_t stream) {
    const float* x     = (const float*)d_in[0];
    const float* ln1_g = (const float*)d_in[1];
    const float* ln1_b = (const float*)d_in[2];
    const float* wq    = (const float*)d_in[3];
    const float* wk    = (const float*)d_in[4];
    const float* wv    = (const float*)d_in[5];
    const float* wo    = (const float*)d_in[6];
    const float* ln2_g = (const float*)d_in[7];
    const float* ln2_b = (const float*)d_in[8];
    const float* wr    = (const float*)d_in[9];
    const float* w1    = (const float*)d_in[10];
    const float* b1    = (const float*)d_in[11];
    const float* w2    = (const float*)d_in[12];
    const float* b2    = (const float*)d_in[13];
    float* out = (float*)d_out;

    const size_t TH   = (size_t)Tc * Hc;        // 2,097,152
    const size_t ECH  = (size_t)Ec * Cap * Hc;  // 8,388,608
    const size_t ECF  = (size_t)Ec * Cap * Fc;  // 33,554,432
    const size_t HF   = (size_t)Hc * Fc;        // 1,048,576 (per-expert w size)

    // ---- workspace carve (bytes) ----
    char* wsb = (char*)d_ws;
    size_t off = 0;
    auto alloc = [&](size_t bytes) { size_t r = off; off = (off + bytes + 255) & ~(size_t)255; return r; };
    size_t x1b_off = alloc(TH * 2);       // bf16 x1
    size_t qkv_off = alloc(TH * 2 * 3);   // bf16 q|k|v contiguous
    size_t ab_off  = alloc(TH * 2);       // bf16 attention output
    size_t xa_off  = alloc(TH * 4);       // fp32 attn residual out
    size_t x2b_off = alloc(TH * 2);       // bf16 LN2 out
    size_t ef_off  = alloc((size_t)Tc * 2 * 4);
    size_t pos_off = alloc((size_t)Tc * 2 * 4);
    size_t gf_off  = alloc((size_t)Tc * 2 * 4);
    size_t buf_off = alloc(ECH * 2);      // bf16 expert inputs
    size_t h_off   = alloc(ECF * 2);      // bf16 h (all experts)
    size_t y_off   = alloc(ECH * 2);      // bf16 expert outputs
    if (ws_size < off) return;            // insufficient workspace

    unsigned short* x1b  = (unsigned short*)(wsb + x1b_off);
    unsigned short* qb   = (unsigned short*)(wsb + qkv_off);
    unsigned short* kb   = qb + TH;
    unsigned short* vb   = qb + 2 * TH;
    unsigned short* ab   = (unsigned short*)(wsb + ab_off);
    float* xa  = (float*)(wsb + xa_off);
    unsigned short* x2b = (unsigned short*)(wsb + x2b_off);
    int*   ef  = (int*)(wsb + ef_off);
    int*   pos = (int*)(wsb + pos_off);
    float* gf  = (float*)(wsb + gf_off);
    unsigned short* bufb = (unsigned short*)(wsb + buf_off);
    unsigned short* h    = (unsigned short*)(wsb + h_off);
    unsigned short* y    = (unsigned short*)(wsb + y_off);

    dim3 blk(256);

    // 1. LN1 -> bf16 (wave per row)
    ln_rows_kernel<<<Tc / 4, blk, 0, stream>>>(x, ln1_g, ln1_b, x1b);

    // 2. fused QKV projections: one launch, z selects {wq,wk,wv} -> q|k|v
    gemm_mfma<128, 0, 0, unsigned short><<<dim3(Hc / 128, Tc / 128, 3), blk, 0, stream>>>(
        x1b, wq, qb, nullptr, Tc, Hc, Hc, 0, 0, (long)TH, 0, wk, wv);

    // 3. attention -> bf16 ab (1-D grid, XCD-swizzled)
    attn_mfma_kernel<<<dim3(512), blk, 0, stream>>>(qb, kb, vb, ab);

    // 4. output projection + residual: xa = attn @ wo + x
    gemm_mfma<128, 1, 0, float><<<dim3(Hc / 128, Tc / 128, 1), blk, 0, stream>>>(
        ab, wo, xa, x, Tc, Hc, Hc, 0, 0, 0, 0, nullptr, nullptr);

    // 5. fused LN2 + router + top2 -> x2b, ef, gf
    ln2_router_kernel<<<Tc, blk, 0, stream>>>(xa, ln2_g, ln2_b, wr, x2b, ef, gf);

    // 6. positions within expert queues
    pos_kernel<<<Ec, blk, 0, stream>>>(ef, pos);

    // 7. dispatch tokens to expert buffers (bf16 copy)
    dispatch_kernel<<<Tc * 2, dim3(128), 0, stream>>>(x2b, ef, pos, bufb);

    // 8. expert GEMM1: h = gelu(buf @ w1 + b1), BM=256 (w1 read exactly once)
    gemm_mfma<256, 2, 1, unsigned short><<<dim3(Fc / 128, Cap / 256, Ec), dim3(512), 0, stream>>>(
        bufb, w1, h, b1, Cap, Fc, Hc,
        (long)Cap * Hc, (long)HF, (long)Cap * Fc, (long)Fc, nullptr, nullptr);

    // 9. expert GEMM2: y = h @ w2 + b2 (bf16 out, XCD-swizzled)
    gemm_mfma<256, 3, 1, unsigned short><<<dim3(Hc / 128, Cap / 256, Ec), dim3(512), 0, stream>>>(
        h, w2, y, b2, Cap, Hc, Fc,
        (long)Cap * Fc, (long)HF, (long)Cap * Hc, (long)Hc, nullptr, nullptr);

    // 10. combine + final residual
    combine_kernel<<<Tc, dim3(128), 0, stream>>>(xa, y, ef, pos, gf, out);
}